// Round 8
// baseline (32896.954 us; speedup 1.0000x reference)
//
#include <hip/hip_runtime.h>
#include <hip/hip_cooperative_groups.h>
#include <math.h>

#define NN 1147
#define HID 512
#define LDAe 1152
#define LDQ 1152
#define LDD 1147
#define EPS32 5.9604644775390625e-08f
#define SAFMIN32 1.17549435e-38f
#define IMID 762   // midgame start (m = 384 at entry): single-block, no grid barrier
#define I0E 1026   // endgame start iteration (m = 120 at entry)
#define TGRID 64   // persistent tridiag grid (64 blocks x 1024 thr = 1024 row-slots)
#define TBLK 1024
#define GENSTRIDE 16  // one 64B line per block for the replicated release word

struct EDMeta { int K; int nrot; int early; float rho; };
struct ETree { int st[64]; int sz[64]; int cnt; };
struct MergeLvl { int cnt; int st[32]; int n1[32]; int n2[32]; };

__device__ __forceinline__ float lapy2f(float x, float y){
  float xa=fabsf(x), ya=fabsf(y), w=fmaxf(xa,ya), z2=fminf(xa,ya);
  if (z2==0.f) return w;
  float q=z2/w; return w*sqrtf(1.f+q*q);
}
__device__ __forceinline__ void slartg(float ff, float gg, float* c, float* s, float* r){
  if (gg==0.f){ *c=1.f; *s=0.f; *r=ff; }
  else if (ff==0.f){ *c=0.f; *s=copysignf(1.f,gg); *r=fabsf(gg); }
  else {
    float d=sqrtf(ff*ff+gg*gg);
    *c=fabsf(ff)/d;
    *r=copysignf(d,ff);
    *s=gg/(*r);
  }
}
__device__ void slaev2(float a, float b, float cc, float* rt1, float* rt2, float* cs1, float* sn1){
  float sm=a+cc, df=a-cc, adf=fabsf(df), tb=b+b, ab=fabsf(tb);
  float acmx, acmn;
  if (fabsf(a)>fabsf(cc)){ acmx=a; acmn=cc; } else { acmx=cc; acmn=a; }
  float rt;
  if (adf>ab) rt=adf*sqrtf(1.f+(ab/adf)*(ab/adf));
  else if (adf<ab) rt=ab*sqrtf(1.f+(adf/ab)*(adf/ab));
  else rt=ab*sqrtf(2.f);
  int sgn1;
  if (sm<0.f){ *rt1=0.5f*(sm-rt); sgn1=-1; *rt2=(acmx/(*rt1))*acmn-(b/(*rt1))*b; }
  else if (sm>0.f){ *rt1=0.5f*(sm+rt); sgn1=1; *rt2=(acmx/(*rt1))*acmn-(b/(*rt1))*b; }
  else { *rt1=0.5f*rt; *rt2=-0.5f*rt; sgn1=1; }
  int sgn2; float cs;
  if (df>=0.f){ cs=df+rt; sgn2=1; } else { cs=df-rt; sgn2=-1; }
  float acs=fabsf(cs);
  if (acs>ab){ float ct=-tb/cs; *sn1=1.f/sqrtf(1.f+ct*ct); *cs1=ct*(*sn1); }
  else {
    if (ab==0.f){ *cs1=1.f; *sn1=0.f; }
    else { float tn=-cs/tb; *cs1=1.f/sqrtf(1.f+tn*tn); *sn1=tn*(*cs1); }
  }
  if (sgn1==sgn2){ float tn=*cs1; *cs1=-(*sn1); *sn1=tn; }
}
// LAPACK dlamrg, 0-based; works on global or LDS pointers
__device__ void lamrg0(int n1,int n2,const float* a,int dtrd1,int dtrd2,int* idx){
  int n1sv=n1,n2sv=n2;
  int ind1=(dtrd1>0)?0:(n1-1);
  int ind2=(dtrd2>0)?n1:(n1+n2-1);
  int i=0;
  while(n1sv>0&&n2sv>0){
    if(a[ind1]<=a[ind2]){idx[i++]=ind1;ind1+=dtrd1;n1sv--;}
    else{idx[i++]=ind2;ind2+=dtrd2;n2sv--;}
  }
  while(n2sv>0){idx[i++]=ind2;ind2+=dtrd2;n2sv--;}
  while(n1sv>0){idx[i++]=ind1;ind1+=dtrd1;n1sv--;}
}

// 256-entry tree reduction, bitwise-identical to the sequential st=128..1
// pairwise tree; wave 0 computes steps 128,64 explicitly, then folds 32..1 via
// shuffles with the same pairwise association. 2 block barriers instead of 9.
__device__ __forceinline__ float tree256(float* red, float* bc, int tid){
  __syncthreads();
  if (tid<64){
    float b=(red[tid]+red[tid+128])+(red[tid+64]+red[tid+192]);
    b+=__shfl_down(b,32,64);
    b+=__shfl_down(b,16,64);
    b+=__shfl_down(b,8,64);
    b+=__shfl_down(b,4,64);
    b+=__shfl_down(b,2,64);
    b+=__shfl_down(b,1,64);
    if (tid==0) *bc=b;
  }
  __syncthreads();
  return *bc;
}

// ---------------- utility ----------------
__global__ __launch_bounds__(256) void k_zero_f(float* p, int n){
  int i = blockIdx.x*256+threadIdx.x; if (i<n) p[i]=0.f;
}
__global__ __launch_bounds__(256) void k_zero_i(int* p, int n){
  int i = blockIdx.x*256+threadIdx.x; if (i<n) p[i]=0;
}

// ---------------- Laplacian ----------------
__global__ __launch_bounds__(256) void k_adj(const int* __restrict__ src, const int* __restrict__ dst,
                                             float* __restrict__ A, int P){
  int p = blockIdx.x*256+threadIdx.x;
  if (p>=P) return;
  int s=src[p], d=dst[p];
  A[(size_t)s*LDAe+d]=1.f;
  A[(size_t)d*LDAe+s]=1.f;
}
__global__ __launch_bounds__(256) void k_deg(const float* __restrict__ A, float* __restrict__ dinv){
  int row=blockIdx.x; int tid=threadIdx.x;
  __shared__ float red[256];
  float s=0.f;
  for (int c=tid;c<NN;c+=256) s+=A[(size_t)row*LDAe+c];
  red[tid]=s; __syncthreads();
  for(int st=128;st;st>>=1){ if(tid<st) red[tid]+=red[tid+st]; __syncthreads(); }
  if(tid==0) dinv[row]=1.f/sqrtf(fmaxf(red[0],1.f));
}
__global__ __launch_bounds__(256) void k_lap(float* __restrict__ A, const float* __restrict__ dinv){
  int row=blockIdx.y; int col=blockIdx.x*256+threadIdx.x;
  if (col>=NN) return;
  size_t idx=(size_t)row*LDAe+col;
  float v=A[idx];
  float v1=(dinv[row]*v)*dinv[col];
  float v2=(dinv[col]*v)*dinv[row];
  A[idx] = ((row==col)?1.f:0.f) - 0.5f*(v1+v2);
}

// ---------------- device-scope (cross-XCD coherent) accessors ----------------
__device__ __forceinline__ float dload(const float* p){
  return __hip_atomic_load(p, __ATOMIC_RELAXED, __HIP_MEMORY_SCOPE_AGENT);
}
__device__ __forceinline__ void dstore(float* p, float v){
  __hip_atomic_store(p, v, __ATOMIC_RELAXED, __HIP_MEMORY_SCOPE_AGENT);
}

// ---------------- fence-free hierarchical grid barrier, contention-free release ----------------
__device__ __forceinline__ void gbar(unsigned* flags, unsigned* genrep, unsigned tgt){
  __syncthreads();
  if (threadIdx.x==0)
    __hip_atomic_store(&flags[blockIdx.x], tgt, __ATOMIC_RELAXED, __HIP_MEMORY_SCOPE_AGENT);
  if (blockIdx.x==0){
    if (threadIdx.x<TGRID){
      while (__hip_atomic_load(&flags[threadIdx.x], __ATOMIC_RELAXED, __HIP_MEMORY_SCOPE_AGENT) < tgt)
        __builtin_amdgcn_s_sleep(1);
    }
    __syncthreads();
    if (threadIdx.x<TGRID)
      __hip_atomic_store(&genrep[threadIdx.x*GENSTRIDE], tgt, __ATOMIC_RELAXED, __HIP_MEMORY_SCOPE_AGENT);
  } else {
    if (threadIdx.x==0){
      while (__hip_atomic_load(&genrep[blockIdx.x*GENSTRIDE], __ATOMIC_RELAXED, __HIP_MEMORY_SCOPE_AGENT) < tgt)
        __builtin_amdgcn_s_sleep(1);
    }
    __syncthreads();
  }
}

// ---------------- tridiagonalization: persistent, single-writer ownership ----------------
// 64 blocks x 1024 threads = 1024 row-slots; slot s owns rows s and s+1024.
// Columns 0..IMID-1 only; the rest is handled barrier-free by k_tmid + k_tend.
__global__ __launch_bounds__(1024) void k_trid(float* __restrict__ A, float* __restrict__ evec,
    float* __restrict__ tauv, float* __restrict__ scalv, float* __restrict__ pv2,
    float* __restrict__ pub4, unsigned* __restrict__ flags, unsigned* __restrict__ genrep){
  __shared__ float vbuf[2][1152];
  __shared__ float pcur[1152];
  __shared__ float pubc[1152];
  __shared__ float red[256];
  __shared__ float bcv;
  int tid=threadIdx.x, bid=blockIdx.x;
  int wv=tid>>6, lane=tid&63;
  unsigned tgt=0;
  float tau, scal;
  // ---- prologue: column-0 scalars (redundant), p_0 over own rows, publish row 1 ----
  {
    const float* row0=A;
    int m0=NN-1;
    if (tid<256){
      float s=0.f;
      for(int t=tid;t<m0-1;t+=256){ float x=row0[2+t]; s+=x*x; }
      red[tid]=s;
    }
    float xn2=tree256(red,&bcv,tid);
    float alpha=row0[1];
    float beta;
    if(xn2==0.f){ tau=0.f; beta=alpha; scal=0.f; }
    else { beta=-copysignf(sqrtf(alpha*alpha+xn2),alpha); tau=(beta-alpha)/beta; scal=1.f/(alpha-beta); }
    if(bid==0&&tid==0){ evec[0]=beta; tauv[0]=tau; scalv[0]=scal; }
    for(int t=tid;t<m0;t+=TBLK) vbuf[0][t]=row0[1+t];
    __syncthreads();
    for(int rr=0;rr<2;rr++){
      int r=16*bid+wv+rr*1024;
      if(r<1||r>=NN) continue;
      const float* arow=A+(size_t)r*LDAe+1;
      float acc=0.f;
      for(int c=lane;c<m0;c+=64){
        float v=(c==0)?1.f:vbuf[0][c]*scal;
        acc+=arow[c]*v;
      }
      for(int o=32;o;o>>=1) acc+=__shfl_down(acc,o,64);
      if(lane==0) dstore(&pv2[r],acc);
    }
    if(bid==0&&wv==1){  // owner of row 1 publishes original row 1 (cols >= 2)
      const float* r1=A+(size_t)LDAe;
      for(int c=2+lane;c<NN;c+=64) dstore(&pub4[1280+c],r1[c]);
    }
  }
  gbar(flags,genrep,++tgt);
  int cur=0;
  for(int i=0;i<IMID;i++){
    // retirement: blocks >=8 with no remaining rows exit forever
    if (bid>=8 && i>=16*bid+15){
      if (tid==0)
        __hip_atomic_store(&flags[bid], 0x7FFFFFFFu, __ATOMIC_RELAXED, __HIP_MEMORY_SCOPE_AGENT);
      return;
    }
    int m=NN-1-i, mp=m-1;
    float* vcur=vbuf[cur]; float* nxt=vbuf[cur^1];
    const float* pvs=pv2+(size_t)(i&1)*1280;
    const float* pbs=pub4+(size_t)((i+1)&3)*1280;
    // fused stage + s=v.p partials (thr 0-255) ; pivot-row stage (thr 256-1023)
    if (tid<256){
      float s=0.f;
      for(int t=tid;t<m;t+=256){
        float pv=dload(&pvs[(i+1)+t]);
        pcur[t]=pv;
        float v=(t==0)?1.f:vcur[t]*scal;
        s+=pv*v;
      }
      red[tid]=s;
    } else {
      for(int t=tid-256;t<mp;t+=768) pubc[t]=dload(&pbs[(i+2)+t]);
    }
    float sv=tree256(red,&bcv,tid);
    float c2=tau*tau*sv*0.5f;
    const float vz=1.f;
    float wR0=tau*pcur[0]-c2*vz;
    // fused next-pivot-row + norm partials (original norm assignment/order)
    if (tid<256){
      float s2=0.f;
      if (tid==0){
        float vC=vcur[1]*scal;
        float wC=tau*pcur[1]-c2*vC;
        nxt[0]=pubc[0]-(vz*wC+wR0*vC);
      }
      for(int u=tid+1;u<mp;u+=256){
        float vC=vcur[1+u]*scal;
        float wC=tau*pcur[1+u]-c2*vC;
        float x=pubc[u]-(vz*wC+wR0*vC);
        nxt[u]=x;
        s2+=x*x;
      }
      red[tid]=s2;
    }
    float xn2=tree256(red,&bcv,tid);
    float alpha1=nxt[0];
    float beta1,tau1,scal1;
    if(xn2==0.f){ tau1=0.f; beta1=alpha1; scal1=0.f; }
    else { beta1=-copysignf(sqrtf(alpha1*alpha1+xn2),alpha1); tau1=(beta1-alpha1)/beta1; scal1=1.f/(alpha1-beta1); }
    if(bid==0&&tid==0){ evec[i+1]=beta1; tauv[i+1]=tau1; scalv[i+1]=scal1; }
    // fused own-row pass: rank-2 update + dot with next v (+publish / +pivot overwrite)
    float* pvd=pv2+(size_t)((i+1)&1)*1280;
    float* pbd=pub4+(size_t)((i+2)&3)*1280;
    for(int rr=0;rr<2;rr++){
      int r=16*bid+wv+rr*1024;
      if(r<i+1||r>=NN) continue;
      int tr=r-(i+1);
      float vR=(tr==0)?1.f:vcur[tr]*scal;
      float wR=tau*pcur[tr]-c2*vR;
      float* arow=A+(size_t)r*LDAe;
      if(lane==0) arow[i+1]=arow[i+1]-(vR*wR0+wR*vz);
      if(tr==0){
        // row i+1: store the redundantly-computed values for bitwise consistency
        for(int c=lane;c<mp;c+=64) arow[i+2+c]=nxt[c];
      } else {
        float acc=0.f;
        int ispub=(tr==1);  // r == i+2: next iteration's pivot row
        for(int c=lane;c<mp;c+=64){
          float vC=vcur[1+c]*scal;
          float wC=tau*pcur[1+c]-c2*vC;
          float val=arow[i+2+c]-(vR*wC+wR*vC);
          arow[i+2+c]=val;
          float v1=(c==0)?1.f:nxt[c]*scal1;
          acc+=val*v1;
          if(ispub) dstore(&pbd[(i+2)+c],val);
        }
        for(int o=32;o;o>>=1) acc+=__shfl_down(acc,o,64);
        if(lane==0) dstore(&pvd[r],acc);
      }
    }
    gbar(flags,genrep,++tgt);
    cur^=1; tau=tau1; scal=scal1;
  }
}

// ---------------- midgame: columns IMID..I0E-1, single block, no grid barrier ----------------
// Byte-identical arithmetic to k_trid: same 256-thread partial orders, same
// tree256, same 64-lane per-row dot order. The p / pivot-row rings live in LDS;
// A stays global (single block -> own-L2 resident trailing matrix).
__global__ __launch_bounds__(1024) void k_tmid(float* __restrict__ A, float* __restrict__ evec,
    float* __restrict__ tauv, float* __restrict__ scalv,
    const float* __restrict__ pv2, const float* __restrict__ pub4){
  __shared__ float vbuf[2][1152];
  __shared__ float pvl[2][1152];
  __shared__ float pbl[4][1152];
  __shared__ float red[256];
  __shared__ float bcv;
  int tid=threadIdx.x;
  int wv=tid>>6, lane=tid&63;
  int cur=IMID&1;
  float tau=tauv[IMID], scal=scalv[IMID];
  {
    int m0=NN-1-IMID;
    const float* rowv=A+(size_t)IMID*LDAe+(IMID+1);
    for(int t=tid;t<m0;t+=TBLK) vbuf[cur][t]=rowv[t];
    const float* pvs=pv2+(size_t)(IMID&1)*1280;
    for(int t=tid;t<m0;t+=TBLK) pvl[IMID&1][(IMID+1)+t]=pvs[(IMID+1)+t];
    const float* pbs=pub4+(size_t)((IMID+1)&3)*1280;
    for(int t=tid;t<m0-1;t+=TBLK) pbl[(IMID+1)&3][(IMID+2)+t]=pbs[(IMID+2)+t];
  }
  __syncthreads();
  for(int i=IMID;i<I0E;i++){
    int m=NN-1-i, mp=m-1;
    float* vcur=vbuf[cur]; float* nxt=vbuf[cur^1];
    float* pvs=pvl[i&1];
    float* pbs=pbl[(i+1)&3];
    if (tid<256){
      float s=0.f;
      for(int t=tid;t<m;t+=256){
        float pv=pvs[(i+1)+t];
        float v=(t==0)?1.f:vcur[t]*scal;
        s+=pv*v;
      }
      red[tid]=s;
    }
    float sv=tree256(red,&bcv,tid);
    float c2=tau*tau*sv*0.5f;
    const float vz=1.f;
    float wR0=tau*pvs[i+1]-c2*vz;
    if (tid<256){
      float s2=0.f;
      if (tid==0){
        float vC=vcur[1]*scal;
        float wC=tau*pvs[(i+1)+1]-c2*vC;
        nxt[0]=pbs[(i+2)]-(vz*wC+wR0*vC);
      }
      for(int u=tid+1;u<mp;u+=256){
        float vC=vcur[1+u]*scal;
        float wC=tau*pvs[(i+1)+1+u]-c2*vC;
        float x=pbs[(i+2)+u]-(vz*wC+wR0*vC);
        nxt[u]=x;
        s2+=x*x;
      }
      red[tid]=s2;
    }
    float xn2=tree256(red,&bcv,tid);
    float alpha1=nxt[0];
    float beta1,tau1,scal1;
    if(xn2==0.f){ tau1=0.f; beta1=alpha1; scal1=0.f; }
    else { beta1=-copysignf(sqrtf(alpha1*alpha1+xn2),alpha1); tau1=(beta1-alpha1)/beta1; scal1=1.f/(alpha1-beta1); }
    if(tid==0){ evec[i+1]=beta1; tauv[i+1]=tau1; scalv[i+1]=scal1; }
    float* pvd=pvl[(i+1)&1];
    float* pbd=pbl[(i+2)&3];
    for(int r=i+1+wv; r<NN; r+=16){
      int tr=r-(i+1);
      float vR=(tr==0)?1.f:vcur[tr]*scal;
      float wR=tau*pvs[(i+1)+tr]-c2*vR;
      float* arow=A+(size_t)r*LDAe;
      if(lane==0) arow[i+1]=arow[i+1]-(vR*wR0+wR*vz);
      if(tr==0){
        for(int c=lane;c<mp;c+=64) arow[i+2+c]=nxt[c];
      } else {
        float acc=0.f;
        int ispub=(tr==1);
        for(int c=lane;c<mp;c+=64){
          float vC=vcur[1+c]*scal;
          float wC=tau*pvs[(i+1)+1+c]-c2*vC;
          float val=arow[i+2+c]-(vR*wC+wR*vC);
          arow[i+2+c]=val;
          float v1=(c==0)?1.f:nxt[c]*scal1;
          acc+=val*v1;
          if(ispub) pbd[(i+2)+c]=val;
        }
        for(int o=32;o;o>>=1) acc+=__shfl_down(acc,o,64);
        if(lane==0) pvd[r]=acc;
      }
    }
    __syncthreads();
    cur^=1; tau=tau1; scal=scal1;
  }
}
// endgame: iterations I0E..NN-2 entirely in LDS (121x121 trailing tile)
__global__ __launch_bounds__(256) void k_tend(float* __restrict__ A, float* __restrict__ evec,
    float* __restrict__ tauv, float* __restrict__ scalv){
  __shared__ float T[121][122];
  __shared__ float red[256];
  __shared__ float bct;
  __shared__ float pl[121];
  __shared__ float el[121], tl[121], sl[121];
  __shared__ float sh3[2];
  int tid=threadIdx.x;
  for(int e=tid;e<121*121;e+=256){ int r=e/121,c=e%121; T[r][c]=A[(size_t)(I0E+r)*LDAe + I0E+c]; }
  __syncthreads();
  for(int li=0; li<120; ++li){
    int m=120-li;
    float s=0.f;
    for(int t=tid;t<m-1;t+=256){ float x=T[li][li+2+t]; s+=x*x; }
    red[tid]=s;
    float xn2t=tree256(red,&bct,tid);
    if(tid==0){
      float alpha=T[li][li+1], xn2=xn2t;
      float beta,tau,scal;
      if(xn2==0.f){ tau=0.f; beta=alpha; scal=0.f; }
      else { beta=-copysignf(sqrtf(alpha*alpha+xn2),alpha); tau=(beta-alpha)/beta; scal=1.f/(alpha-beta); }
      el[li]=beta; tl[li]=tau; sl[li]=scal;
      sh3[0]=tau; sh3[1]=scal;
    }
    __syncthreads();
    float tau=sh3[0], scal=sh3[1];
    if(tid<m){
      float acc=0.f;
      for(int c=0;c<m;c++){
        float v=(c==0)?1.f:T[li][li+1+c]*scal;
        acc+=T[li+1+tid][li+1+c]*v;
      }
      pl[tid]=acc;
    }
    __syncthreads();
    s=0.f;
    for(int t=tid;t<m;t+=256){
      float v=(t==0)?1.f:T[li][li+1+t]*scal;
      s+=pl[t]*v;
    }
    red[tid]=s;
    float sv=tree256(red,&bct,tid);
    float c2=tau*tau*sv*0.5f;
    for(int e=tid;e<m*m;e+=256){
      int r=e/m, c=e%m;
      float vR=(r==0)?1.f:T[li][li+1+r]*scal;
      float vC=(c==0)?1.f:T[li][li+1+c]*scal;
      float wR=tau*pl[r]-c2*vR;
      float wC=tau*pl[c]-c2*vC;
      T[li+1+r][li+1+c]-=vR*wC+wR*vC;
    }
    __syncthreads();
  }
  for(int e=tid;e<121*121;e+=256){ int r=e/121,c=e%121; A[(size_t)(I0E+r)*LDAe + I0E+c]=T[r][c]; }
  for(int t=tid;t<120;t+=256){ evec[I0E+t]=el[t]; tauv[I0E+t]=tl[t]; scalv[I0E+t]=sl[t]; }
}

// ---------------- fused harvest + sstedc scale + cuts (1 block) ----------------
__global__ __launch_bounds__(256) void k_prep_ed(const float* __restrict__ A, float* __restrict__ D,
                                                 float* __restrict__ E, ETree t){
  __shared__ float red[256];
  int tid=threadIdx.x;
  for(int i=tid;i<NN;i+=256) D[i]=A[(size_t)i*LDAe+i];
  __syncthreads();
  float m=0.f;
  for(int i=tid;i<NN;i+=256) m=fmaxf(m,fabsf(D[i]));
  for(int i=tid;i<NN-1;i+=256) m=fmaxf(m,fabsf(E[i]));
  red[tid]=m; __syncthreads();
  for(int s=128;s;s>>=1){ if(tid<s) red[tid]=fmaxf(red[tid],red[tid+s]); __syncthreads(); }
  float mul=1.f/red[0];
  __syncthreads();
  for(int i=tid;i<NN;i+=256) D[i]*=mul;
  for(int i=tid;i<NN-1;i+=256) E[i]*=mul;
  __syncthreads();
  if (tid>0 && tid<t.cnt){
    int cut=t.st[tid];
    float ae=fabsf(E[cut-1]);
    D[cut-1]-=ae; D[cut]-=ae;
  }
}

// ---------------- ssteqr('I'), one WAVE per leaf, d/e AND z in LDS ----------------
__device__ void steqr1w(int n, float* d, float* e, float* z, int ldz, int lane){
  if (n<=1) return;
  const float eps=EPS32, eps2=EPS32*EPS32, safmin=SAFMIN32;
  float workc[32], works[32];
  int nmaxit=n*30, jtot=0;
  int l1=0;
  for(;;){
    if (l1>n-1) break;
    if (l1>0) e[l1-1]=0.f;
    int m;
    for(m=l1;m<n-1;m++){
      float tst=fabsf(e[m]);
      if (tst==0.f) break;
      if (tst<=(sqrtf(fabsf(d[m]))*sqrtf(fabsf(d[m+1])))*eps){ e[m]=0.f; break; }
    }
    int l=l1, lend=m, lsv=l, lendsv=lend;
    l1=m+1;
    if (lend==l) continue;
    float anorm=0.f;
    for(int i=l;i<=lend;i++) anorm=fmaxf(anorm,fabsf(d[i]));
    for(int i=l;i<lend;i++) anorm=fmaxf(anorm,fabsf(e[i]));
    if (anorm==0.f) continue;
    if (fabsf(d[lend])<fabsf(d[l])){ lend=lsv; l=lendsv; }
    float c,s,g,r,p,f,b,rt1,rt2;
    if (lend>l){
      for(;;){
        int mm;
        for(mm=l;mm<lend;mm++){
          float tst=e[mm]*e[mm];
          if (tst<=(eps2*fabsf(d[mm]))*fabsf(d[mm+1])+safmin) break;
        }
        if (mm<lend) e[mm]=0.f;
        p=d[l];
        if (mm==l){ d[l]=p; l++; if (l<=lend) continue; else break; }
        if (mm==l+1){
          slaev2(d[l],e[l],d[l+1],&rt1,&rt2,&c,&s);
          for(int row=lane;row<n;row+=64){
            float t1=z[(size_t)(l+1)*ldz+row];
            z[(size_t)(l+1)*ldz+row]=c*t1 - s*z[(size_t)l*ldz+row];
            z[(size_t)l*ldz+row]=s*t1 + c*z[(size_t)l*ldz+row];
          }
          d[l]=rt1; d[l+1]=rt2; e[l]=0.f;
          l+=2;
          if (l<=lend) continue; else break;
        }
        if (jtot==nmaxit) break;
        jtot++;
        g=(d[l+1]-p)/(2.f*e[l]);
        r=lapy2f(g,1.f);
        g=d[mm]-p+(e[l]/(g+copysignf(r,g)));
        s=1.f; c=1.f; p=0.f;
        for(int i=mm-1;i>=l;i--){
          f=s*e[i]; b=c*e[i];
          slartg(g,f,&c,&s,&r);
          if (i!=mm-1) e[i+1]=r;
          g=d[i+1]-p;
          r=(d[i]-g)*s+2.f*c*b;
          p=s*r;
          d[i+1]=g+p;
          g=c*r-b;
          workc[i-l]=c; works[i-l]=-s;
        }
        for(int j2=mm-1;j2>=l;j2--){
          float cc=workc[j2-l], ss2=works[j2-l];
          if (cc!=1.f||ss2!=0.f)
            for(int row=lane;row<n;row+=64){
              float t1=z[(size_t)(j2+1)*ldz+row];
              z[(size_t)(j2+1)*ldz+row]=cc*t1 - ss2*z[(size_t)j2*ldz+row];
              z[(size_t)j2*ldz+row]=ss2*t1 + cc*z[(size_t)j2*ldz+row];
            }
        }
        d[l]=d[l]-p;
        e[l]=g;
      }
    } else {
      for(;;){
        int mm;
        for(mm=l;mm>lend;mm--){
          float tst=e[mm-1]*e[mm-1];
          if (tst<=(eps2*fabsf(d[mm]))*fabsf(d[mm-1])+safmin) break;
        }
        if (mm>lend) e[mm-1]=0.f;
        p=d[l];
        if (mm==l){ d[l]=p; l--; if (l>=lend) continue; else break; }
        if (mm==l-1){
          slaev2(d[l-1],e[l-1],d[l],&rt1,&rt2,&c,&s);
          for(int row=lane;row<n;row+=64){
            float t1=z[(size_t)l*ldz+row];
            z[(size_t)l*ldz+row]=c*t1 - s*z[(size_t)(l-1)*ldz+row];
            z[(size_t)(l-1)*ldz+row]=s*t1 + c*z[(size_t)(l-1)*ldz+row];
          }
          d[l-1]=rt1; d[l]=rt2; e[l-1]=0.f;
          l-=2;
          if (l>=lend) continue; else break;
        }
        if (jtot==nmaxit) break;
        jtot++;
        g=(d[l-1]-p)/(2.f*e[l-1]);
        r=lapy2f(g,1.f);
        g=d[mm]-p+(e[l-1]/(g+copysignf(r,g)));
        s=1.f; c=1.f; p=0.f;
        for(int i=mm;i<=l-1;i++){
          f=s*e[i]; b=c*e[i];
          slartg(g,f,&c,&s,&r);
          if (i!=mm) e[i-1]=r;
          g=d[i]-p;
          r=(d[i+1]-g)*s+2.f*c*b;
          p=s*r;
          d[i]=g+p;
          g=c*r-b;
          workc[i-mm]=c; works[i-mm]=s;
        }
        for(int j2=mm;j2<=l-1;j2++){
          float cc=workc[j2-mm], ss2=works[j2-mm];
          if (cc!=1.f||ss2!=0.f)
            for(int row=lane;row<n;row+=64){
              float t1=z[(size_t)(j2+1)*ldz+row];
              z[(size_t)(j2+1)*ldz+row]=cc*t1 - ss2*z[(size_t)j2*ldz+row];
              z[(size_t)j2*ldz+row]=ss2*t1 + cc*z[(size_t)j2*ldz+row];
            }
        }
        d[l]=d[l]-p;
        e[l-1]=g;
      }
    }
  }
  for(int ii=1;ii<n;ii++){
    int i=ii-1,k=i; float pp=d[i];
    for(int j2=ii;j2<n;j2++) if (d[j2]<pp){k=j2;pp=d[j2];}
    if (k!=i){
      d[k]=d[i]; d[i]=pp;
      for(int row=lane;row<n;row+=64){
        float t1=z[(size_t)i*ldz+row];
        z[(size_t)i*ldz+row]=z[(size_t)k*ldz+row];
        z[(size_t)k*ldz+row]=t1;
      }
    }
  }
}
__global__ __launch_bounds__(64) void k_ed_leaves(float* D, float* E, float* QM, int* indxq, ETree t){
  int lf=blockIdx.x;
  if (lf>=t.cnt) return;
  int lane=threadIdx.x;
  int st=t.st[lf], n=t.sz[lf];
  __shared__ float dl[32], el[32];
  __shared__ float zloc[32][33];
  for(int i=lane;i<n;i+=64) dl[i]=D[st+i];
  for(int i=lane;i<n-1;i+=64) el[i]=E[st+i];
  for(int e=lane;e<n*n;e+=64){ int c=e/n, r=e%n; zloc[c][r]=(c==r)?1.f:0.f; }
  __syncthreads();
  steqr1w(n, dl, el, &zloc[0][0], 33, lane);
  __syncthreads();
  for(int i=lane;i<n;i+=64){ D[st+i]=dl[i]; indxq[st+i]=i; }
  for(int i=lane;i<n-1;i+=64) E[st+i]=el[i];
  for(int e=lane;e<n*n;e+=64){ int c=e/n, r=e%n; QM[(size_t)(st+c)*LDQ + st+r]=zloc[c][r]; }
}

// ---------------- batched slaed1/slaed2: formz + deflation in LDS ----------------
__global__ __launch_bounds__(256) void k_ed_deflate2(float* __restrict__ D, int* __restrict__ indxq,
    float* __restrict__ dlamda, float* __restrict__ w, float* __restrict__ dstage,
    int* __restrict__ colmap, int* __restrict__ cmtype, int* __restrict__ indxcg,
    int* __restrict__ rotp, int* __restrict__ rotn, float* __restrict__ rotc, float* __restrict__ rots,
    EDMeta* __restrict__ meta, const float* __restrict__ QM, const float* __restrict__ E, MergeLvl lv){
  int mid=blockIdx.x; if(mid>=lv.cnt) return;
  int st=lv.st[mid], n1=lv.n1[mid], n2=lv.n2[mid], n=n1+n2;
  int tid=threadIdx.x;
  __shared__ float zl[1152], dl_[1152], dlam[1152], wl[1152], ds2[1152];
  __shared__ int iq[1152], im[1152], ix[1152], ixp[1152], ict[1152], is2[1152];
  __shared__ float rv[256]; __shared__ int ri[256];
  __shared__ float srho; __shared__ int sK, snrot, searly, simax, sjmax;
  float rr=E[st+n1-1];
  if(tid==0) srho=fabsf(2.f*rr);
  for(int i=tid;i<n;i+=256){
    float v = (i<n1)? QM[(size_t)(st+i)*LDQ + st+n1-1] : QM[(size_t)(st+i)*LDQ + st+n1];
    if(rr<0.f && i>=n1) v=-v;
    zl[i]=v*0.70710678118654752440f;
    dl_[i]=D[st+i];
    int q=indxq[st+i]; if(i>=n1) q+=n1;
    iq[i]=q;
    ict[i]=(i<n1)?1:3;
  }
  __syncthreads();
  // argmax |z| (first-max-wins == serial scan)
  {
    float bv=-1.f; int bi=0;
    for(int i2=tid;i2<n;i2+=256){ float a=fabsf(zl[i2]); if(a>bv){bv=a;bi=i2;} }
    rv[tid]=bv; ri[tid]=bi; __syncthreads();
    for(int stp=128;stp;stp>>=1){
      if(tid<stp){ if(rv[tid+stp]>rv[tid]||(rv[tid+stp]==rv[tid]&&ri[tid+stp]<ri[tid])){rv[tid]=rv[tid+stp];ri[tid]=ri[tid+stp];} }
      __syncthreads();
    }
    if(tid==0) simax=ri[0];
    __syncthreads();
  }
  {
    float bv=-1.f; int bi=0;
    for(int i2=tid;i2<n;i2+=256){ float a=fabsf(dl_[i2]); if(a>bv){bv=a;bi=i2;} }
    rv[tid]=bv; ri[tid]=bi; __syncthreads();
    for(int stp=128;stp;stp>>=1){
      if(tid<stp){ if(rv[tid+stp]>rv[tid]||(rv[tid+stp]==rv[tid]&&ri[tid+stp]<ri[tid])){rv[tid]=rv[tid+stp];ri[tid]=ri[tid+stp];} }
      __syncthreads();
    }
    if(tid==0) sjmax=ri[0];
    __syncthreads();
  }
  if(tid==0){
    for(int i=0;i<n;i++) dlam[i]=dl_[iq[i]];
    lamrg0(n1,n2,dlam,1,1,im);
    for(int i=0;i<n;i++) ix[i]=iq[im[i]];
    float tol=8.f*EPS32*fmaxf(fabsf(dl_[sjmax]),fabsf(zl[simax]));
    float rho=srho;
    int K=0,nrot=0,early=0;
    if(rho*fabsf(zl[simax])<=tol){
      early=1;
      for(int i=0;i<n;i++){ int s2=ix[i]; im[i]=s2; iq[i]=2; ds2[i]=dl_[s2]; is2[i]=i; }
    } else {
      int K2=n; int pj=0; int j=0;
      for(;j<n;j++){ int nj=ix[j]; if(rho*fabsf(zl[nj])<=tol){K2--;ict[nj]=4;ixp[K2]=nj;} else {pj=nj;break;} }
      for(j=j+1;;j++){
        if(j>=n) break;
        int nj=ix[j];
        if(rho*fabsf(zl[nj])<=tol){K2--;ict[nj]=4;ixp[K2]=nj;}
        else {
          float s=zl[pj], c=zl[nj];
          float tau2=lapy2f(c,s);
          float t=dl_[nj]-dl_[pj];
          c=c/tau2; s=-s/tau2;
          if(fabsf(t*c*s)<=tol){
            zl[nj]=tau2; zl[pj]=0.f;
            if(ict[nj]!=ict[pj]) ict[nj]=2;
            ict[pj]=4;
            rotp[st+nrot]=pj; rotn[st+nrot]=nj; rotc[st+nrot]=c; rots[st+nrot]=s; nrot++;
            float t2=dl_[pj]*c*c + dl_[nj]*s*s;
            dl_[nj]=dl_[pj]*s*s + dl_[nj]*c*c;
            dl_[pj]=t2;
            K2--;
            int i2=1;
            for(;;){
              if(K2+i2<=n-1 && dl_[pj]<dl_[ixp[K2+i2]]){ ixp[K2+i2-1]=ixp[K2+i2]; ixp[K2+i2]=pj; i2++; }
              else { ixp[K2+i2-1]=pj; break; }
            }
            pj=nj;
          } else {
            dlam[K]=dl_[pj]; wl[K]=zl[pj]; ixp[K]=pj; K++;
            pj=nj;
          }
        }
      }
      dlam[K]=dl_[pj]; wl[K]=zl[pj]; ixp[K]=pj; K++;
      int ctot[5]={0,0,0,0,0};
      for(int i=0;i<n;i++) ctot[ict[i]]++;
      int psm[5]; psm[1]=0; psm[2]=ctot[1]; psm[3]=psm[2]+ctot[2]; psm[4]=psm[3]+ctot[3];
      for(int jj=0;jj<n;jj++){
        int js=ixp[jj]; int ct=ict[js];
        int slot=psm[ct]++;
        im[slot]=js; is2[slot]=jj; ds2[slot]=dl_[js]; iq[slot]=ct;
      }
    }
    sK=K; snrot=nrot; searly=early;
  }
  __syncthreads();
  int K=sK;
  for(int i=tid;i<n;i+=256){
    colmap[st+i]=im[i];
    cmtype[st+i]=iq[i];
    indxcg[st+i]=is2[i];
    dstage[st+i]=ds2[i];
    if(i<K){ dlamda[st+i]=dlam[i]; w[st+i]=wl[i]; }
  }
  if(tid==0){ meta[mid].K=K; meta[mid].nrot=snrot; meta[mid].early=searly; meta[mid].rho=srho; }
}

// batched Givens application: row-parallel, per-thread sequential over rotations
__global__ __launch_bounds__(256) void k_ed_rot2(float* __restrict__ QM, const int* __restrict__ rotp,
    const int* __restrict__ rotn, const float* __restrict__ rotc, const float* __restrict__ rots,
    const EDMeta* __restrict__ meta, MergeLvl lv){
  int mid=blockIdx.y; if(mid>=lv.cnt) return;
  int st=lv.st[mid], n=lv.n1[mid]+lv.n2[mid];
  int row=blockIdx.x*256+threadIdx.x;
  if(row>=n) return;
  int nr=meta[mid].nrot;
  for(int k=0;k<nr;k++){
    size_t ip=(size_t)(st+rotp[st+k])*LDQ+st+row;
    size_t iq2=(size_t)(st+rotn[st+k])*LDQ+st+row;
    float c=rotc[st+k], s=rots[st+k];
    float x=QM[ip], y=QM[iq2];
    QM[ip]=c*x+s*y;
    QM[iq2]=c*y-s*x;
  }
}
// batched gather of grouped columns into Q2 (zero-padded per column type)
__global__ __launch_bounds__(256) void k_ed_permute(const float* __restrict__ QM, float* __restrict__ Q2,
    const int* __restrict__ colmap, const int* __restrict__ cmtype, MergeLvl lv){
  int mid=blockIdx.z; if(mid>=lv.cnt) return;
  int st=lv.st[mid], n1=lv.n1[mid], n=n1+lv.n2[mid];
  int row=blockIdx.x*256+threadIdx.x;
  int slot=blockIdx.y;
  if(row>=n||slot>=n) return;
  int src=colmap[st+slot], ct=cmtype[st+slot];
  float v=QM[(size_t)(st+src)*LDQ + st+row];
  if(ct==1&&row>=n1) v=0.f;
  else if(ct==3&&row<n1) v=0.f;
  Q2[(size_t)(st+slot)*LDQ + st+row]=v;
}

// ---------------- slaed4-style secular root (f64, safeguarded) ----------------
__device__ void ed4_general(int K, int j, const float* __restrict__ dl, const float* __restrict__ wv,
                            double rho, float* __restrict__ dcol, float* __restrict__ lamout){
  bool last=(j==K-1);
  bool orgati=true; double org, lo, hi;
  int i0,i1;
  if (!last){
    i0=j; i1=j+1;
    double dj=(double)dl[j];
    double del=(double)dl[j+1]-dj, mid=0.5*del;
    double g0=1.0/rho;
    for(int i=0;i<K;i++){ double de=((double)dl[i]-dj)-mid; double zi=(double)wv[i]; g0+=zi*zi/de; }
    if (g0>0.0){ orgati=true; org=dj; lo=0.0; hi=mid; }
    else { orgati=false; org=(double)dl[j+1]; lo=-mid; hi=0.0; }
  } else {
    i0=K-2; i1=K-1;
    org=(double)dl[K-1];
    double mid=0.5*rho;
    double g0=1.0/rho;
    for(int i=0;i<K;i++){ double de=((double)dl[i]-org)-mid; double zi=(double)wv[i]; g0+=zi*zi/de; }
    if (g0<=0.0){ lo=mid; hi=rho; } else { lo=0.0; hi=mid; }
  }
  double tau=0.5*(lo+hi);
  for(int it=0; it<60; ++it){
    double g=1.0/rho, gpsi=0.0, gphi=0.0;
    for(int i=0;i<K;i++){
      double de=((double)dl[i]-org)-tau;
      double zi=(double)wv[i];
      double t=zi/de;
      g+=zi*t;
      if (i<=i0) gpsi+=t*t; else gphi+=t*t;
    }
    double gp=gpsi+gphi;
    if (g==0.0) break;
    if (g<0.0){ if (tau>lo) lo=tau; } else { if (tau<hi) hi=tau; }
    double dI=((double)dl[i0]-org)-tau, dIP=((double)dl[i1]-org)-tau;
    double c2,A,B,eta;
    if (!last){
      double zi0=(double)wv[i0], zi1=(double)wv[i1];
      if (orgati){ double t1=zi0/dI; c2=g - dIP*gp - ((double)dl[i0]-(double)dl[i1])*t1*t1; }
      else { double t1=zi1/dIP; c2=g - dI*gp - ((double)dl[i1]-(double)dl[i0])*t1*t1; }
      A=(dI+dIP)*g - dI*dIP*gp;
      B=dI*dIP*g;
      if (c2==0.0){
        if (A==0.0){
          if (orgati) A=zi0*zi0+dIP*dIP*gp;
          else A=zi1*zi1+dI*dI*gp;
        }
        eta=B/A;
      } else if (A<=0.0) eta=(A-sqrt(fabs(A*A-4.0*B*c2)))/(2.0*c2);
      else eta=2.0*B/(A+sqrt(fabs(A*A-4.0*B*c2)));
    } else {
      c2=g - dI*gpsi - dIP*gphi;
      if (c2<0.0) c2=fabs(c2);
      A=(dI+dIP)*g - dI*dIP*gp;
      B=dI*dIP*g;
      if (c2==0.0) eta=hi-tau;
      else if (A>=0.0) eta=(A+sqrt(fabs(A*A-4.0*B*c2)))/(2.0*c2);
      else eta=2.0*B/(A-sqrt(fabs(A*A-4.0*B*c2)));
    }
    if (g*eta>=0.0) eta=-g/gp;
    double tn=tau+eta;
    if (!(tn>lo && tn<hi)) tn=0.5*(lo+hi);
    double ch=fabs(tn-tau);
    tau=tn;
    if (ch<=2.220446049250313e-16*(fabs(org)+fabs(tau))) break;
  }
  for(int i=0;i<K;i++) dcol[i]=(float)(((double)dl[i]-org)-tau);
  *lamout=(float)(org+tau);
}

__global__ __launch_bounds__(64) void k_ed_secular(const float* __restrict__ dlamda, const float* __restrict__ w,
    const EDMeta* __restrict__ meta, float* __restrict__ D_, float* __restrict__ DC, MergeLvl lv){
  int mid=blockIdx.y; if(mid>=lv.cnt) return;
  int st=lv.st[mid];
  int K=meta[mid].K;
  int j=blockIdx.x*64+threadIdx.x;
  if (j>=K) return;
  const float* dl=dlamda+st;
  const float* wv=w+st;
  double rho=(double)meta[mid].rho;
  float* dcol=DC+(size_t)(st+j)*LDD;
  if (K==1){
    double lam=(double)dl[0]+rho*(double)wv[0]*(double)wv[0];
    dcol[0]=1.f; D_[st]=(float)lam;
    return;
  }
  if (K==2){
    double d1=(double)dl[0], d2=(double)dl[1], z1=(double)wv[0], z2=(double)wv[1];
    double del=d2-d1, tau, lam, v0, v1;
    if (j==0){
      double ww=1.0+2.0*rho*(z2*z2-z1*z1)/del;
      if (ww>0.0){
        double bq=del+rho*(z1*z1+z2*z2), cq=rho*z1*z1*del;
        tau=2.0*cq/(bq+sqrt(fabs(bq*bq-4.0*cq)));
        lam=d1+tau; v0=-z1/tau; v1=z2/(del-tau);
      } else {
        double bq=-del+rho*(z1*z1+z2*z2), cq=rho*z2*z2*del;
        tau=(bq>0.0)? -2.0*cq/(bq+sqrt(bq*bq+4.0*cq)) : (bq-sqrt(bq*bq+4.0*cq))*0.5;
        lam=d2+tau; v0=-z1/(del+tau); v1=-z2/tau;
      }
    } else {
      double bq=-del+rho*(z1*z1+z2*z2), cq=rho*z2*z2*del;
      tau=(bq>0.0)? (bq+sqrt(bq*bq+4.0*cq))*0.5 : 2.0*cq/(-bq+sqrt(bq*bq+4.0*cq));
      lam=d2+tau; v0=-z1/(del+tau); v1=-z2/tau;
    }
    double nr=sqrt(v0*v0+v1*v1);
    dcol[0]=(float)(v0/nr); dcol[1]=(float)(v1/nr);
    D_[st+j]=(float)lam;
    return;
  }
  float lam;
  ed4_general(K, j, dl, wv, rho, dcol, &lam);
  D_[st+j]=lam;
}

__global__ __launch_bounds__(64) void k_ed_lowner(const float* __restrict__ dlamda, float* __restrict__ w,
    const float* __restrict__ DC, const EDMeta* __restrict__ meta, MergeLvl lv){
  int mid=blockIdx.y; if(mid>=lv.cnt) return;
  int st=lv.st[mid];
  int K=meta[mid].K; if (K<=2) return;
  int i=blockIdx.x*64+threadIdx.x; if (i>=K) return;
  const float* dl=dlamda+st;
  double p=(double)DC[(size_t)(st+i)*LDD+i];
  double di=(double)dl[i];
  for(int j2=0;j2<K;j2++){
    if (j2==i) continue;
    p *= (double)DC[(size_t)(st+j2)*LDD+i]/(di-(double)dl[j2]);
  }
  float val=sqrtf(fmaxf(-(float)p,0.f));
  w[st+i]=copysignf(val,w[st+i]);
}
__global__ __launch_bounds__(256) void k_ed_vecs(const float* __restrict__ w, float* __restrict__ DC,
    const int* __restrict__ indxcg, const EDMeta* __restrict__ meta, MergeLvl lv){
  int mid=blockIdx.y; if(mid>=lv.cnt) return;
  int st=lv.st[mid];
  int K=meta[mid].K;
  int j=blockIdx.x; if (j>=K) return;
  float* dcol=DC+(size_t)(st+j)*LDD;
  const int* indxc=indxcg+st;
  int tid=threadIdx.x;
  if (K==1){ if (tid==0) dcol[0]=1.f; return; }
  if (K==2){
    if (tid==0){
      float a=dcol[0], b=dcol[1];
      float o0=(indxc[0]==0)?a:b;
      float o1=(indxc[1]==0)?a:b;
      dcol[0]=o0; dcol[1]=o1;
    }
    return;
  }
  __shared__ float sv[1152];
  __shared__ double red[256];
  double ss=0.0;
  for(int i=tid;i<K;i+=256){
    float s=w[st+i]/dcol[i];
    sv[i]=s;
    ss+=(double)s*(double)s;
  }
  red[tid]=ss; __syncthreads();
  for(int st2=128;st2;st2>>=1){ if(tid<st2) red[tid]+=red[tid+st2]; __syncthreads(); }
  float tempf=(float)sqrt(red[0]);
  __syncthreads();
  for(int i=tid;i<K;i+=256) dcol[i]=sv[indxc[i]]/tempf;
}
// Qnew(:,0..K-1) = Q2 * DC ; cols K..n-1 copied from Q2 (fused copyback)
__global__ __launch_bounds__(256) void k_gemm_cm2(const float* __restrict__ Q2, const float* __restrict__ DC,
    float* __restrict__ QM, const EDMeta* __restrict__ meta, MergeLvl lv){
  int mid=blockIdx.z; if(mid>=lv.cnt) return;
  int st=lv.st[mid], n=lv.n1[mid]+lv.n2[mid];
  int K=meta[mid].K;
  int br=blockIdx.x*64, bj=blockIdx.y*64;
  if (br>=n||bj>=n) return;
  int tid=threadIdx.x, tr=tid/16, tc=tid%16;
  if (bj>=K){
    for(int i=0;i<4;i++){ int r=br+tr*4+i; if(r>=n)continue;
      for(int j2=0;j2<4;j2++){ int cc=bj+tc*4+j2; if(cc>=n)continue;
        QM[(size_t)(st+cc)*LDQ+st+r]=Q2[(size_t)(st+cc)*LDQ+st+r]; } }
    return;
  }
  __shared__ float As[16][65], Bs[16][65];
  float acc[4][4]={};
  for(int k0=0;k0<K;k0+=16){
    for(int l=0;l<4;l++){
      int e2=tid+l*256;
      int rr=e2&63, ii=e2>>6;
      float av=0.f;
      if (br+rr<n && k0+ii<K) av=Q2[(size_t)(st+k0+ii)*LDQ + st+br+rr];
      As[ii][rr]=av;
      int bi=e2&15, bj2=e2>>4;
      float bv=0.f;
      if (k0+bi<K && bj+bj2<n) bv=DC[(size_t)(st+bj+bj2)*LDD + k0+bi];
      Bs[bi][bj2]=bv;
    }
    __syncthreads();
    #pragma unroll
    for(int kk=0;kk<16;kk++){
      float ar[4],br2[4];
      #pragma unroll
      for(int i=0;i<4;i++) ar[i]=As[kk][tr*4+i];
      #pragma unroll
      for(int j2=0;j2<4;j2++) br2[j2]=Bs[kk][tc*4+j2];
      #pragma unroll
      for(int i=0;i<4;i++)
        #pragma unroll
        for(int j2=0;j2<4;j2++) acc[i][j2]+=ar[i]*br2[j2];
    }
    __syncthreads();
  }
  for(int i=0;i<4;i++){
    int r=br+tr*4+i; if (r>=n) continue;
    for(int j2=0;j2<4;j2++){
      int cc=bj+tc*4+j2; if (cc>=n) continue;
      if (cc<K) QM[(size_t)(st+cc)*LDQ + st+r]=acc[i][j2];
      else      QM[(size_t)(st+cc)*LDQ + st+r]=Q2[(size_t)(st+cc)*LDQ + st+r];
    }
  }
}
// post: D tail restore + merge (lamrg0 on LDS)
__global__ __launch_bounds__(256) void k_ed_post(float* __restrict__ D, const float* __restrict__ dstage,
    int* __restrict__ indxq, const EDMeta* __restrict__ meta, MergeLvl lv){
  int mid=blockIdx.x; if(mid>=lv.cnt) return;
  int st=lv.st[mid], n=lv.n1[mid]+lv.n2[mid];
  int K=meta[mid].K;
  int tid=threadIdx.x;
  __shared__ float dl[1152];
  __shared__ int iq[1152];
  float* Ds=D+st;
  for(int i=tid;i<n;i+=256){
    float v = (i<K)? Ds[i] : dstage[st+i];
    dl[i]=v;
    if (i>=K) Ds[i]=v;
  }
  __syncthreads();
  if (meta[mid].early){
    for(int i=tid;i<n;i+=256) indxq[st+i]=i;
    return;
  }
  if (tid==0) lamrg0(K, n-K, dl, 1, -1, iq);
  __syncthreads();
  for(int i=tid;i<n;i+=256) indxq[st+i]=iq[i];
}
// final: pull ascending columns 1..512 (drop trivial eigvec 0)
__global__ __launch_bounds__(256) void k_ed_gather(const float* __restrict__ QM, const int* __restrict__ indxq,
    float* __restrict__ Vt){
  int row=blockIdx.x*256+threadIdx.x;
  int vec=blockIdx.y;
  if (row>=NN) return;
  int src=indxq[vec+1];
  Vt[(size_t)vec*NN+row]=QM[(size_t)src*LDQ+row];
}

// ---------------- back-transform V = H0 H1 ... V_tri (v from A rows + scalv) ----------------
__global__ __launch_bounds__(128) void k_backt(const float* __restrict__ A, const float* __restrict__ tauv,
                                               const float* __restrict__ scalv, float* __restrict__ Vt){
  __shared__ float cols[2][1168];
  __shared__ float tl[1152], sl[1152];
  int wv=threadIdx.x>>6, lane=threadIdx.x&63;
  int vec=blockIdx.x*2+wv;
  float* col=Vt+(size_t)vec*NN;
  float* cl=cols[wv];
  for(int t=threadIdx.x;t<NN;t+=128){ tl[t]=tauv[t]; sl[t]=scalv[t]; }
  for(int t=lane;t<NN;t+=64) cl[t]=col[t];
  __syncthreads();
  for(int i=NN-2;i>=0;i--){
    float tau=tl[i];
    if (tau==0.f) continue;
    int m=NN-1-i;
    float scal=sl[i];
    const float* rowi=A+(size_t)i*LDAe;
    float s=0.f;
    for(int t=lane;t<m;t+=64){
      float v=(t==0)?1.f:rowi[i+1+t]*scal;
      s+=v*cl[i+1+t];
    }
    for(int o=32;o;o>>=1) s+=__shfl_down(s,o,64);
    s=__shfl(s,0,64);
    s*=tau;
    for(int t=lane;t<m;t+=64){
      float v=(t==0)?1.f:rowi[i+1+t]*scal;
      cl[i+1+t]-=s*v;
    }
  }
  for(int t=lane;t<NN;t+=64) col[t]=cl[t];
}

// ---------------- transpose Vt[512][1147] -> pe[1147][512] ----------------
__global__ __launch_bounds__(256) void k_transpose(const float* __restrict__ in, float* __restrict__ outp){
  __shared__ float tile[32][33];
  int c0=blockIdx.x*32, r0=blockIdx.y*32;
  int tx=threadIdx.x%32, ty=threadIdx.x/32;
  for(int s=0;s<32;s+=8){
    int r=r0+ty+s, c=c0+tx;
    tile[ty+s][tx]=(r<512 && c<NN)? in[(size_t)r*NN+c] : 0.f;
  }
  __syncthreads();
  for(int s=0;s<32;s+=8){
    int r=c0+ty+s, c=r0+tx;
    if (r<NN && c<512) outp[(size_t)r*512+c]=tile[tx][ty+s];
  }
}

// ---------------- generic f32 GEMM: C = A@B (+bias)(+add)(relu) ----------------
__global__ __launch_bounds__(256) void k_gemm(const float* __restrict__ A, const float* __restrict__ B,
    const float* __restrict__ bias, const float* __restrict__ add, float* __restrict__ C,
    int M, int Nc, int K, int relu){
  __shared__ float As[16][65];
  __shared__ float Bs[16][65];
  int bm=blockIdx.y*64, bn=blockIdx.x*64;
  int tid=threadIdx.x;
  int tr=tid/16, tc=tid%16;
  float acc[4][4]={};
  for(int k0=0;k0<K;k0+=16){
    for(int l=0;l<4;l++){
      int e2=tid+l*256;
      int m_=e2/16, kk=e2%16;
      float av=0.f;
      if (bm+m_<M && k0+kk<K) av=A[(size_t)(bm+m_)*K + k0+kk];
      As[kk][m_]=av;
      int k2=e2/64, n2=e2%64;
      float bv=0.f;
      if (k0+k2<K && bn+n2<Nc) bv=B[(size_t)(k0+k2)*Nc + bn+n2];
      Bs[k2][n2]=bv;
    }
    __syncthreads();
    for(int kk=0;kk<16;kk++){
      float ar[4], br[4];
      #pragma unroll
      for(int i=0;i<4;i++) ar[i]=As[kk][tr*4+i];
      #pragma unroll
      for(int j=0;j<4;j++) br[j]=Bs[kk][tc*4+j];
      #pragma unroll
      for(int i=0;i<4;i++)
        #pragma unroll
        for(int j=0;j<4;j++) acc[i][j]+=ar[i]*br[j];
    }
    __syncthreads();
  }
  for(int i=0;i<4;i++){
    int r=bm+tr*4+i;
    if (r>=M) continue;
    for(int j=0;j<4;j++){
      int c=bn+tc*4+j;
      if (c>=Nc) continue;
      float x=acc[i][j];
      if (bias) x+=bias[c];
      if (add)  x+=add[(size_t)r*Nc+c];
      if (relu) x=fmaxf(x,0.f);
      C[(size_t)r*Nc+c]=x;
    }
  }
}

// ---------------- fused 3-output GEMM (QKV): per-output arithmetic identical to k_gemm ----------------
__global__ __launch_bounds__(256) void k_gemm3(const float* __restrict__ A,
    const float* __restrict__ B0, const float* __restrict__ B1, const float* __restrict__ B2,
    float* __restrict__ C0, float* __restrict__ C1, float* __restrict__ C2,
    int M, int Nc, int K){
  __shared__ float As[16][65];
  __shared__ float Bs[3][16][65];
  int bm=blockIdx.y*64, bn=blockIdx.x*64;
  int tid=threadIdx.x;
  int tr=tid/16, tc=tid%16;
  float acc[3][4][4]={};
  const float* Bp0=B0; const float* Bp1=B1; const float* Bp2=B2;
  for(int k0=0;k0<K;k0+=16){
    for(int l=0;l<4;l++){
      int e2=tid+l*256;
      int m_=e2/16, kk=e2%16;
      float av=0.f;
      if (bm+m_<M && k0+kk<K) av=A[(size_t)(bm+m_)*K + k0+kk];
      As[kk][m_]=av;
      int k2=e2/64, n2=e2%64;
      bool ok=(k0+k2<K && bn+n2<Nc);
      size_t bidx=(size_t)(k0+k2)*Nc + bn+n2;
      Bs[0][k2][n2]= ok? Bp0[bidx]:0.f;
      Bs[1][k2][n2]= ok? Bp1[bidx]:0.f;
      Bs[2][k2][n2]= ok? Bp2[bidx]:0.f;
    }
    __syncthreads();
    for(int kk=0;kk<16;kk++){
      float ar[4];
      #pragma unroll
      for(int i=0;i<4;i++) ar[i]=As[kk][tr*4+i];
      #pragma unroll
      for(int q=0;q<3;q++){
        float br[4];
        #pragma unroll
        for(int j=0;j<4;j++) br[j]=Bs[q][kk][tc*4+j];
        #pragma unroll
        for(int i=0;i<4;i++)
          #pragma unroll
          for(int j=0;j<4;j++) acc[q][i][j]+=ar[i]*br[j];
      }
    }
    __syncthreads();
  }
  for(int i=0;i<4;i++){
    int r=bm+tr*4+i;
    if (r>=M) continue;
    for(int j=0;j<4;j++){
      int c=bn+tc*4+j;
      if (c>=Nc) continue;
      C0[(size_t)r*Nc+c]=acc[0][i][j];
      C1[(size_t)r*Nc+c]=acc[1][i][j];
      C2[(size_t)r*Nc+c]=acc[2][i][j];
    }
  }
}

// ---------------- LayerNorm(x+y) over 512 ----------------
__global__ __launch_bounds__(256) void k_lnadd(const float* __restrict__ x, const float* __restrict__ y,
                                               float* __restrict__ out){
  int row=blockIdx.x; int tid=threadIdx.x;
  __shared__ float red[256];
  size_t base=(size_t)row*HID;
  float v0=x[base+tid]+y[base+tid];
  float v1=x[base+256+tid]+y[base+256+tid];
  red[tid]=v0+v1; __syncthreads();
  for(int st=128;st;st>>=1){ if(tid<st) red[tid]+=red[tid+st]; __syncthreads(); }
  float mean=red[0]*(1.f/512.f);
  __syncthreads();
  float d0=v0-mean, d1=v1-mean;
  red[tid]=d0*d0+d1*d1; __syncthreads();
  for(int st=128;st;st>>=1){ if(tid<st) red[tid]+=red[tid+st]; __syncthreads(); }
  float r=rsqrtf(red[0]*(1.f/512.f)+1e-5f);
  out[base+tid]=d0*r;
  out[base+256+tid]=d1*r;
}

// ---------------- edge-path rank-1 collapse ----------------
__global__ __launch_bounds__(256) void k_prep_uw(const float* __restrict__ We, const float* __restrict__ be,
    const float* __restrict__ We1, float* __restrict__ u, float* __restrict__ w1){
  int c=blockIdx.x*256+threadIdx.x;
  if (c>=HID) return;
  float a=0.f,b=0.f;
  for(int f=0;f<HID;f++){ float m=We1[(size_t)f*HID+c]; a+=We[f]*m; b+=be[f]*m; }
  u[c]=a; w1[c]=b;
}

// ---------------- per-edge logits ----------------
__global__ __launch_bounds__(256) void k_elogits(const float* __restrict__ q, const float* __restrict__ kk,
    const int* __restrict__ src, const int* __restrict__ dst, const float* __restrict__ ew,
    const float* __restrict__ uu, const float* __restrict__ ww, float* __restrict__ logit, int P, int useep){
  int gw=(blockIdx.x*256+threadIdx.x)>>6;
  int lane=threadIdx.x&63;
  if (gw>=P) return;
  int s=src[gw], d=dst[gw];
  const float* kr=kk+(size_t)s*HID;
  const float* qr=q+(size_t)d*HID;
  float a1[8], a2[8];
  #pragma unroll
  for(int j=0;j<8;j++){
    int c=j*64+lane;
    float prod=kr[c]*qr[c];
    if (useep){ a1[j]=prod*uu[c]; a2[j]=prod*ww[c]; }
    else { a1[j]=prod; a2[j]=0.f; }
  }
  #pragma unroll
  for(int o=32;o;o>>=1){
    #pragma unroll
    for(int j=0;j<8;j++){ a1[j]+=__shfl_down(a1[j],o,64); a2[j]+=__shfl_down(a2[j],o,64); }
  }
  if (lane==0){
    float w0 = useep? ew[gw] : 0.f;
    #pragma unroll
    for(int j=0;j<8;j++){
      float lg = useep ? 0.125f*(w0*a1[j]+a2[j]) : 0.125f*a1[j];
      logit[(size_t)gw*8+j]=lg;
    }
  }
}

// ---------------- deterministic CSR by dst ----------------
__global__ __launch_bounds__(256) void k_count(const int* __restrict__ dst, int* __restrict__ cnt, int P){
  int p=blockIdx.x*256+threadIdx.x;
  if (p<P) atomicAdd(&cnt[dst[p]],1);
}
// scan on LDS (single-thread integer scan at LDS latency; exact)
__global__ __launch_bounds__(256) void k_scan(const int* __restrict__ cnt, int* __restrict__ iptr){
  __shared__ int c[NN+1];
  int tid=threadIdx.x;
  for(int i=tid;i<NN;i+=256) c[i]=cnt[i];
  __syncthreads();
  if (tid==0){
    int s=0;
    for(int n=0;n<NN;n++){ int t=c[n]; c[n]=s; s+=t; }
    c[NN]=s;
  }
  __syncthreads();
  for(int i=tid;i<=NN;i+=256) iptr[i]=c[i];
}
__global__ __launch_bounds__(256) void k_fill(const int* __restrict__ dst, const int* __restrict__ iptr,
                                              int* __restrict__ iidx, int P){
  int n=blockIdx.x; int tid=threadIdx.x;
  int lane=tid&63, wv=tid>>6;
  __shared__ int wb[4]; __shared__ int scnt;
  if (tid==0) scnt=iptr[n];
  __syncthreads();
  for(int base=0;base<P;base+=256){
    int p=base+tid;
    bool f=(p<P)&&(dst[p]==n);
    unsigned long long m=__ballot(f);
    if (lane==0) wb[wv]=__popcll(m);
    __syncthreads();
    int off=0;
    #pragma unroll
    for(int i=0;i<4;i++) if (i<wv) off+=wb[i];
    if (f){
      int pre=__popcll(m & ((1ull<<lane)-1ull));
      iidx[scnt+off+pre]=p;
    }
    int tot=wb[0]+wb[1]+wb[2]+wb[3];
    __syncthreads();
    if (tid==0) scnt+=tot;
    __syncthreads();
  }
}

// ---------------- per-dst segment softmax ----------------
__global__ __launch_bounds__(256) void k_softmax(const float* __restrict__ logit, const int* __restrict__ iptr,
    const int* __restrict__ iidx, float* __restrict__ wght){
  int n=blockIdx.x; int tid=threadIdx.x;
  int beg=iptr[n], end=iptr[n+1];
  if (beg==end) return;
  __shared__ float red[256];
  __shared__ float smax[8], sden[8];
  float mx[8];
  #pragma unroll
  for(int h=0;h<8;h++) mx[h]=-1e30f;
  for(int t=beg+tid;t<end;t+=256){
    int e=iidx[t];
    #pragma unroll
    for(int h=0;h<8;h++) mx[h]=fmaxf(mx[h],logit[(size_t)e*8+h]);
  }
  for(int h=0;h<8;h++){
    red[tid]=mx[h]; __syncthreads();
    for(int st=128;st;st>>=1){ if(tid<st) red[tid]=fmaxf(red[tid],red[tid+st]); __syncthreads(); }
    if (tid==0) smax[h]=red[0];
    __syncthreads();
  }
  float sm[8];
  #pragma unroll
  for(int h=0;h<8;h++) sm[h]=0.f;
  for(int t=beg+tid;t<end;t+=256){
    int e=iidx[t];
    #pragma unroll
    for(int h=0;h<8;h++) sm[h]+=expf(logit[(size_t)e*8+h]-smax[h]);
  }
  for(int h=0;h<8;h++){
    red[tid]=sm[h]; __syncthreads();
    for(int st=128;st;st>>=1){ if(tid<st) red[tid]+=red[tid+st]; __syncthreads(); }
    if (tid==0) sden[h]=red[0];
    __syncthreads();
  }
  for(int t=beg+tid;t<end;t+=256){
    int e=iidx[t];
    #pragma unroll
    for(int h=0;h<8;h++) wght[(size_t)e*8+h]=expf(logit[(size_t)e*8+h]-smax[h])/(sden[h]+1e-9f);
  }
}

// ---------------- weighted aggregation per dst node ----------------
__global__ __launch_bounds__(512) void k_agg(const float* __restrict__ wght, const float* __restrict__ vv,
    const int* __restrict__ src, const int* __restrict__ iptr, const int* __restrict__ iidx,
    float* __restrict__ agg){
  int n=blockIdx.x; int c=threadIdx.x; int h=c>>6;
  int beg=iptr[n], end=iptr[n+1];
  float acc=0.f;
  for(int t=beg;t<end;++t){
    int e=iidx[t];
    acc += wght[(size_t)e*8+h]*vv[(size_t)src[e]*HID+c];
  }
  agg[(size_t)n*HID+c]=acc;
}

// =======================================================================
extern "C" void kernel_launch(void* const* d_in, const int* in_sizes, int n_in,
                              void* d_out, int out_size, void* d_ws, size_t ws_size,
                              hipStream_t stream){
  const float* H      = (const float*)d_in[0];
  const float* edge_w = (const float*)d_in[1];
  const int*   esrc   = (const int*)d_in[2];
  const int*   edst   = (const int*)d_in[3];
  const float* W_lin  = (const float*)d_in[4];
  const float* b_lin  = (const float*)d_in[5];
  const float* W_e    = (const float*)d_in[6];
  const float* b_e    = (const float*)d_in[7];
  const float* W_h    = (const float*)d_in[8];
  const float* b_h    = (const float*)d_in[9];
  const float* W_lap  = (const float*)d_in[10];
  const float* b_lap  = (const float*)d_in[11];
  const float* Wq1    = (const float*)d_in[12];
  const float* Wk1    = (const float*)d_in[13];
  const float* Wv1    = (const float*)d_in[14];
  const float* We1    = (const float*)d_in[15];
  const float* Wo1    = (const float*)d_in[16];
  const float* Wf1a   = (const float*)d_in[18];
  const float* Wf1b   = (const float*)d_in[19];
  const float* Wq2    = (const float*)d_in[22];
  const float* Wk2    = (const float*)d_in[23];
  const float* Wv2    = (const float*)d_in[24];
  const float* Wo2    = (const float*)d_in[25];
  const float* Wf2a   = (const float*)d_in[26];
  const float* Wf2b   = (const float*)d_in[27];
  const int P = in_sizes[1];
  float* out = (float*)d_out;

  // ---- workspace: fully disjoint explicit layout (~21.6 MB) ----
  char* base=(char*)d_ws;
  size_t off=0;
  auto AF=[&](size_t n)->float*{ float* r=(float*)(base+off); off+=((n*4+255)/256)*256; return r; };
  auto AI=[&](size_t n)->int*{ int* r=(int*)(base+off); off+=((n*4+255)/256)*256; return r; };
  const size_t SLOT=(size_t)NN*HID;           // 587,264 floats
  float* A   = AF((size_t)NN*LDAe);           // 1,321,344 floats
  float* QM  = AF((size_t)LDQ*NN);            // 1,321,344
  float* Q2  = AF((size_t)LDQ*NN);            // 1,321,344
  float* DC  = AF((size_t)LDD*LDD);           // 1,315,609
  float* dvec  = AF(1280);
  float* evec  = AF(1280);
  float* tauv  = AF(1280);
  float* scalv = AF(1280);
  float* pvec  = AF(1280);
  float* eddl  = AF(1280);
  float* edw   = AF(1280);
  float* edds  = AF(1280);
  float* rotc  = AF(1280);
  float* rots  = AF(1280);
  float* ub    = AF(512);
  float* w1b   = AF(512);
  float* pv2   = AF(2*1280);                  // device-scope p double buffer
  float* pub4  = AF(4*1280);                  // device-scope pivot-row ring
  int* indxq=AI(1280); int* edcm=AI(1280); int* edcmt=AI(1280); int* edic=AI(1280);
  int* rotp=AI(1280); int* rotn=AI(1280);
  EDMeta* meta=(EDMeta*)AI(192);  // 32 structs
  int* icnt=AI(NN); int* iptr=AI(NN+1); int* iidx=AI(P);
  int* barws=AI(2048);                        // flags[64] + genrep[64*16]
  unsigned* flags=(unsigned*)barws;
  unsigned* genrep=(unsigned*)(barws+64);
  (void)ws_size; (void)n_in; (void)out_size;

  // network-phase sub-slots (each SLOT floats; A/QM/Q2 hold 2.25 slots, DC 2.24)
  float* W0=A;        float* W1=A+SLOT;    // A region  (tb layer1 uses W0..W1 contiguous)
  float* W2=QM;       float* W3=QM+SLOT;   // QM region (tb layer2 uses W2..W3 contiguous)
  float* W4=Q2;       float* W5=Q2+SLOT;   // Q2 region
  float* W6=DC;       float* W7=DC+SLOT;   // DC region
  (void)W7;
  float* Vt=W6;   // written after last merge (DC dead)
  float* pe=W2;   // written after gather (QM dead)

  auto GEMM=[&](const float*Am,const float*Bm,const float*bias,const float*add,float*C,int M,int Nc,int K,int relu){
    dim3 g((Nc+63)/64,(M+63)/64);
    k_gemm<<<g,256,0,stream>>>(Am,Bm,bias,add,C,M,Nc,K,relu);
  };

  // ---- Laplacian (into A) ----
  {
    int ntot=NN*LDAe;
    k_zero_f<<<(ntot+255)/256,256,0,stream>>>(A,ntot);
    k_adj<<<(P+255)/256,256,0,stream>>>(esrc,edst,A,P);
    k_deg<<<NN,256,0,stream>>>(A,pvec);  // pvec reused as dinv
    dim3 g((NN+255)/256,NN);
    k_lap<<<g,256,0,stream>>>(A,pvec);
  }
  // ---- tridiagonalization: persistent (cols 0..IMID-1) + single-block midgame + LDS endgame ----
  k_zero_i<<<8,256,0,stream>>>(barws,2048);
  {
    void* kargs[] = { (void*)&A, (void*)&evec, (void*)&tauv, (void*)&scalv,
                      (void*)&pv2, (void*)&pub4, (void*)&flags, (void*)&genrep };
    hipLaunchCooperativeKernel((const void*)k_trid, dim3(TGRID), dim3(TBLK), kargs, 0, stream);
  }
  k_tmid<<<1,TBLK,0,stream>>>(A,evec,tauv,scalv,pv2,pub4);
  k_tend<<<1,256,0,stream>>>(A,evec,tauv,scalv);

  // ---- sstedc: harvest+scale+cuts (fused), tree, leaves ----
  ETree tr;
  {
    int tmp[64]; tmp[0]=NN; int cnt=1;
    while (tmp[cnt-1]>25){
      for(int j2=cnt-1;j2>=0;j2--){ int p=tmp[j2]; tmp[2*j2]=p/2; tmp[2*j2+1]=p-p/2; }
      cnt*=2;
    }
    tr.cnt=cnt;
    int acc=0;
    for(int j2=0;j2<cnt;j2++){ tr.st[j2]=acc; tr.sz[j2]=tmp[j2]; acc+=tmp[j2]; }
  }
  k_prep_ed<<<1,256,0,stream>>>(A,dvec,evec,tr);
  k_zero_f<<<(LDQ*NN+255)/256,256,0,stream>>>(QM,LDQ*NN);
  k_ed_leaves<<<tr.cnt,64,0,stream>>>(dvec,evec,QM,indxq,tr);

  // ---- slaed0 merge tree, level-batched ----
  {
    int csz[64], cst[64], cn=tr.cnt;
    for(int i=0;i<cn;i++){ csz[i]=tr.sz[i]; cst[i]=tr.st[i]; }
    while (cn>1){
      MergeLvl lv; lv.cnt=cn/2;
      int maxn=0;
      for(int i=0;i<cn/2;i++){
        lv.st[i]=cst[2*i]; lv.n1[i]=csz[2*i]; lv.n2[i]=csz[2*i+1];
        int n=lv.n1[i]+lv.n2[i]; if(n>maxn) maxn=n;
      }
      k_ed_deflate2<<<lv.cnt,256,0,stream>>>(dvec,indxq,eddl,edw,edds,edcm,edcmt,edic,
                                             rotp,rotn,rotc,rots,meta,QM,evec,lv);
      { dim3 gr((maxn+255)/256,lv.cnt);
        k_ed_rot2<<<gr,256,0,stream>>>(QM,rotp,rotn,rotc,rots,meta,lv); }
      { dim3 gp((maxn+255)/256,maxn,lv.cnt);
        k_ed_permute<<<gp,256,0,stream>>>(QM,Q2,edcm,edcmt,lv); }
      { dim3 gs((maxn+63)/64,lv.cnt);
        k_ed_secular<<<gs,64,0,stream>>>(eddl,edw,meta,dvec,DC,lv);
        k_ed_lowner<<<gs,64,0,stream>>>(eddl,edw,DC,meta,lv); }
      { dim3 gv(maxn,lv.cnt);
        k_ed_vecs<<<gv,256,0,stream>>>(edw,DC,edic,meta,lv); }
      { dim3 gg((maxn+63)/64,(maxn+63)/64,lv.cnt);
        k_gemm_cm2<<<gg,256,0,stream>>>(Q2,DC,QM,meta,lv); }
      k_ed_post<<<lv.cnt,256,0,stream>>>(dvec,edds,indxq,meta,lv);
      for(int i=0;i<cn/2;i++){ cst[i]=cst[2*i]; csz[i]=csz[2*i]+csz[2*i+1]; }
      cn>>=1;
    }
  }
  // ---- gather ascending columns 1..512 -> Vt (DC region, DC dead) ----
  { dim3 gg((NN+255)/256,512); k_ed_gather<<<gg,256,0,stream>>>(QM,indxq,Vt); }
  // ---- back-transform (reads A), then transpose -> pe (QM region, QM dead) ----
  k_backt<<<256,128,0,stream>>>(A,tauv,scalv,Vt);
  { dim3 g((NN+31)/32,(512+31)/32); k_transpose<<<g,256,0,stream>>>(Vt,pe); }

  // ---- network phase (A dead after backt; liveness-checked W-slot schedule) ----
  float* hx=W0; float* h0=W1; float* hb=W4;
  GEMM(H,W_lin,b_lin,nullptr,hx,NN,HID,NN,0);
  GEMM(hx,W_h,b_h,nullptr,h0,NN,HID,HID,0);
  GEMM(pe,W_lap,b_lap,h0,hb,NN,HID,HID,0);      // pe dead after this
  k_prep_uw<<<2,256,0,stream>>>(W_e,b_e,We1,ub,w1b);
  k_zero_i<<<(NN+255)/256,256,0,stream>>>(icnt,NN);
  k_count<<<(P+255)/256,256,0,stream>>>(edst,icnt,P);
  k_scan<<<1,256,0,stream>>>(icnt,iptr);
  k_fill<<<NN,256,0,stream>>>(edst,iptr,iidx,P);
  // ---- layer 1 (edge layer; e1 branch dead) ----
  float* qb=W0; float* kb=W1; float* vb=W3;     // hx,h0 dead
  { dim3 g((HID+63)/64,(NN+63)/64);
    k_gemm3<<<g,256,0,stream>>>(hb,Wq1,Wk1,Wv1,qb,kb,vb,NN,HID,HID); }
  float* logit=W2;                               // pe dead
  k_elogits<<<(P+3)/4,256,0,stream>>>(qb,kb,esrc,edst,edge_w,ub,w1b,logit,P,1);
  float* wght=W5;
  k_softmax<<<NN,256,0,stream>>>(logit,iptr,iidx,wght);
  float* aggb=W6;                                // Vt dead
  k_agg<<<NN,512,0,stream>>>(wght,vb,esrc,iptr,iidx,aggb);
  float* ob=W0;                                  // qb dead
  GEMM(aggb,Wo1,nullptr,nullptr,ob,NN,HID,HID,0);
  float* h1a=W3;                                 // vb dead
  k_lnadd<<<NN,256,0,stream>>>(hb,ob,h1a);
  float* tb1=W0;                                 // spans W0..W1 (ob,kb dead); NN x 1024
  GEMM(h1a,Wf1a,nullptr,nullptr,tb1,NN,1024,HID,1);
  float* fb=W2;                                  // logit dead
  GEMM(tb1,Wf1b,nullptr,nullptr,fb,NN,HID,1024,0);
  float* h1=W5;                                  // wght dead
  k_lnadd<<<NN,256,0,stream>>>(h1a,fb,h1);
  // ---- layer 2 (plain GT layer) ----
  float* q2=W0; float* k2=W1; float* v2=W2;      // tb1,fb dead
  { dim3 g((HID+63)/64,(NN+63)/64);
    k_gemm3<<<g,256,0,stream>>>(h1,Wq2,Wk2,Wv2,q2,k2,v2,NN,HID,HID); }
  float* logit2=W3;                              // h1a dead
  k_elogits<<<(P+3)/4,256,0,stream>>>(q2,k2,esrc,edst,nullptr,nullptr,nullptr,logit2,P,0);
  float* wght2=W4;                               // hb dead
  k_softmax<<<NN,256,0,stream>>>(logit2,iptr,iidx,wght2);
  float* agg2=W6;                                // aggb dead
  k_agg<<<NN,512,0,stream>>>(wght2,v2,esrc,iptr,iidx,agg2);
  float* o2=W0;                                  // q2 dead
  GEMM(agg2,Wo2,nullptr,nullptr,o2,NN,HID,HID,0);
  float* h2a=W1;                                 // k2 dead
  k_lnadd<<<NN,256,0,stream>>>(h1,o2,h2a);
  float* tb2=W2;                                 // spans W2..W3 (v2,logit2 dead); NN x 1024
  GEMM(h2a,Wf2a,nullptr,nullptr,tb2,NN,1024,HID,1);
  float* f2=W0;                                  // o2 dead
  GEMM(tb2,Wf2b,nullptr,nullptr,f2,NN,HID,1024,0);
  k_lnadd<<<NN,256,0,stream>>>(h2a,f2,out);
}

// Round 9
// 28301.685 us; speedup vs baseline: 1.1624x; 1.1624x over previous
//
#include <hip/hip_runtime.h>
#include <hip/hip_cooperative_groups.h>
#include <math.h>

#define NN 1147
#define HID 512
#define LDAe 1152
#define LDQ 1152
#define LDD 1147
#define EPS32 5.9604644775390625e-08f
#define SAFMIN32 1.17549435e-38f
#define I0E 1026   // endgame start iteration (m = 120 at entry)
#define TGRID 64   // persistent tridiag grid (64 blocks x 1024 thr = 1024 row-slots)
#define TBLK 1024
#define GENSTRIDE 16  // one 64B line per block for the replicated release word

struct EDMeta { int K; int nrot; int early; float rho; };
struct ETree { int st[64]; int sz[64]; int cnt; };
struct MergeLvl { int cnt; int st[32]; int n1[32]; int n2[32]; };

__device__ __forceinline__ float lapy2f(float x, float y){
  float xa=fabsf(x), ya=fabsf(y), w=fmaxf(xa,ya), z2=fminf(xa,ya);
  if (z2==0.f) return w;
  float q=z2/w; return w*sqrtf(1.f+q*q);
}
__device__ __forceinline__ void slartg(float ff, float gg, float* c, float* s, float* r){
  if (gg==0.f){ *c=1.f; *s=0.f; *r=ff; }
  else if (ff==0.f){ *c=0.f; *s=copysignf(1.f,gg); *r=fabsf(gg); }
  else {
    float d=sqrtf(ff*ff+gg*gg);
    *c=fabsf(ff)/d;
    *r=copysignf(d,ff);
    *s=gg/(*r);
  }
}
__device__ void slaev2(float a, float b, float cc, float* rt1, float* rt2, float* cs1, float* sn1){
  float sm=a+cc, df=a-cc, adf=fabsf(df), tb=b+b, ab=fabsf(tb);
  float acmx, acmn;
  if (fabsf(a)>fabsf(cc)){ acmx=a; acmn=cc; } else { acmx=cc; acmn=a; }
  float rt;
  if (adf>ab) rt=adf*sqrtf(1.f+(ab/adf)*(ab/adf));
  else if (adf<ab) rt=ab*sqrtf(1.f+(adf/ab)*(adf/ab));
  else rt=ab*sqrtf(2.f);
  int sgn1;
  if (sm<0.f){ *rt1=0.5f*(sm-rt); sgn1=-1; *rt2=(acmx/(*rt1))*acmn-(b/(*rt1))*b; }
  else if (sm>0.f){ *rt1=0.5f*(sm+rt); sgn1=1; *rt2=(acmx/(*rt1))*acmn-(b/(*rt1))*b; }
  else { *rt1=0.5f*rt; *rt2=-0.5f*rt; sgn1=1; }
  int sgn2; float cs;
  if (df>=0.f){ cs=df+rt; sgn2=1; } else { cs=df-rt; sgn2=-1; }
  float acs=fabsf(cs);
  if (acs>ab){ float ct=-tb/cs; *sn1=1.f/sqrtf(1.f+ct*ct); *cs1=ct*(*sn1); }
  else {
    if (ab==0.f){ *cs1=1.f; *sn1=0.f; }
    else { float tn=-cs/tb; *cs1=1.f/sqrtf(1.f+tn*tn); *sn1=tn*(*cs1); }
  }
  if (sgn1==sgn2){ float tn=*cs1; *cs1=-(*sn1); *sn1=tn; }
}
// LAPACK dlamrg, 0-based; works on global or LDS pointers
__device__ void lamrg0(int n1,int n2,const float* a,int dtrd1,int dtrd2,int* idx){
  int n1sv=n1,n2sv=n2;
  int ind1=(dtrd1>0)?0:(n1-1);
  int ind2=(dtrd2>0)?n1:(n1+n2-1);
  int i=0;
  while(n1sv>0&&n2sv>0){
    if(a[ind1]<=a[ind2]){idx[i++]=ind1;ind1+=dtrd1;n1sv--;}
    else{idx[i++]=ind2;ind2+=dtrd2;n2sv--;}
  }
  while(n2sv>0){idx[i++]=ind2;ind2+=dtrd2;n2sv--;}
  while(n1sv>0){idx[i++]=ind1;ind1+=dtrd1;n1sv--;}
}

// 256-entry tree reduction, bitwise-identical to the sequential st=128..1
// pairwise tree; wave 0 computes steps 128,64 explicitly, then folds 32..1 via
// shuffles with the same pairwise association. 2 block barriers instead of 9.
__device__ __forceinline__ float tree256(float* red, float* bc, int tid){
  __syncthreads();
  if (tid<64){
    float b=(red[tid]+red[tid+128])+(red[tid+64]+red[tid+192]);
    b+=__shfl_down(b,32,64);
    b+=__shfl_down(b,16,64);
    b+=__shfl_down(b,8,64);
    b+=__shfl_down(b,4,64);
    b+=__shfl_down(b,2,64);
    b+=__shfl_down(b,1,64);
    if (tid==0) *bc=b;
  }
  __syncthreads();
  return *bc;
}

// ---------------- utility ----------------
__global__ __launch_bounds__(256) void k_zero_f(float* p, int n){
  int i = blockIdx.x*256+threadIdx.x; if (i<n) p[i]=0.f;
}
__global__ __launch_bounds__(256) void k_zero_i(int* p, int n){
  int i = blockIdx.x*256+threadIdx.x; if (i<n) p[i]=0;
}

// ---------------- Laplacian ----------------
__global__ __launch_bounds__(256) void k_adj(const int* __restrict__ src, const int* __restrict__ dst,
                                             float* __restrict__ A, int P){
  int p = blockIdx.x*256+threadIdx.x;
  if (p>=P) return;
  int s=src[p], d=dst[p];
  A[(size_t)s*LDAe+d]=1.f;
  A[(size_t)d*LDAe+s]=1.f;
}
__global__ __launch_bounds__(256) void k_deg(const float* __restrict__ A, float* __restrict__ dinv){
  int row=blockIdx.x; int tid=threadIdx.x;
  __shared__ float red[256];
  float s=0.f;
  for (int c=tid;c<NN;c+=256) s+=A[(size_t)row*LDAe+c];
  red[tid]=s; __syncthreads();
  for(int st=128;st;st>>=1){ if(tid<st) red[tid]+=red[tid+st]; __syncthreads(); }
  if(tid==0) dinv[row]=1.f/sqrtf(fmaxf(red[0],1.f));
}
__global__ __launch_bounds__(256) void k_lap(float* __restrict__ A, const float* __restrict__ dinv){
  int row=blockIdx.y; int col=blockIdx.x*256+threadIdx.x;
  if (col>=NN) return;
  size_t idx=(size_t)row*LDAe+col;
  float v=A[idx];
  float v1=(dinv[row]*v)*dinv[col];
  float v2=(dinv[col]*v)*dinv[row];
  A[idx] = ((row==col)?1.f:0.f) - 0.5f*(v1+v2);
}

// ---------------- device-scope (cross-XCD coherent) accessors ----------------
__device__ __forceinline__ float dload(const float* p){
  return __hip_atomic_load(p, __ATOMIC_RELAXED, __HIP_MEMORY_SCOPE_AGENT);
}
__device__ __forceinline__ void dstore(float* p, float v){
  __hip_atomic_store(p, v, __ATOMIC_RELAXED, __HIP_MEMORY_SCOPE_AGENT);
}

// ---------------- fence-free hierarchical grid barrier, contention-free release ----------------
// Retired blocks store 0x7FFFFFFF once and exit; their flag permanently satisfies
// block0's arrival poll.
__device__ __forceinline__ void gbar(unsigned* flags, unsigned* genrep, unsigned tgt){
  __syncthreads();
  if (threadIdx.x==0)
    __hip_atomic_store(&flags[blockIdx.x], tgt, __ATOMIC_RELAXED, __HIP_MEMORY_SCOPE_AGENT);
  if (blockIdx.x==0){
    if (threadIdx.x<TGRID){
      while (__hip_atomic_load(&flags[threadIdx.x], __ATOMIC_RELAXED, __HIP_MEMORY_SCOPE_AGENT) < tgt)
        __builtin_amdgcn_s_sleep(1);
    }
    __syncthreads();
    if (threadIdx.x<TGRID)
      __hip_atomic_store(&genrep[threadIdx.x*GENSTRIDE], tgt, __ATOMIC_RELAXED, __HIP_MEMORY_SCOPE_AGENT);
  } else {
    if (threadIdx.x==0){
      while (__hip_atomic_load(&genrep[blockIdx.x*GENSTRIDE], __ATOMIC_RELAXED, __HIP_MEMORY_SCOPE_AGENT) < tgt)
        __builtin_amdgcn_s_sleep(1);
    }
    __syncthreads();
  }
}

// ---------------- tridiagonalization: persistent, single-writer ownership ----------------
// 64 blocks x 1024 threads = 1024 row-slots; slot s owns rows s and s+1024.
// Blocks 8..63 RETIRE once i >= 16b+15 (flag = MAX, exit).
__global__ __launch_bounds__(1024) void k_trid(float* __restrict__ A, float* __restrict__ evec,
    float* __restrict__ tauv, float* __restrict__ scalv, float* __restrict__ pv2,
    float* __restrict__ pub4, unsigned* __restrict__ flags, unsigned* __restrict__ genrep){
  __shared__ float vbuf[2][1152];
  __shared__ float pcur[1152];
  __shared__ float pubc[1152];
  __shared__ float red[256];
  __shared__ float bcv;
  int tid=threadIdx.x, bid=blockIdx.x;
  int wv=tid>>6, lane=tid&63;
  unsigned tgt=0;
  float tau, scal;
  // ---- prologue: column-0 scalars (redundant), p_0 over own rows, publish row 1 ----
  {
    const float* row0=A;
    int m0=NN-1;
    if (tid<256){
      float s=0.f;
      for(int t=tid;t<m0-1;t+=256){ float x=row0[2+t]; s+=x*x; }
      red[tid]=s;
    }
    float xn2=tree256(red,&bcv,tid);
    float alpha=row0[1];
    float beta;
    if(xn2==0.f){ tau=0.f; beta=alpha; scal=0.f; }
    else { beta=-copysignf(sqrtf(alpha*alpha+xn2),alpha); tau=(beta-alpha)/beta; scal=1.f/(alpha-beta); }
    if(bid==0&&tid==0){ evec[0]=beta; tauv[0]=tau; scalv[0]=scal; }
    for(int t=tid;t<m0;t+=TBLK) vbuf[0][t]=row0[1+t];
    __syncthreads();
    for(int rr=0;rr<2;rr++){
      int r=16*bid+wv+rr*1024;
      if(r<1||r>=NN) continue;
      const float* arow=A+(size_t)r*LDAe+1;
      float acc=0.f;
      for(int c=lane;c<m0;c+=64){
        float v=(c==0)?1.f:vbuf[0][c]*scal;
        acc+=arow[c]*v;
      }
      for(int o=32;o;o>>=1) acc+=__shfl_down(acc,o,64);
      if(lane==0) dstore(&pv2[r],acc);
    }
    if(bid==0&&wv==1){  // owner of row 1 publishes original row 1 (cols >= 2)
      const float* r1=A+(size_t)LDAe;
      for(int c=2+lane;c<NN;c+=64) dstore(&pub4[1280+c],r1[c]);
    }
  }
  gbar(flags,genrep,++tgt);
  int cur=0;
  for(int i=0;i<I0E;i++){
    // retirement: blocks >=8 with no remaining rows exit forever
    if (bid>=8 && i>=16*bid+15){
      if (tid==0)
        __hip_atomic_store(&flags[bid], 0x7FFFFFFFu, __ATOMIC_RELAXED, __HIP_MEMORY_SCOPE_AGENT);
      return;
    }
    int m=NN-1-i, mp=m-1;
    float* vcur=vbuf[cur]; float* nxt=vbuf[cur^1];
    const float* pvs=pv2+(size_t)(i&1)*1280;
    const float* pbs=pub4+(size_t)((i+1)&3)*1280;
    // fused stage + s=v.p partials (thr 0-255) ; pivot-row stage (thr 256-1023)
    if (tid<256){
      float s=0.f;
      for(int t=tid;t<m;t+=256){
        float pv=dload(&pvs[(i+1)+t]);
        pcur[t]=pv;
        float v=(t==0)?1.f:vcur[t]*scal;
        s+=pv*v;
      }
      red[tid]=s;
    } else {
      for(int t=tid-256;t<mp;t+=768) pubc[t]=dload(&pbs[(i+2)+t]);
    }
    float sv=tree256(red,&bcv,tid);
    float c2=tau*tau*sv*0.5f;
    const float vz=1.f;
    float wR0=tau*pcur[0]-c2*vz;
    // fused next-pivot-row + norm partials (original norm assignment/order)
    if (tid<256){
      float s2=0.f;
      if (tid==0){
        float vC=vcur[1]*scal;
        float wC=tau*pcur[1]-c2*vC;
        nxt[0]=pubc[0]-(vz*wC+wR0*vC);
      }
      for(int u=tid+1;u<mp;u+=256){
        float vC=vcur[1+u]*scal;
        float wC=tau*pcur[1+u]-c2*vC;
        float x=pubc[u]-(vz*wC+wR0*vC);
        nxt[u]=x;
        s2+=x*x;
      }
      red[tid]=s2;
    }
    float xn2=tree256(red,&bcv,tid);
    float alpha1=nxt[0];
    float beta1,tau1,scal1;
    if(xn2==0.f){ tau1=0.f; beta1=alpha1; scal1=0.f; }
    else { beta1=-copysignf(sqrtf(alpha1*alpha1+xn2),alpha1); tau1=(beta1-alpha1)/beta1; scal1=1.f/(alpha1-beta1); }
    if(bid==0&&tid==0){ evec[i+1]=beta1; tauv[i+1]=tau1; scalv[i+1]=scal1; }
    // fused own-row pass: rank-2 update + dot with next v (+publish / +pivot overwrite)
    float* pvd=pv2+(size_t)((i+1)&1)*1280;
    float* pbd=pub4+(size_t)((i+2)&3)*1280;
    for(int rr=0;rr<2;rr++){
      int r=16*bid+wv+rr*1024;
      if(r<i+1||r>=NN) continue;
      int tr=r-(i+1);
      float vR=(tr==0)?1.f:vcur[tr]*scal;
      float wR=tau*pcur[tr]-c2*vR;
      float* arow=A+(size_t)r*LDAe;
      if(lane==0) arow[i+1]=arow[i+1]-(vR*wR0+wR*vz);
      if(tr==0){
        // row i+1: store the redundantly-computed values for bitwise consistency
        for(int c=lane;c<mp;c+=64) arow[i+2+c]=nxt[c];
      } else {
        float acc=0.f;
        int ispub=(tr==1);  // r == i+2: next iteration's pivot row
        for(int c=lane;c<mp;c+=64){
          float vC=vcur[1+c]*scal;
          float wC=tau*pcur[1+c]-c2*vC;
          float val=arow[i+2+c]-(vR*wC+wR*vC);
          arow[i+2+c]=val;
          float v1=(c==0)?1.f:nxt[c]*scal1;
          acc+=val*v1;
          if(ispub) dstore(&pbd[(i+2)+c],val);
        }
        for(int o=32;o;o>>=1) acc+=__shfl_down(acc,o,64);
        if(lane==0) dstore(&pvd[r],acc);
      }
    }
    gbar(flags,genrep,++tgt);
    cur^=1; tau=tau1; scal=scal1;
  }
}
// endgame: iterations I0E..NN-2 entirely in LDS (121x121 trailing tile)
__global__ __launch_bounds__(256) void k_tend(float* __restrict__ A, float* __restrict__ evec,
    float* __restrict__ tauv, float* __restrict__ scalv){
  __shared__ float T[121][122];
  __shared__ float red[256];
  __shared__ float bct;
  __shared__ float pl[121];
  __shared__ float el[121], tl[121], sl[121];
  __shared__ float sh3[2];
  int tid=threadIdx.x;
  for(int e=tid;e<121*121;e+=256){ int r=e/121,c=e%121; T[r][c]=A[(size_t)(I0E+r)*LDAe + I0E+c]; }
  __syncthreads();
  for(int li=0; li<120; ++li){
    int m=120-li;
    float s=0.f;
    for(int t=tid;t<m-1;t+=256){ float x=T[li][li+2+t]; s+=x*x; }
    red[tid]=s;
    float xn2t=tree256(red,&bct,tid);
    if(tid==0){
      float alpha=T[li][li+1], xn2=xn2t;
      float beta,tau,scal;
      if(xn2==0.f){ tau=0.f; beta=alpha; scal=0.f; }
      else { beta=-copysignf(sqrtf(alpha*alpha+xn2),alpha); tau=(beta-alpha)/beta; scal=1.f/(alpha-beta); }
      el[li]=beta; tl[li]=tau; sl[li]=scal;
      sh3[0]=tau; sh3[1]=scal;
    }
    __syncthreads();
    float tau=sh3[0], scal=sh3[1];
    if(tid<m){
      float acc=0.f;
      for(int c=0;c<m;c++){
        float v=(c==0)?1.f:T[li][li+1+c]*scal;
        acc+=T[li+1+tid][li+1+c]*v;
      }
      pl[tid]=acc;
    }
    __syncthreads();
    s=0.f;
    for(int t=tid;t<m;t+=256){
      float v=(t==0)?1.f:T[li][li+1+t]*scal;
      s+=pl[t]*v;
    }
    red[tid]=s;
    float sv=tree256(red,&bct,tid);
    float c2=tau*tau*sv*0.5f;
    for(int e=tid;e<m*m;e+=256){
      int r=e/m, c=e%m;
      float vR=(r==0)?1.f:T[li][li+1+r]*scal;
      float vC=(c==0)?1.f:T[li][li+1+c]*scal;
      float wR=tau*pl[r]-c2*vR;
      float wC=tau*pl[c]-c2*vC;
      T[li+1+r][li+1+c]-=vR*wC+wR*vC;
    }
    __syncthreads();
  }
  for(int e=tid;e<121*121;e+=256){ int r=e/121,c=e%121; A[(size_t)(I0E+r)*LDAe + I0E+c]=T[r][c]; }
  for(int t=tid;t<120;t+=256){ evec[I0E+t]=el[t]; tauv[I0E+t]=tl[t]; scalv[I0E+t]=sl[t]; }
}

// ---------------- fused harvest + sstedc scale + cuts (1 block) ----------------
__global__ __launch_bounds__(256) void k_prep_ed(const float* __restrict__ A, float* __restrict__ D,
                                                 float* __restrict__ E, ETree t){
  __shared__ float red[256];
  int tid=threadIdx.x;
  for(int i=tid;i<NN;i+=256) D[i]=A[(size_t)i*LDAe+i];
  __syncthreads();
  float m=0.f;
  for(int i=tid;i<NN;i+=256) m=fmaxf(m,fabsf(D[i]));
  for(int i=tid;i<NN-1;i+=256) m=fmaxf(m,fabsf(E[i]));
  red[tid]=m; __syncthreads();
  for(int s=128;s;s>>=1){ if(tid<s) red[tid]=fmaxf(red[tid],red[tid+s]); __syncthreads(); }
  float mul=1.f/red[0];
  __syncthreads();
  for(int i=tid;i<NN;i+=256) D[i]*=mul;
  for(int i=tid;i<NN-1;i+=256) E[i]*=mul;
  __syncthreads();
  if (tid>0 && tid<t.cnt){
    int cut=t.st[tid];
    float ae=fabsf(E[cut-1]);
    D[cut-1]-=ae; D[cut]-=ae;
  }
}

// ---------------- ssteqr('I'), one WAVE per leaf, d/e AND z in LDS ----------------
__device__ void steqr1w(int n, float* d, float* e, float* z, int ldz, int lane){
  if (n<=1) return;
  const float eps=EPS32, eps2=EPS32*EPS32, safmin=SAFMIN32;
  float workc[32], works[32];
  int nmaxit=n*30, jtot=0;
  int l1=0;
  for(;;){
    if (l1>n-1) break;
    if (l1>0) e[l1-1]=0.f;
    int m;
    for(m=l1;m<n-1;m++){
      float tst=fabsf(e[m]);
      if (tst==0.f) break;
      if (tst<=(sqrtf(fabsf(d[m]))*sqrtf(fabsf(d[m+1])))*eps){ e[m]=0.f; break; }
    }
    int l=l1, lend=m, lsv=l, lendsv=lend;
    l1=m+1;
    if (lend==l) continue;
    float anorm=0.f;
    for(int i=l;i<=lend;i++) anorm=fmaxf(anorm,fabsf(d[i]));
    for(int i=l;i<lend;i++) anorm=fmaxf(anorm,fabsf(e[i]));
    if (anorm==0.f) continue;
    if (fabsf(d[lend])<fabsf(d[l])){ lend=lsv; l=lendsv; }
    float c,s,g,r,p,f,b,rt1,rt2;
    if (lend>l){
      for(;;){
        int mm;
        for(mm=l;mm<lend;mm++){
          float tst=e[mm]*e[mm];
          if (tst<=(eps2*fabsf(d[mm]))*fabsf(d[mm+1])+safmin) break;
        }
        if (mm<lend) e[mm]=0.f;
        p=d[l];
        if (mm==l){ d[l]=p; l++; if (l<=lend) continue; else break; }
        if (mm==l+1){
          slaev2(d[l],e[l],d[l+1],&rt1,&rt2,&c,&s);
          for(int row=lane;row<n;row+=64){
            float t1=z[(size_t)(l+1)*ldz+row];
            z[(size_t)(l+1)*ldz+row]=c*t1 - s*z[(size_t)l*ldz+row];
            z[(size_t)l*ldz+row]=s*t1 + c*z[(size_t)l*ldz+row];
          }
          d[l]=rt1; d[l+1]=rt2; e[l]=0.f;
          l+=2;
          if (l<=lend) continue; else break;
        }
        if (jtot==nmaxit) break;
        jtot++;
        g=(d[l+1]-p)/(2.f*e[l]);
        r=lapy2f(g,1.f);
        g=d[mm]-p+(e[l]/(g+copysignf(r,g)));
        s=1.f; c=1.f; p=0.f;
        for(int i=mm-1;i>=l;i--){
          f=s*e[i]; b=c*e[i];
          slartg(g,f,&c,&s,&r);
          if (i!=mm-1) e[i+1]=r;
          g=d[i+1]-p;
          r=(d[i]-g)*s+2.f*c*b;
          p=s*r;
          d[i+1]=g+p;
          g=c*r-b;
          workc[i-l]=c; works[i-l]=-s;
        }
        for(int j2=mm-1;j2>=l;j2--){
          float cc=workc[j2-l], ss2=works[j2-l];
          if (cc!=1.f||ss2!=0.f)
            for(int row=lane;row<n;row+=64){
              float t1=z[(size_t)(j2+1)*ldz+row];
              z[(size_t)(j2+1)*ldz+row]=cc*t1 - ss2*z[(size_t)j2*ldz+row];
              z[(size_t)j2*ldz+row]=ss2*t1 + cc*z[(size_t)j2*ldz+row];
            }
        }
        d[l]=d[l]-p;
        e[l]=g;
      }
    } else {
      for(;;){
        int mm;
        for(mm=l;mm>lend;mm--){
          float tst=e[mm-1]*e[mm-1];
          if (tst<=(eps2*fabsf(d[mm]))*fabsf(d[mm-1])+safmin) break;
        }
        if (mm>lend) e[mm-1]=0.f;
        p=d[l];
        if (mm==l){ d[l]=p; l--; if (l>=lend) continue; else break; }
        if (mm==l-1){
          slaev2(d[l-1],e[l-1],d[l],&rt1,&rt2,&c,&s);
          for(int row=lane;row<n;row+=64){
            float t1=z[(size_t)l*ldz+row];
            z[(size_t)l*ldz+row]=c*t1 - s*z[(size_t)(l-1)*ldz+row];
            z[(size_t)(l-1)*ldz+row]=s*t1 + c*z[(size_t)(l-1)*ldz+row];
          }
          d[l-1]=rt1; d[l]=rt2; e[l-1]=0.f;
          l-=2;
          if (l>=lend) continue; else break;
        }
        if (jtot==nmaxit) break;
        jtot++;
        g=(d[l-1]-p)/(2.f*e[l-1]);
        r=lapy2f(g,1.f);
        g=d[mm]-p+(e[l-1]/(g+copysignf(r,g)));
        s=1.f; c=1.f; p=0.f;
        for(int i=mm;i<=l-1;i++){
          f=s*e[i]; b=c*e[i];
          slartg(g,f,&c,&s,&r);
          if (i!=mm) e[i-1]=r;
          g=d[i]-p;
          r=(d[i+1]-g)*s+2.f*c*b;
          p=s*r;
          d[i]=g+p;
          g=c*r-b;
          workc[i-mm]=c; works[i-mm]=s;
        }
        for(int j2=mm;j2<=l-1;j2++){
          float cc=workc[j2-mm], ss2=works[j2-mm];
          if (cc!=1.f||ss2!=0.f)
            for(int row=lane;row<n;row+=64){
              float t1=z[(size_t)(j2+1)*ldz+row];
              z[(size_t)(j2+1)*ldz+row]=cc*t1 - ss2*z[(size_t)j2*ldz+row];
              z[(size_t)j2*ldz+row]=ss2*t1 + cc*z[(size_t)j2*ldz+row];
            }
        }
        d[l]=d[l]-p;
        e[l-1]=g;
      }
    }
  }
  for(int ii=1;ii<n;ii++){
    int i=ii-1,k=i; float pp=d[i];
    for(int j2=ii;j2<n;j2++) if (d[j2]<pp){k=j2;pp=d[j2];}
    if (k!=i){
      d[k]=d[i]; d[i]=pp;
      for(int row=lane;row<n;row+=64){
        float t1=z[(size_t)i*ldz+row];
        z[(size_t)i*ldz+row]=z[(size_t)k*ldz+row];
        z[(size_t)k*ldz+row]=t1;
      }
    }
  }
}
__global__ __launch_bounds__(64) void k_ed_leaves(float* D, float* E, float* QM, int* indxq, ETree t){
  int lf=blockIdx.x;
  if (lf>=t.cnt) return;
  int lane=threadIdx.x;
  int st=t.st[lf], n=t.sz[lf];
  __shared__ float dl[32], el[32];
  __shared__ float zloc[32][33];
  for(int i=lane;i<n;i+=64) dl[i]=D[st+i];
  for(int i=lane;i<n-1;i+=64) el[i]=E[st+i];
  for(int e=lane;e<n*n;e+=64){ int c=e/n, r=e%n; zloc[c][r]=(c==r)?1.f:0.f; }
  __syncthreads();
  steqr1w(n, dl, el, &zloc[0][0], 33, lane);
  __syncthreads();
  for(int i=lane;i<n;i+=64){ D[st+i]=dl[i]; indxq[st+i]=i; }
  for(int i=lane;i<n-1;i+=64) E[st+i]=el[i];
  for(int e=lane;e<n*n;e+=64){ int c=e/n, r=e%n; QM[(size_t)(st+c)*LDQ + st+r]=zloc[c][r]; }
}

// ---------------- batched slaed1/slaed2: formz + deflation in LDS ----------------
__global__ __launch_bounds__(256) void k_ed_deflate2(float* __restrict__ D, int* __restrict__ indxq,
    float* __restrict__ dlamda, float* __restrict__ w, float* __restrict__ dstage,
    int* __restrict__ colmap, int* __restrict__ cmtype, int* __restrict__ indxcg,
    int* __restrict__ rotp, int* __restrict__ rotn, float* __restrict__ rotc, float* __restrict__ rots,
    EDMeta* __restrict__ meta, const float* __restrict__ QM, const float* __restrict__ E, MergeLvl lv){
  int mid=blockIdx.x; if(mid>=lv.cnt) return;
  int st=lv.st[mid], n1=lv.n1[mid], n2=lv.n2[mid], n=n1+n2;
  int tid=threadIdx.x;
  __shared__ float zl[1152], dl_[1152], dlam[1152], wl[1152], ds2[1152];
  __shared__ int iq[1152], im[1152], ix[1152], ixp[1152], ict[1152], is2[1152];
  __shared__ float rv[256]; __shared__ int ri[256];
  __shared__ float srho; __shared__ int sK, snrot, searly, simax, sjmax;
  float rr=E[st+n1-1];
  if(tid==0) srho=fabsf(2.f*rr);
  for(int i=tid;i<n;i+=256){
    float v = (i<n1)? QM[(size_t)(st+i)*LDQ + st+n1-1] : QM[(size_t)(st+i)*LDQ + st+n1];
    if(rr<0.f && i>=n1) v=-v;
    zl[i]=v*0.70710678118654752440f;
    dl_[i]=D[st+i];
    int q=indxq[st+i]; if(i>=n1) q+=n1;
    iq[i]=q;
    ict[i]=(i<n1)?1:3;
  }
  __syncthreads();
  // argmax |z| (first-max-wins == serial scan)
  {
    float bv=-1.f; int bi=0;
    for(int i2=tid;i2<n;i2+=256){ float a=fabsf(zl[i2]); if(a>bv){bv=a;bi=i2;} }
    rv[tid]=bv; ri[tid]=bi; __syncthreads();
    for(int stp=128;stp;stp>>=1){
      if(tid<stp){ if(rv[tid+stp]>rv[tid]||(rv[tid+stp]==rv[tid]&&ri[tid+stp]<ri[tid])){rv[tid]=rv[tid+stp];ri[tid]=ri[tid+stp];} }
      __syncthreads();
    }
    if(tid==0) simax=ri[0];
    __syncthreads();
  }
  {
    float bv=-1.f; int bi=0;
    for(int i2=tid;i2<n;i2+=256){ float a=fabsf(dl_[i2]); if(a>bv){bv=a;bi=i2;} }
    rv[tid]=bv; ri[tid]=bi; __syncthreads();
    for(int stp=128;stp;stp>>=1){
      if(tid<stp){ if(rv[tid+stp]>rv[tid]||(rv[tid+stp]==rv[tid]&&ri[tid+stp]<ri[tid])){rv[tid]=rv[tid+stp];ri[tid]=ri[tid+stp];} }
      __syncthreads();
    }
    if(tid==0) sjmax=ri[0];
    __syncthreads();
  }
  if(tid==0){
    for(int i=0;i<n;i++) dlam[i]=dl_[iq[i]];
    lamrg0(n1,n2,dlam,1,1,im);
    for(int i=0;i<n;i++) ix[i]=iq[im[i]];
    float tol=8.f*EPS32*fmaxf(fabsf(dl_[sjmax]),fabsf(zl[simax]));
    float rho=srho;
    int K=0,nrot=0,early=0;
    if(rho*fabsf(zl[simax])<=tol){
      early=1;
      for(int i=0;i<n;i++){ int s2=ix[i]; im[i]=s2; iq[i]=2; ds2[i]=dl_[s2]; is2[i]=i; }
    } else {
      int K2=n; int pj=0; int j=0;
      for(;j<n;j++){ int nj=ix[j]; if(rho*fabsf(zl[nj])<=tol){K2--;ict[nj]=4;ixp[K2]=nj;} else {pj=nj;break;} }
      for(j=j+1;;j++){
        if(j>=n) break;
        int nj=ix[j];
        if(rho*fabsf(zl[nj])<=tol){K2--;ict[nj]=4;ixp[K2]=nj;}
        else {
          float s=zl[pj], c=zl[nj];
          float tau2=lapy2f(c,s);
          float t=dl_[nj]-dl_[pj];
          c=c/tau2; s=-s/tau2;
          if(fabsf(t*c*s)<=tol){
            zl[nj]=tau2; zl[pj]=0.f;
            if(ict[nj]!=ict[pj]) ict[nj]=2;
            ict[pj]=4;
            rotp[st+nrot]=pj; rotn[st+nrot]=nj; rotc[st+nrot]=c; rots[st+nrot]=s; nrot++;
            float t2=dl_[pj]*c*c + dl_[nj]*s*s;
            dl_[nj]=dl_[pj]*s*s + dl_[nj]*c*c;
            dl_[pj]=t2;
            K2--;
            int i2=1;
            for(;;){
              if(K2+i2<=n-1 && dl_[pj]<dl_[ixp[K2+i2]]){ ixp[K2+i2-1]=ixp[K2+i2]; ixp[K2+i2]=pj; i2++; }
              else { ixp[K2+i2-1]=pj; break; }
            }
            pj=nj;
          } else {
            dlam[K]=dl_[pj]; wl[K]=zl[pj]; ixp[K]=pj; K++;
            pj=nj;
          }
        }
      }
      dlam[K]=dl_[pj]; wl[K]=zl[pj]; ixp[K]=pj; K++;
      int ctot[5]={0,0,0,0,0};
      for(int i=0;i<n;i++) ctot[ict[i]]++;
      int psm[5]; psm[1]=0; psm[2]=ctot[1]; psm[3]=psm[2]+ctot[2]; psm[4]=psm[3]+ctot[3];
      for(int jj=0;jj<n;jj++){
        int js=ixp[jj]; int ct=ict[js];
        int slot=psm[ct]++;
        im[slot]=js; is2[slot]=jj; ds2[slot]=dl_[js]; iq[slot]=ct;
      }
    }
    sK=K; snrot=nrot; searly=early;
  }
  __syncthreads();
  int K=sK;
  for(int i=tid;i<n;i+=256){
    colmap[st+i]=im[i];
    cmtype[st+i]=iq[i];
    indxcg[st+i]=is2[i];
    dstage[st+i]=ds2[i];
    if(i<K){ dlamda[st+i]=dlam[i]; w[st+i]=wl[i]; }
  }
  if(tid==0){ meta[mid].K=K; meta[mid].nrot=snrot; meta[mid].early=searly; meta[mid].rho=srho; }
}

// batched Givens application: row-parallel; per-thread sequential over rotations.
// Chain-cache: rotations chain (rotp[k+1]==rotn[k] for merged runs), so the value
// this thread just computed for column rotn[k] is usually the next rotation's x.
// Carrying it in a register reads the IDENTICAL value (same-thread load-after-store)
// while breaking the dependent global-latency chain.
__global__ __launch_bounds__(256) void k_ed_rot2(float* __restrict__ QM, const int* __restrict__ rotp,
    const int* __restrict__ rotn, const float* __restrict__ rotc, const float* __restrict__ rots,
    const EDMeta* __restrict__ meta, MergeLvl lv){
  int mid=blockIdx.y; if(mid>=lv.cnt) return;
  int st=lv.st[mid], n=lv.n1[mid]+lv.n2[mid];
  int row=blockIdx.x*256+threadIdx.x;
  if(row>=n) return;
  int nr=meta[mid].nrot;
  int prevn=-1; float cached=0.f;
  for(int k=0;k<nr;k++){
    int pc=rotp[st+k], nc=rotn[st+k];
    size_t ip=(size_t)(st+pc)*LDQ+st+row;
    size_t iq2=(size_t)(st+nc)*LDQ+st+row;
    float c=rotc[st+k], s=rots[st+k];
    float x=(pc==prevn)? cached : QM[ip];
    float y=(nc==prevn)? cached : QM[iq2];
    float newx=c*x+s*y;
    float newy=c*y-s*x;
    QM[ip]=newx;
    QM[iq2]=newy;
    prevn=nc; cached=newy;
  }
}
// batched gather of grouped columns into Q2 (zero-padded per column type)
__global__ __launch_bounds__(256) void k_ed_permute(const float* __restrict__ QM, float* __restrict__ Q2,
    const int* __restrict__ colmap, const int* __restrict__ cmtype, MergeLvl lv){
  int mid=blockIdx.z; if(mid>=lv.cnt) return;
  int st=lv.st[mid], n1=lv.n1[mid], n=n1+lv.n2[mid];
  int row=blockIdx.x*256+threadIdx.x;
  int slot=blockIdx.y;
  if(row>=n||slot>=n) return;
  int src=colmap[st+slot], ct=cmtype[st+slot];
  float v=QM[(size_t)(st+src)*LDQ + st+row];
  if(ct==1&&row>=n1) v=0.f;
  else if(ct==3&&row<n1) v=0.f;
  Q2[(size_t)(st+slot)*LDQ + st+row]=v;
}

// ---------------- slaed4-style secular root (f64, safeguarded) ----------------
__device__ void ed4_general(int K, int j, const float* __restrict__ dl, const float* __restrict__ wv,
                            double rho, float* __restrict__ dcol, float* __restrict__ lamout){
  bool last=(j==K-1);
  bool orgati=true; double org, lo, hi;
  int i0,i1;
  if (!last){
    i0=j; i1=j+1;
    double dj=(double)dl[j];
    double del=(double)dl[j+1]-dj, mid=0.5*del;
    double g0=1.0/rho;
    for(int i=0;i<K;i++){ double de=((double)dl[i]-dj)-mid; double zi=(double)wv[i]; g0+=zi*zi/de; }
    if (g0>0.0){ orgati=true; org=dj; lo=0.0; hi=mid; }
    else { orgati=false; org=(double)dl[j+1]; lo=-mid; hi=0.0; }
  } else {
    i0=K-2; i1=K-1;
    org=(double)dl[K-1];
    double mid=0.5*rho;
    double g0=1.0/rho;
    for(int i=0;i<K;i++){ double de=((double)dl[i]-org)-mid; double zi=(double)wv[i]; g0+=zi*zi/de; }
    if (g0<=0.0){ lo=mid; hi=rho; } else { lo=0.0; hi=mid; }
  }
  double tau=0.5*(lo+hi);
  for(int it=0; it<60; ++it){
    double g=1.0/rho, gpsi=0.0, gphi=0.0;
    for(int i=0;i<K;i++){
      double de=((double)dl[i]-org)-tau;
      double zi=(double)wv[i];
      double t=zi/de;
      g+=zi*t;
      if (i<=i0) gpsi+=t*t; else gphi+=t*t;
    }
    double gp=gpsi+gphi;
    if (g==0.0) break;
    if (g<0.0){ if (tau>lo) lo=tau; } else { if (tau<hi) hi=tau; }
    double dI=((double)dl[i0]-org)-tau, dIP=((double)dl[i1]-org)-tau;
    double c2,A,B,eta;
    if (!last){
      double zi0=(double)wv[i0], zi1=(double)wv[i1];
      if (orgati){ double t1=zi0/dI; c2=g - dIP*gp - ((double)dl[i0]-(double)dl[i1])*t1*t1; }
      else { double t1=zi1/dIP; c2=g - dI*gp - ((double)dl[i1]-(double)dl[i0])*t1*t1; }
      A=(dI+dIP)*g - dI*dIP*gp;
      B=dI*dIP*g;
      if (c2==0.0){
        if (A==0.0){
          if (orgati) A=zi0*zi0+dIP*dIP*gp;
          else A=zi1*zi1+dI*dI*gp;
        }
        eta=B/A;
      } else if (A<=0.0) eta=(A-sqrt(fabs(A*A-4.0*B*c2)))/(2.0*c2);
      else eta=2.0*B/(A+sqrt(fabs(A*A-4.0*B*c2)));
    } else {
      c2=g - dI*gpsi - dIP*gphi;
      if (c2<0.0) c2=fabs(c2);
      A=(dI+dIP)*g - dI*dIP*gp;
      B=dI*dIP*g;
      if (c2==0.0) eta=hi-tau;
      else if (A>=0.0) eta=(A+sqrt(fabs(A*A-4.0*B*c2)))/(2.0*c2);
      else eta=2.0*B/(A-sqrt(fabs(A*A-4.0*B*c2)));
    }
    if (g*eta>=0.0) eta=-g/gp;
    double tn=tau+eta;
    if (!(tn>lo && tn<hi)) tn=0.5*(lo+hi);
    double ch=fabs(tn-tau);
    tau=tn;
    if (ch<=2.220446049250313e-16*(fabs(org)+fabs(tau))) break;
  }
  for(int i=0;i<K;i++) dcol[i]=(float)(((double)dl[i]-org)-tau);
  *lamout=(float)(org+tau);
}

__global__ __launch_bounds__(64) void k_ed_secular(const float* __restrict__ dlamda, const float* __restrict__ w,
    const EDMeta* __restrict__ meta, float* __restrict__ D_, float* __restrict__ DC, MergeLvl lv){
  int mid=blockIdx.y; if(mid>=lv.cnt) return;
  int st=lv.st[mid];
  int K=meta[mid].K;
  int j=blockIdx.x*64+threadIdx.x;
  if (j>=K) return;
  const float* dl=dlamda+st;
  const float* wv=w+st;
  double rho=(double)meta[mid].rho;
  float* dcol=DC+(size_t)(st+j)*LDD;
  if (K==1){
    double lam=(double)dl[0]+rho*(double)wv[0]*(double)wv[0];
    dcol[0]=1.f; D_[st]=(float)lam;
    return;
  }
  if (K==2){
    double d1=(double)dl[0], d2=(double)dl[1], z1=(double)wv[0], z2=(double)wv[1];
    double del=d2-d1, tau, lam, v0, v1;
    if (j==0){
      double ww=1.0+2.0*rho*(z2*z2-z1*z1)/del;
      if (ww>0.0){
        double bq=del+rho*(z1*z1+z2*z2), cq=rho*z1*z1*del;
        tau=2.0*cq/(bq+sqrt(fabs(bq*bq-4.0*cq)));
        lam=d1+tau; v0=-z1/tau; v1=z2/(del-tau);
      } else {
        double bq=-del+rho*(z1*z1+z2*z2), cq=rho*z2*z2*del;
        tau=(bq>0.0)? -2.0*cq/(bq+sqrt(bq*bq+4.0*cq)) : (bq-sqrt(bq*bq+4.0*cq))*0.5;
        lam=d2+tau; v0=-z1/(del+tau); v1=-z2/tau;
      }
    } else {
      double bq=-del+rho*(z1*z1+z2*z2), cq=rho*z2*z2*del;
      tau=(bq>0.0)? (bq+sqrt(bq*bq+4.0*cq))*0.5 : 2.0*cq/(-bq+sqrt(bq*bq+4.0*cq));
      lam=d2+tau; v0=-z1/(del+tau); v1=-z2/tau;
    }
    double nr=sqrt(v0*v0+v1*v1);
    dcol[0]=(float)(v0/nr); dcol[1]=(float)(v1/nr);
    D_[st+j]=(float)lam;
    return;
  }
  float lam;
  ed4_general(K, j, dl, wv, rho, dcol, &lam);
  D_[st+j]=lam;
}

__global__ __launch_bounds__(64) void k_ed_lowner(const float* __restrict__ dlamda, float* __restrict__ w,
    const float* __restrict__ DC, const EDMeta* __restrict__ meta, MergeLvl lv){
  int mid=blockIdx.y; if(mid>=lv.cnt) return;
  int st=lv.st[mid];
  int K=meta[mid].K; if (K<=2) return;
  int i=blockIdx.x*64+threadIdx.x; if (i>=K) return;
  const float* dl=dlamda+st;
  double p=(double)DC[(size_t)(st+i)*LDD+i];
  double di=(double)dl[i];
  for(int j2=0;j2<K;j2++){
    if (j2==i) continue;
    p *= (double)DC[(size_t)(st+j2)*LDD+i]/(di-(double)dl[j2]);
  }
  float val=sqrtf(fmaxf(-(float)p,0.f));
  w[st+i]=copysignf(val,w[st+i]);
}
__global__ __launch_bounds__(256) void k_ed_vecs(const float* __restrict__ w, float* __restrict__ DC,
    const int* __restrict__ indxcg, const EDMeta* __restrict__ meta, MergeLvl lv){
  int mid=blockIdx.y; if(mid>=lv.cnt) return;
  int st=lv.st[mid];
  int K=meta[mid].K;
  int j=blockIdx.x; if (j>=K) return;
  float* dcol=DC+(size_t)(st+j)*LDD;
  const int* indxc=indxcg+st;
  int tid=threadIdx.x;
  if (K==1){ if (tid==0) dcol[0]=1.f; return; }
  if (K==2){
    if (tid==0){
      float a=dcol[0], b=dcol[1];
      float o0=(indxc[0]==0)?a:b;
      float o1=(indxc[1]==0)?a:b;
      dcol[0]=o0; dcol[1]=o1;
    }
    return;
  }
  __shared__ float sv[1152];
  __shared__ double red[256];
  double ss=0.0;
  for(int i=tid;i<K;i+=256){
    float s=w[st+i]/dcol[i];
    sv[i]=s;
    ss+=(double)s*(double)s;
  }
  red[tid]=ss; __syncthreads();
  for(int st2=128;st2;st2>>=1){ if(tid<st2) red[tid]+=red[tid+st2]; __syncthreads(); }
  float tempf=(float)sqrt(red[0]);
  __syncthreads();
  for(int i=tid;i<K;i+=256) dcol[i]=sv[indxc[i]]/tempf;
}
// Qnew(:,0..K-1) = Q2 * DC ; cols K..n-1 copied from Q2 (fused copyback)
__global__ __launch_bounds__(256) void k_gemm_cm2(const float* __restrict__ Q2, const float* __restrict__ DC,
    float* __restrict__ QM, const EDMeta* __restrict__ meta, MergeLvl lv){
  int mid=blockIdx.z; if(mid>=lv.cnt) return;
  int st=lv.st[mid], n=lv.n1[mid]+lv.n2[mid];
  int K=meta[mid].K;
  int br=blockIdx.x*64, bj=blockIdx.y*64;
  if (br>=n||bj>=n) return;
  int tid=threadIdx.x, tr=tid/16, tc=tid%16;
  if (bj>=K){
    for(int i=0;i<4;i++){ int r=br+tr*4+i; if(r>=n)continue;
      for(int j2=0;j2<4;j2++){ int cc=bj+tc*4+j2; if(cc>=n)continue;
        QM[(size_t)(st+cc)*LDQ+st+r]=Q2[(size_t)(st+cc)*LDQ+st+r]; } }
    return;
  }
  __shared__ float As[16][65], Bs[16][65];
  float acc[4][4]={};
  for(int k0=0;k0<K;k0+=16){
    for(int l=0;l<4;l++){
      int e2=tid+l*256;
      int rr=e2&63, ii=e2>>6;
      float av=0.f;
      if (br+rr<n && k0+ii<K) av=Q2[(size_t)(st+k0+ii)*LDQ + st+br+rr];
      As[ii][rr]=av;
      int bi=e2&15, bj2=e2>>4;
      float bv=0.f;
      if (k0+bi<K && bj+bj2<n) bv=DC[(size_t)(st+bj+bj2)*LDD + k0+bi];
      Bs[bi][bj2]=bv;
    }
    __syncthreads();
    #pragma unroll
    for(int kk=0;kk<16;kk++){
      float ar[4],br2[4];
      #pragma unroll
      for(int i=0;i<4;i++) ar[i]=As[kk][tr*4+i];
      #pragma unroll
      for(int j2=0;j2<4;j2++) br2[j2]=Bs[kk][tc*4+j2];
      #pragma unroll
      for(int i=0;i<4;i++)
        #pragma unroll
        for(int j2=0;j2<4;j2++) acc[i][j2]+=ar[i]*br2[j2];
    }
    __syncthreads();
  }
  for(int i=0;i<4;i++){
    int r=br+tr*4+i; if (r>=n) continue;
    for(int j2=0;j2<4;j2++){
      int cc=bj+tc*4+j2; if (cc>=n) continue;
      if (cc<K) QM[(size_t)(st+cc)*LDQ + st+r]=acc[i][j2];
      else      QM[(size_t)(st+cc)*LDQ + st+r]=Q2[(size_t)(st+cc)*LDQ + st+r];
    }
  }
}
// post: D tail restore + merge (lamrg0 on LDS)
__global__ __launch_bounds__(256) void k_ed_post(float* __restrict__ D, const float* __restrict__ dstage,
    int* __restrict__ indxq, const EDMeta* __restrict__ meta, MergeLvl lv){
  int mid=blockIdx.x; if(mid>=lv.cnt) return;
  int st=lv.st[mid], n=lv.n1[mid]+lv.n2[mid];
  int K=meta[mid].K;
  int tid=threadIdx.x;
  __shared__ float dl[1152];
  __shared__ int iq[1152];
  float* Ds=D+st;
  for(int i=tid;i<n;i+=256){
    float v = (i<K)? Ds[i] : dstage[st+i];
    dl[i]=v;
    if (i>=K) Ds[i]=v;
  }
  __syncthreads();
  if (meta[mid].early){
    for(int i=tid;i<n;i+=256) indxq[st+i]=i;
    return;
  }
  if (tid==0) lamrg0(K, n-K, dl, 1, -1, iq);
  __syncthreads();
  for(int i=tid;i<n;i+=256) indxq[st+i]=iq[i];
}
// final: pull ascending columns 1..512 (drop trivial eigvec 0)
__global__ __launch_bounds__(256) void k_ed_gather(const float* __restrict__ QM, const int* __restrict__ indxq,
    float* __restrict__ Vt){
  int row=blockIdx.x*256+threadIdx.x;
  int vec=blockIdx.y;
  if (row>=NN) return;
  int src=indxq[vec+1];
  Vt[(size_t)vec*NN+row]=QM[(size_t)src*LDQ+row];
}

// ---------------- back-transform V = H0 H1 ... V_tri (v from A rows + scalv) ----------------
__global__ __launch_bounds__(128) void k_backt(const float* __restrict__ A, const float* __restrict__ tauv,
                                               const float* __restrict__ scalv, float* __restrict__ Vt){
  __shared__ float cols[2][1168];
  __shared__ float tl[1152], sl[1152];
  int wv=threadIdx.x>>6, lane=threadIdx.x&63;
  int vec=blockIdx.x*2+wv;
  float* col=Vt+(size_t)vec*NN;
  float* cl=cols[wv];
  for(int t=threadIdx.x;t<NN;t+=128){ tl[t]=tauv[t]; sl[t]=scalv[t]; }
  for(int t=lane;t<NN;t+=64) cl[t]=col[t];
  __syncthreads();
  for(int i=NN-2;i>=0;i--){
    float tau=tl[i];
    if (tau==0.f) continue;
    int m=NN-1-i;
    float scal=sl[i];
    const float* rowi=A+(size_t)i*LDAe;
    float s=0.f;
    for(int t=lane;t<m;t+=64){
      float v=(t==0)?1.f:rowi[i+1+t]*scal;
      s+=v*cl[i+1+t];
    }
    for(int o=32;o;o>>=1) s+=__shfl_down(s,o,64);
    s=__shfl(s,0,64);
    s*=tau;
    for(int t=lane;t<m;t+=64){
      float v=(t==0)?1.f:rowi[i+1+t]*scal;
      cl[i+1+t]-=s*v;
    }
  }
  for(int t=lane;t<NN;t+=64) col[t]=cl[t];
}

// ---------------- transpose Vt[512][1147] -> pe[1147][512] ----------------
__global__ __launch_bounds__(256) void k_transpose(const float* __restrict__ in, float* __restrict__ outp){
  __shared__ float tile[32][33];
  int c0=blockIdx.x*32, r0=blockIdx.y*32;
  int tx=threadIdx.x%32, ty=threadIdx.x/32;
  for(int s=0;s<32;s+=8){
    int r=r0+ty+s, c=c0+tx;
    tile[ty+s][tx]=(r<512 && c<NN)? in[(size_t)r*NN+c] : 0.f;
  }
  __syncthreads();
  for(int s=0;s<32;s+=8){
    int r=c0+ty+s, c=r0+tx;
    if (r<NN && c<512) outp[(size_t)r*512+c]=tile[tx][ty+s];
  }
}

// ---------------- generic f32 GEMM: C = A@B (+bias)(+add)(relu) ----------------
__global__ __launch_bounds__(256) void k_gemm(const float* __restrict__ A, const float* __restrict__ B,
    const float* __restrict__ bias, const float* __restrict__ add, float* __restrict__ C,
    int M, int Nc, int K, int relu){
  __shared__ float As[16][65];
  __shared__ float Bs[16][65];
  int bm=blockIdx.y*64, bn=blockIdx.x*64;
  int tid=threadIdx.x;
  int tr=tid/16, tc=tid%16;
  float acc[4][4]={};
  for(int k0=0;k0<K;k0+=16){
    for(int l=0;l<4;l++){
      int e2=tid+l*256;
      int m_=e2/16, kk=e2%16;
      float av=0.f;
      if (bm+m_<M && k0+kk<K) av=A[(size_t)(bm+m_)*K + k0+kk];
      As[kk][m_]=av;
      int k2=e2/64, n2=e2%64;
      float bv=0.f;
      if (k0+k2<K && bn+n2<Nc) bv=B[(size_t)(k0+k2)*Nc + bn+n2];
      Bs[k2][n2]=bv;
    }
    __syncthreads();
    for(int kk=0;kk<16;kk++){
      float ar[4], br[4];
      #pragma unroll
      for(int i=0;i<4;i++) ar[i]=As[kk][tr*4+i];
      #pragma unroll
      for(int j=0;j<4;j++) br[j]=Bs[kk][tc*4+j];
      #pragma unroll
      for(int i=0;i<4;i++)
        #pragma unroll
        for(int j=0;j<4;j++) acc[i][j]+=ar[i]*br[j];
    }
    __syncthreads();
  }
  for(int i=0;i<4;i++){
    int r=bm+tr*4+i;
    if (r>=M) continue;
    for(int j=0;j<4;j++){
      int c=bn+tc*4+j;
      if (c>=Nc) continue;
      float x=acc[i][j];
      if (bias) x+=bias[c];
      if (add)  x+=add[(size_t)r*Nc+c];
      if (relu) x=fmaxf(x,0.f);
      C[(size_t)r*Nc+c]=x;
    }
  }
}

// ---------------- fused 3-output GEMM (QKV): per-output arithmetic identical to k_gemm ----------------
__global__ __launch_bounds__(256) void k_gemm3(const float* __restrict__ A,
    const float* __restrict__ B0, const float* __restrict__ B1, const float* __restrict__ B2,
    float* __restrict__ C0, float* __restrict__ C1, float* __restrict__ C2,
    int M, int Nc, int K){
  __shared__ float As[16][65];
  __shared__ float Bs[3][16][65];
  int bm=blockIdx.y*64, bn=blockIdx.x*64;
  int tid=threadIdx.x;
  int tr=tid/16, tc=tid%16;
  float acc[3][4][4]={};
  const float* Bp0=B0; const float* Bp1=B1; const float* Bp2=B2;
  for(int k0=0;k0<K;k0+=16){
    for(int l=0;l<4;l++){
      int e2=tid+l*256;
      int m_=e2/16, kk=e2%16;
      float av=0.f;
      if (bm+m_<M && k0+kk<K) av=A[(size_t)(bm+m_)*K + k0+kk];
      As[kk][m_]=av;
      int k2=e2/64, n2=e2%64;
      bool ok=(k0+k2<K && bn+n2<Nc);
      size_t bidx=(size_t)(k0+k2)*Nc + bn+n2;
      Bs[0][k2][n2]= ok? Bp0[bidx]:0.f;
      Bs[1][k2][n2]= ok? Bp1[bidx]:0.f;
      Bs[2][k2][n2]= ok? Bp2[bidx]:0.f;
    }
    __syncthreads();
    for(int kk=0;kk<16;kk++){
      float ar[4];
      #pragma unroll
      for(int i=0;i<4;i++) ar[i]=As[kk][tr*4+i];
      #pragma unroll
      for(int q=0;q<3;q++){
        float br[4];
        #pragma unroll
        for(int j=0;j<4;j++) br[j]=Bs[q][kk][tc*4+j];
        #pragma unroll
        for(int i=0;i<4;i++)
          #pragma unroll
          for(int j=0;j<4;j++) acc[q][i][j]+=ar[i]*br[j];
      }
    }
    __syncthreads();
  }
  for(int i=0;i<4;i++){
    int r=bm+tr*4+i;
    if (r>=M) continue;
    for(int j=0;j<4;j++){
      int c=bn+tc*4+j;
      if (c>=Nc) continue;
      C0[(size_t)r*Nc+c]=acc[0][i][j];
      C1[(size_t)r*Nc+c]=acc[1][i][j];
      C2[(size_t)r*Nc+c]=acc[2][i][j];
    }
  }
}

// ---------------- LayerNorm(x+y) over 512 ----------------
__global__ __launch_bounds__(256) void k_lnadd(const float* __restrict__ x, const float* __restrict__ y,
                                               float* __restrict__ out){
  int row=blockIdx.x; int tid=threadIdx.x;
  __shared__ float red[256];
  size_t base=(size_t)row*HID;
  float v0=x[base+tid]+y[base+tid];
  float v1=x[base+256+tid]+y[base+256+tid];
  red[tid]=v0+v1; __syncthreads();
  for(int st=128;st;st>>=1){ if(tid<st) red[tid]+=red[tid+st]; __syncthreads(); }
  float mean=red[0]*(1.f/512.f);
  __syncthreads();
  float d0=v0-mean, d1=v1-mean;
  red[tid]=d0*d0+d1*d1; __syncthreads();
  for(int st=128;st;st>>=1){ if(tid<st) red[tid]+=red[tid+st]; __syncthreads(); }
  float r=rsqrtf(red[0]*(1.f/512.f)+1e-5f);
  out[base+tid]=d0*r;
  out[base+256+tid]=d1*r;
}

// ---------------- edge-path rank-1 collapse ----------------
__global__ __launch_bounds__(256) void k_prep_uw(const float* __restrict__ We, const float* __restrict__ be,
    const float* __restrict__ We1, float* __restrict__ u, float* __restrict__ w1){
  int c=blockIdx.x*256+threadIdx.x;
  if (c>=HID) return;
  float a=0.f,b=0.f;
  for(int f=0;f<HID;f++){ float m=We1[(size_t)f*HID+c]; a+=We[f]*m; b+=be[f]*m; }
  u[c]=a; w1[c]=b;
}

// ---------------- per-edge logits ----------------
__global__ __launch_bounds__(256) void k_elogits(const float* __restrict__ q, const float* __restrict__ kk,
    const int* __restrict__ src, const int* __restrict__ dst, const float* __restrict__ ew,
    const float* __restrict__ uu, const float* __restrict__ ww, float* __restrict__ logit, int P, int useep){
  int gw=(blockIdx.x*256+threadIdx.x)>>6;
  int lane=threadIdx.x&63;
  if (gw>=P) return;
  int s=src[gw], d=dst[gw];
  const float* kr=kk+(size_t)s*HID;
  const float* qr=q+(size_t)d*HID;
  float a1[8], a2[8];
  #pragma unroll
  for(int j=0;j<8;j++){
    int c=j*64+lane;
    float prod=kr[c]*qr[c];
    if (useep){ a1[j]=prod*uu[c]; a2[j]=prod*ww[c]; }
    else { a1[j]=prod; a2[j]=0.f; }
  }
  #pragma unroll
  for(int o=32;o;o>>=1){
    #pragma unroll
    for(int j=0;j<8;j++){ a1[j]+=__shfl_down(a1[j],o,64); a2[j]+=__shfl_down(a2[j],o,64); }
  }
  if (lane==0){
    float w0 = useep? ew[gw] : 0.f;
    #pragma unroll
    for(int j=0;j<8;j++){
      float lg = useep ? 0.125f*(w0*a1[j]+a2[j]) : 0.125f*a1[j];
      logit[(size_t)gw*8+j]=lg;
    }
  }
}

// ---------------- deterministic CSR by dst ----------------
__global__ __launch_bounds__(256) void k_count(const int* __restrict__ dst, int* __restrict__ cnt, int P){
  int p=blockIdx.x*256+threadIdx.x;
  if (p<P) atomicAdd(&cnt[dst[p]],1);
}
// scan on LDS (single-thread integer scan at LDS latency; exact)
__global__ __launch_bounds__(256) void k_scan(const int* __restrict__ cnt, int* __restrict__ iptr){
  __shared__ int c[NN+1];
  int tid=threadIdx.x;
  for(int i=tid;i<NN;i+=256) c[i]=cnt[i];
  __syncthreads();
  if (tid==0){
    int s=0;
    for(int n=0;n<NN;n++){ int t=c[n]; c[n]=s; s+=t; }
    c[NN]=s;
  }
  __syncthreads();
  for(int i=tid;i<=NN;i+=256) iptr[i]=c[i];
}
__global__ __launch_bounds__(256) void k_fill(const int* __restrict__ dst, const int* __restrict__ iptr,
                                              int* __restrict__ iidx, int P){
  int n=blockIdx.x; int tid=threadIdx.x;
  int lane=tid&63, wv=tid>>6;
  __shared__ int wb[4]; __shared__ int scnt;
  if (tid==0) scnt=iptr[n];
  __syncthreads();
  for(int base=0;base<P;base+=256){
    int p=base+tid;
    bool f=(p<P)&&(dst[p]==n);
    unsigned long long m=__ballot(f);
    if (lane==0) wb[wv]=__popcll(m);
    __syncthreads();
    int off=0;
    #pragma unroll
    for(int i=0;i<4;i++) if (i<wv) off+=wb[i];
    if (f){
      int pre=__popcll(m & ((1ull<<lane)-1ull));
      iidx[scnt+off+pre]=p;
    }
    int tot=wb[0]+wb[1]+wb[2]+wb[3];
    __syncthreads();
    if (tid==0) scnt+=tot;
    __syncthreads();
  }
}

// ---------------- per-dst segment softmax ----------------
__global__ __launch_bounds__(256) void k_softmax(const float* __restrict__ logit, const int* __restrict__ iptr,
    const int* __restrict__ iidx, float* __restrict__ wght){
  int n=blockIdx.x; int tid=threadIdx.x;
  int beg=iptr[n], end=iptr[n+1];
  if (beg==end) return;
  __shared__ float red[256];
  __shared__ float smax[8], sden[8];
  float mx[8];
  #pragma unroll
  for(int h=0;h<8;h++) mx[h]=-1e30f;
  for(int t=beg+tid;t<end;t+=256){
    int e=iidx[t];
    #pragma unroll
    for(int h=0;h<8;h++) mx[h]=fmaxf(mx[h],logit[(size_t)e*8+h]);
  }
  for(int h=0;h<8;h++){
    red[tid]=mx[h]; __syncthreads();
    for(int st=128;st;st>>=1){ if(tid<st) red[tid]=fmaxf(red[tid],red[tid+st]); __syncthreads(); }
    if (tid==0) smax[h]=red[0];
    __syncthreads();
  }
  float sm[8];
  #pragma unroll
  for(int h=0;h<8;h++) sm[h]=0.f;
  for(int t=beg+tid;t<end;t+=256){
    int e=iidx[t];
    #pragma unroll
    for(int h=0;h<8;h++) sm[h]+=expf(logit[(size_t)e*8+h]-smax[h]);
  }
  for(int h=0;h<8;h++){
    red[tid]=sm[h]; __syncthreads();
    for(int st=128;st;st>>=1){ if(tid<st) red[tid]+=red[tid+st]; __syncthreads(); }
    if (tid==0) sden[h]=red[0];
    __syncthreads();
  }
  for(int t=beg+tid;t<end;t+=256){
    int e=iidx[t];
    #pragma unroll
    for(int h=0;h<8;h++) wght[(size_t)e*8+h]=expf(logit[(size_t)e*8+h]-smax[h])/(sden[h]+1e-9f);
  }
}

// ---------------- weighted aggregation per dst node ----------------
__global__ __launch_bounds__(512) void k_agg(const float* __restrict__ wght, const float* __restrict__ vv,
    const int* __restrict__ src, const int* __restrict__ iptr, const int* __restrict__ iidx,
    float* __restrict__ agg){
  int n=blockIdx.x; int c=threadIdx.x; int h=c>>6;
  int beg=iptr[n], end=iptr[n+1];
  float acc=0.f;
  for(int t=beg;t<end;++t){
    int e=iidx[t];
    acc += wght[(size_t)e*8+h]*vv[(size_t)src[e]*HID+c];
  }
  agg[(size_t)n*HID+c]=acc;
}

// =======================================================================
extern "C" void kernel_launch(void* const* d_in, const int* in_sizes, int n_in,
                              void* d_out, int out_size, void* d_ws, size_t ws_size,
                              hipStream_t stream){
  const float* H      = (const float*)d_in[0];
  const float* edge_w = (const float*)d_in[1];
  const int*   esrc   = (const int*)d_in[2];
  const int*   edst   = (const int*)d_in[3];
  const float* W_lin  = (const float*)d_in[4];
  const float* b_lin  = (const float*)d_in[5];
  const float* W_e    = (const float*)d_in[6];
  const float* b_e    = (const float*)d_in[7];
  const float* W_h    = (const float*)d_in[8];
  const float* b_h    = (const float*)d_in[9];
  const float* W_lap  = (const float*)d_in[10];
  const float* b_lap  = (const float*)d_in[11];
  const float* Wq1    = (const float*)d_in[12];
  const float* Wk1    = (const float*)d_in[13];
  const float* Wv1    = (const float*)d_in[14];
  const float* We1    = (const float*)d_in[15];
  const float* Wo1    = (const float*)d_in[16];
  const float* Wf1a   = (const float*)d_in[18];
  const float* Wf1b   = (const float*)d_in[19];
  const float* Wq2    = (const float*)d_in[22];
  const float* Wk2    = (const float*)d_in[23];
  const float* Wv2    = (const float*)d_in[24];
  const float* Wo2    = (const float*)d_in[25];
  const float* Wf2a   = (const float*)d_in[26];
  const float* Wf2b   = (const float*)d_in[27];
  const int P = in_sizes[1];
  float* out = (float*)d_out;

  // ---- workspace: fully disjoint explicit layout (~21.6 MB) ----
  char* base=(char*)d_ws;
  size_t off=0;
  auto AF=[&](size_t n)->float*{ float* r=(float*)(base+off); off+=((n*4+255)/256)*256; return r; };
  auto AI=[&](size_t n)->int*{ int* r=(int*)(base+off); off+=((n*4+255)/256)*256; return r; };
  const size_t SLOT=(size_t)NN*HID;           // 587,264 floats
  float* A   = AF((size_t)NN*LDAe);           // 1,321,344 floats
  float* QM  = AF((size_t)LDQ*NN);            // 1,321,344
  float* Q2  = AF((size_t)LDQ*NN);            // 1,321,344
  float* DC  = AF((size_t)LDD*LDD);           // 1,315,609
  float* dvec  = AF(1280);
  float* evec  = AF(1280);
  float* tauv  = AF(1280);
  float* scalv = AF(1280);
  float* pvec  = AF(1280);
  float* eddl  = AF(1280);
  float* edw   = AF(1280);
  float* edds  = AF(1280);
  float* rotc  = AF(1280);
  float* rots  = AF(1280);
  float* ub    = AF(512);
  float* w1b   = AF(512);
  float* pv2   = AF(2*1280);                  // device-scope p double buffer
  float* pub4  = AF(4*1280);                  // device-scope pivot-row ring
  int* indxq=AI(1280); int* edcm=AI(1280); int* edcmt=AI(1280); int* edic=AI(1280);
  int* rotp=AI(1280); int* rotn=AI(1280);
  EDMeta* meta=(EDMeta*)AI(192);  // 32 structs
  int* icnt=AI(NN); int* iptr=AI(NN+1); int* iidx=AI(P);
  int* barws=AI(2048);                        // flags[64] + genrep[64*16]
  unsigned* flags=(unsigned*)barws;
  unsigned* genrep=(unsigned*)(barws+64);
  (void)ws_size; (void)n_in; (void)out_size;

  // network-phase sub-slots (each SLOT floats; A/QM/Q2 hold 2.25 slots, DC 2.24)
  float* W0=A;        float* W1=A+SLOT;    // A region  (tb layer1 uses W0..W1 contiguous)
  float* W2=QM;       float* W3=QM+SLOT;   // QM region (tb layer2 uses W2..W3 contiguous)
  float* W4=Q2;       float* W5=Q2+SLOT;   // Q2 region
  float* W6=DC;       float* W7=DC+SLOT;   // DC region
  (void)W7;
  float* Vt=W6;   // written after last merge (DC dead)
  float* pe=W2;   // written after gather (QM dead)

  auto GEMM=[&](const float*Am,const float*Bm,const float*bias,const float*add,float*C,int M,int Nc,int K,int relu){
    dim3 g((Nc+63)/64,(M+63)/64);
    k_gemm<<<g,256,0,stream>>>(Am,Bm,bias,add,C,M,Nc,K,relu);
  };

  // ---- Laplacian (into A) ----
  {
    int ntot=NN*LDAe;
    k_zero_f<<<(ntot+255)/256,256,0,stream>>>(A,ntot);
    k_adj<<<(P+255)/256,256,0,stream>>>(esrc,edst,A,P);
    k_deg<<<NN,256,0,stream>>>(A,pvec);  // pvec reused as dinv
    dim3 g((NN+255)/256,NN);
    k_lap<<<g,256,0,stream>>>(A,pvec);
  }
  // ---- tridiagonalization: persistent ownership kernel (fence-free) + LDS endgame ----
  k_zero_i<<<8,256,0,stream>>>(barws,2048);
  {
    void* kargs[] = { (void*)&A, (void*)&evec, (void*)&tauv, (void*)&scalv,
                      (void*)&pv2, (void*)&pub4, (void*)&flags, (void*)&genrep };
    hipLaunchCooperativeKernel((const void*)k_trid, dim3(TGRID), dim3(TBLK), kargs, 0, stream);
  }
  k_tend<<<1,256,0,stream>>>(A,evec,tauv,scalv);

  // ---- sstedc: harvest+scale+cuts (fused), tree, leaves ----
  ETree tr;
  {
    int tmp[64]; tmp[0]=NN; int cnt=1;
    while (tmp[cnt-1]>25){
      for(int j2=cnt-1;j2>=0;j2--){ int p=tmp[j2]; tmp[2*j2]=p/2; tmp[2*j2+1]=p-p/2; }
      cnt*=2;
    }
    tr.cnt=cnt;
    int acc=0;
    for(int j2=0;j2<cnt;j2++){ tr.st[j2]=acc; tr.sz[j2]=tmp[j2]; acc+=tmp[j2]; }
  }
  k_prep_ed<<<1,256,0,stream>>>(A,dvec,evec,tr);
  k_zero_f<<<(LDQ*NN+255)/256,256,0,stream>>>(QM,LDQ*NN);
  k_ed_leaves<<<tr.cnt,64,0,stream>>>(dvec,evec,QM,indxq,tr);

  // ---- slaed0 merge tree, level-batched ----
  {
    int csz[64], cst[64], cn=tr.cnt;
    for(int i=0;i<cn;i++){ csz[i]=tr.sz[i]; cst[i]=tr.st[i]; }
    while (cn>1){
      MergeLvl lv; lv.cnt=cn/2;
      int maxn=0;
      for(int i=0;i<cn/2;i++){
        lv.st[i]=cst[2*i]; lv.n1[i]=csz[2*i]; lv.n2[i]=csz[2*i+1];
        int n=lv.n1[i]+lv.n2[i]; if(n>maxn) maxn=n;
      }
      k_ed_deflate2<<<lv.cnt,256,0,stream>>>(dvec,indxq,eddl,edw,edds,edcm,edcmt,edic,
                                             rotp,rotn,rotc,rots,meta,QM,evec,lv);
      { dim3 gr((maxn+255)/256,lv.cnt);
        k_ed_rot2<<<gr,256,0,stream>>>(QM,rotp,rotn,rotc,rots,meta,lv); }
      { dim3 gp((maxn+255)/256,maxn,lv.cnt);
        k_ed_permute<<<gp,256,0,stream>>>(QM,Q2,edcm,edcmt,lv); }
      { dim3 gs((maxn+63)/64,lv.cnt);
        k_ed_secular<<<gs,64,0,stream>>>(eddl,edw,meta,dvec,DC,lv);
        k_ed_lowner<<<gs,64,0,stream>>>(eddl,edw,DC,meta,lv); }
      { dim3 gv(maxn,lv.cnt);
        k_ed_vecs<<<gv,256,0,stream>>>(edw,DC,edic,meta,lv); }
      { dim3 gg((maxn+63)/64,(maxn+63)/64,lv.cnt);
        k_gemm_cm2<<<gg,256,0,stream>>>(Q2,DC,QM,meta,lv); }
      k_ed_post<<<lv.cnt,256,0,stream>>>(dvec,edds,indxq,meta,lv);
      for(int i=0;i<cn/2;i++){ cst[i]=cst[2*i]; csz[i]=csz[2*i]+csz[2*i+1]; }
      cn>>=1;
    }
  }
  // ---- gather ascending columns 1..512 -> Vt (DC region, DC dead) ----
  { dim3 gg((NN+255)/256,512); k_ed_gather<<<gg,256,0,stream>>>(QM,indxq,Vt); }
  // ---- back-transform (reads A), then transpose -> pe (QM region, QM dead) ----
  k_backt<<<256,128,0,stream>>>(A,tauv,scalv,Vt);
  { dim3 g((NN+31)/32,(512+31)/32); k_transpose<<<g,256,0,stream>>>(Vt,pe); }

  // ---- network phase (A dead after backt; liveness-checked W-slot schedule) ----
  float* hx=W0; float* h0=W1; float* hb=W4;
  GEMM(H,W_lin,b_lin,nullptr,hx,NN,HID,NN,0);
  GEMM(hx,W_h,b_h,nullptr,h0,NN,HID,HID,0);
  GEMM(pe,W_lap,b_lap,h0,hb,NN,HID,HID,0);      // pe dead after this
  k_prep_uw<<<2,256,0,stream>>>(W_e,b_e,We1,ub,w1b);
  k_zero_i<<<(NN+255)/256,256,0,stream>>>(icnt,NN);
  k_count<<<(P+255)/256,256,0,stream>>>(edst,icnt,P);
  k_scan<<<1,256,0,stream>>>(icnt,iptr);
  k_fill<<<NN,256,0,stream>>>(edst,iptr,iidx,P);
  // ---- layer 1 (edge layer; e1 branch dead) ----
  float* qb=W0; float* kb=W1; float* vb=W3;     // hx,h0 dead
  { dim3 g((HID+63)/64,(NN+63)/64);
    k_gemm3<<<g,256,0,stream>>>(hb,Wq1,Wk1,Wv1,qb,kb,vb,NN,HID,HID); }
  float* logit=W2;                               // pe dead
  k_elogits<<<(P+3)/4,256,0,stream>>>(qb,kb,esrc,edst,edge_w,ub,w1b,logit,P,1);
  float* wght=W5;
  k_softmax<<<NN,256,0,stream>>>(logit,iptr,iidx,wght);
  float* aggb=W6;                                // Vt dead
  k_agg<<<NN,512,0,stream>>>(wght,vb,esrc,iptr,iidx,aggb);
  float* ob=W0;                                  // qb dead
  GEMM(aggb,Wo1,nullptr,nullptr,ob,NN,HID,HID,0);
  float* h1a=W3;                                 // vb dead
  k_lnadd<<<NN,256,0,stream>>>(hb,ob,h1a);
  float* tb1=W0;                                 // spans W0..W1 (ob,kb dead); NN x 1024
  GEMM(h1a,Wf1a,nullptr,nullptr,tb1,NN,1024,HID,1);
  float* fb=W2;                                  // logit dead
  GEMM(tb1,Wf1b,nullptr,nullptr,fb,NN,HID,1024,0);
  float* h1=W5;                                  // wght dead
  k_lnadd<<<NN,256,0,stream>>>(h1a,fb,h1);
  // ---- layer 2 (plain GT layer) ----
  float* q2=W0; float* k2=W1; float* v2=W2;      // tb1,fb dead
  { dim3 g((HID+63)/64,(NN+63)/64);
    k_gemm3<<<g,256,0,stream>>>(h1,Wq2,Wk2,Wv2,q2,k2,v2,NN,HID,HID); }
  float* logit2=W3;                              // h1a dead
  k_elogits<<<(P+3)/4,256,0,stream>>>(q2,k2,esrc,edst,nullptr,nullptr,nullptr,logit2,P,0);
  float* wght2=W4;                               // hb dead
  k_softmax<<<NN,256,0,stream>>>(logit2,iptr,iidx,wght2);
  float* agg2=W6;                                // aggb dead
  k_agg<<<NN,512,0,stream>>>(wght2,v2,esrc,iptr,iidx,agg2);
  float* o2=W0;                                  // q2 dead
  GEMM(agg2,Wo2,nullptr,nullptr,o2,NN,HID,HID,0);
  float* h2a=W1;                                 // k2 dead
  k_lnadd<<<NN,256,0,stream>>>(h1,o2,h2a);
  float* tb2=W2;                                 // spans W2..W3 (v2,logit2 dead); NN x 1024
  GEMM(h2a,Wf2a,nullptr,nullptr,tb2,NN,1024,HID,1);
  float* f2=W0;                                  // o2 dead
  GEMM(tb2,Wf2b,nullptr,nullptr,f2,NN,HID,1024,0);
  k_lnadd<<<NN,256,0,stream>>>(h2a,f2,out);
}

// Round 10
// 28247.281 us; speedup vs baseline: 1.1646x; 1.0019x over previous
//
#include <hip/hip_runtime.h>
#include <hip/hip_cooperative_groups.h>
#include <math.h>

#define NN 1147
#define HID 512
#define LDAe 1152
#define LDQ 1152
#define LDD 1147
#define EPS32 5.9604644775390625e-08f
#define SAFMIN32 1.17549435e-38f
#define I0E 1026   // endgame start iteration (m = 120 at entry)
#define TGRID 64   // persistent tridiag grid (64 blocks x 1024 thr = 1024 row-slots)
#define TBLK 1024
#define GENSTRIDE 16  // one 64B line per block for the replicated release word

struct EDMeta { int K; int nrot; int early; float rho; };
struct ETree { int st[64]; int sz[64]; int cnt; };
struct MergeLvl { int cnt; int st[32]; int n1[32]; int n2[32]; };

__device__ __forceinline__ float lapy2f(float x, float y){
  float xa=fabsf(x), ya=fabsf(y), w=fmaxf(xa,ya), z2=fminf(xa,ya);
  if (z2==0.f) return w;
  float q=z2/w; return w*sqrtf(1.f+q*q);
}
__device__ __forceinline__ void slartg(float ff, float gg, float* c, float* s, float* r){
  if (gg==0.f){ *c=1.f; *s=0.f; *r=ff; }
  else if (ff==0.f){ *c=0.f; *s=copysignf(1.f,gg); *r=fabsf(gg); }
  else {
    float d=sqrtf(ff*ff+gg*gg);
    *c=fabsf(ff)/d;
    *r=copysignf(d,ff);
    *s=gg/(*r);
  }
}
__device__ void slaev2(float a, float b, float cc, float* rt1, float* rt2, float* cs1, float* sn1){
  float sm=a+cc, df=a-cc, adf=fabsf(df), tb=b+b, ab=fabsf(tb);
  float acmx, acmn;
  if (fabsf(a)>fabsf(cc)){ acmx=a; acmn=cc; } else { acmx=cc; acmn=a; }
  float rt;
  if (adf>ab) rt=adf*sqrtf(1.f+(ab/adf)*(ab/adf));
  else if (adf<ab) rt=ab*sqrtf(1.f+(adf/ab)*(adf/ab));
  else rt=ab*sqrtf(2.f);
  int sgn1;
  if (sm<0.f){ *rt1=0.5f*(sm-rt); sgn1=-1; *rt2=(acmx/(*rt1))*acmn-(b/(*rt1))*b; }
  else if (sm>0.f){ *rt1=0.5f*(sm+rt); sgn1=1; *rt2=(acmx/(*rt1))*acmn-(b/(*rt1))*b; }
  else { *rt1=0.5f*rt; *rt2=-0.5f*rt; sgn1=1; }
  int sgn2; float cs;
  if (df>=0.f){ cs=df+rt; sgn2=1; } else { cs=df-rt; sgn2=-1; }
  float acs=fabsf(cs);
  if (acs>ab){ float ct=-tb/cs; *sn1=1.f/sqrtf(1.f+ct*ct); *cs1=ct*(*sn1); }
  else {
    if (ab==0.f){ *cs1=1.f; *sn1=0.f; }
    else { float tn=-cs/tb; *cs1=1.f/sqrtf(1.f+tn*tn); *sn1=tn*(*cs1); }
  }
  if (sgn1==sgn2){ float tn=*cs1; *cs1=-(*sn1); *sn1=tn; }
}
// LAPACK dlamrg, 0-based; works on global or LDS pointers
__device__ void lamrg0(int n1,int n2,const float* a,int dtrd1,int dtrd2,int* idx){
  int n1sv=n1,n2sv=n2;
  int ind1=(dtrd1>0)?0:(n1-1);
  int ind2=(dtrd2>0)?n1:(n1+n2-1);
  int i=0;
  while(n1sv>0&&n2sv>0){
    if(a[ind1]<=a[ind2]){idx[i++]=ind1;ind1+=dtrd1;n1sv--;}
    else{idx[i++]=ind2;ind2+=dtrd2;n2sv--;}
  }
  while(n2sv>0){idx[i++]=ind2;ind2+=dtrd2;n2sv--;}
  while(n1sv>0){idx[i++]=ind1;ind1+=dtrd1;n1sv--;}
}

// 256-entry tree reduction, bitwise-identical to the sequential st=128..1
// pairwise tree; wave 0 computes steps 128,64 explicitly, then folds 32..1 via
// shuffles with the same pairwise association. 2 block barriers instead of 9.
__device__ __forceinline__ float tree256(float* red, float* bc, int tid){
  __syncthreads();
  if (tid<64){
    float b=(red[tid]+red[tid+128])+(red[tid+64]+red[tid+192]);
    b+=__shfl_down(b,32,64);
    b+=__shfl_down(b,16,64);
    b+=__shfl_down(b,8,64);
    b+=__shfl_down(b,4,64);
    b+=__shfl_down(b,2,64);
    b+=__shfl_down(b,1,64);
    if (tid==0) *bc=b;
  }
  __syncthreads();
  return *bc;
}

// ---------------- utility ----------------
__global__ __launch_bounds__(256) void k_zero_f(float* p, int n){
  int i = blockIdx.x*256+threadIdx.x; if (i<n) p[i]=0.f;
}
__global__ __launch_bounds__(256) void k_zero_i(int* p, int n){
  int i = blockIdx.x*256+threadIdx.x; if (i<n) p[i]=0;
}

// ---------------- Laplacian ----------------
__global__ __launch_bounds__(256) void k_adj(const int* __restrict__ src, const int* __restrict__ dst,
                                             float* __restrict__ A, int P){
  int p = blockIdx.x*256+threadIdx.x;
  if (p>=P) return;
  int s=src[p], d=dst[p];
  A[(size_t)s*LDAe+d]=1.f;
  A[(size_t)d*LDAe+s]=1.f;
}
__global__ __launch_bounds__(256) void k_deg(const float* __restrict__ A, float* __restrict__ dinv){
  int row=blockIdx.x; int tid=threadIdx.x;
  __shared__ float red[256];
  float s=0.f;
  for (int c=tid;c<NN;c+=256) s+=A[(size_t)row*LDAe+c];
  red[tid]=s; __syncthreads();
  for(int st=128;st;st>>=1){ if(tid<st) red[tid]+=red[tid+st]; __syncthreads(); }
  if(tid==0) dinv[row]=1.f/sqrtf(fmaxf(red[0],1.f));
}
__global__ __launch_bounds__(256) void k_lap(float* __restrict__ A, const float* __restrict__ dinv){
  int row=blockIdx.y; int col=blockIdx.x*256+threadIdx.x;
  if (col>=NN) return;
  size_t idx=(size_t)row*LDAe+col;
  float v=A[idx];
  float v1=(dinv[row]*v)*dinv[col];
  float v2=(dinv[col]*v)*dinv[row];
  A[idx] = ((row==col)?1.f:0.f) - 0.5f*(v1+v2);
}

// ---------------- device-scope (cross-XCD coherent) accessors ----------------
__device__ __forceinline__ float dload(const float* p){
  return __hip_atomic_load(p, __ATOMIC_RELAXED, __HIP_MEMORY_SCOPE_AGENT);
}
__device__ __forceinline__ void dstore(float* p, float v){
  __hip_atomic_store(p, v, __ATOMIC_RELAXED, __HIP_MEMORY_SCOPE_AGENT);
}

// ---------------- fence-free hierarchical grid barrier, contention-free release ----------------
// Retired blocks store 0x7FFFFFFF once and exit; their flag permanently satisfies
// block0's arrival poll.
__device__ __forceinline__ void gbar(unsigned* flags, unsigned* genrep, unsigned tgt){
  __syncthreads();
  if (threadIdx.x==0)
    __hip_atomic_store(&flags[blockIdx.x], tgt, __ATOMIC_RELAXED, __HIP_MEMORY_SCOPE_AGENT);
  if (blockIdx.x==0){
    if (threadIdx.x<TGRID){
      while (__hip_atomic_load(&flags[threadIdx.x], __ATOMIC_RELAXED, __HIP_MEMORY_SCOPE_AGENT) < tgt)
        __builtin_amdgcn_s_sleep(1);
    }
    __syncthreads();
    if (threadIdx.x<TGRID)
      __hip_atomic_store(&genrep[threadIdx.x*GENSTRIDE], tgt, __ATOMIC_RELAXED, __HIP_MEMORY_SCOPE_AGENT);
  } else {
    if (threadIdx.x==0){
      while (__hip_atomic_load(&genrep[blockIdx.x*GENSTRIDE], __ATOMIC_RELAXED, __HIP_MEMORY_SCOPE_AGENT) < tgt)
        __builtin_amdgcn_s_sleep(1);
    }
    __syncthreads();
  }
}

// ---------------- tridiagonalization: persistent, single-writer ownership ----------------
// 64 blocks x 1024 threads = 1024 row-slots; slot s owns rows s and s+1024.
// Blocks 8..63 RETIRE once i >= 16b+15 (flag = MAX, exit).
__global__ __launch_bounds__(1024) void k_trid(float* __restrict__ A, float* __restrict__ evec,
    float* __restrict__ tauv, float* __restrict__ scalv, float* __restrict__ pv2,
    float* __restrict__ pub4, unsigned* __restrict__ flags, unsigned* __restrict__ genrep){
  __shared__ float vbuf[2][1152];
  __shared__ float pcur[1152];
  __shared__ float pubc[1152];
  __shared__ float red[256];
  __shared__ float bcv;
  int tid=threadIdx.x, bid=blockIdx.x;
  int wv=tid>>6, lane=tid&63;
  unsigned tgt=0;
  float tau, scal;
  // ---- prologue: column-0 scalars (redundant), p_0 over own rows, publish row 1 ----
  {
    const float* row0=A;
    int m0=NN-1;
    if (tid<256){
      float s=0.f;
      for(int t=tid;t<m0-1;t+=256){ float x=row0[2+t]; s+=x*x; }
      red[tid]=s;
    }
    float xn2=tree256(red,&bcv,tid);
    float alpha=row0[1];
    float beta;
    if(xn2==0.f){ tau=0.f; beta=alpha; scal=0.f; }
    else { beta=-copysignf(sqrtf(alpha*alpha+xn2),alpha); tau=(beta-alpha)/beta; scal=1.f/(alpha-beta); }
    if(bid==0&&tid==0){ evec[0]=beta; tauv[0]=tau; scalv[0]=scal; }
    for(int t=tid;t<m0;t+=TBLK) vbuf[0][t]=row0[1+t];
    __syncthreads();
    for(int rr=0;rr<2;rr++){
      int r=16*bid+wv+rr*1024;
      if(r<1||r>=NN) continue;
      const float* arow=A+(size_t)r*LDAe+1;
      float acc=0.f;
      for(int c=lane;c<m0;c+=64){
        float v=(c==0)?1.f:vbuf[0][c]*scal;
        acc+=arow[c]*v;
      }
      for(int o=32;o;o>>=1) acc+=__shfl_down(acc,o,64);
      if(lane==0) dstore(&pv2[r],acc);
    }
    if(bid==0&&wv==1){  // owner of row 1 publishes original row 1 (cols >= 2)
      const float* r1=A+(size_t)LDAe;
      for(int c=2+lane;c<NN;c+=64) dstore(&pub4[1280+c],r1[c]);
    }
  }
  gbar(flags,genrep,++tgt);
  int cur=0;
  for(int i=0;i<I0E;i++){
    // retirement: blocks >=8 with no remaining rows exit forever
    if (bid>=8 && i>=16*bid+15){
      if (tid==0)
        __hip_atomic_store(&flags[bid], 0x7FFFFFFFu, __ATOMIC_RELAXED, __HIP_MEMORY_SCOPE_AGENT);
      return;
    }
    int m=NN-1-i, mp=m-1;
    float* vcur=vbuf[cur]; float* nxt=vbuf[cur^1];
    const float* pvs=pv2+(size_t)(i&1)*1280;
    const float* pbs=pub4+(size_t)((i+1)&3)*1280;
    // fused stage + s=v.p partials (thr 0-255) ; pivot-row stage (thr 256-1023)
    if (tid<256){
      float s=0.f;
      for(int t=tid;t<m;t+=256){
        float pv=dload(&pvs[(i+1)+t]);
        pcur[t]=pv;
        float v=(t==0)?1.f:vcur[t]*scal;
        s+=pv*v;
      }
      red[tid]=s;
    } else {
      for(int t=tid-256;t<mp;t+=768) pubc[t]=dload(&pbs[(i+2)+t]);
    }
    float sv=tree256(red,&bcv,tid);
    float c2=tau*tau*sv*0.5f;
    const float vz=1.f;
    float wR0=tau*pcur[0]-c2*vz;
    // fused next-pivot-row + norm partials (original norm assignment/order)
    if (tid<256){
      float s2=0.f;
      if (tid==0){
        float vC=vcur[1]*scal;
        float wC=tau*pcur[1]-c2*vC;
        nxt[0]=pubc[0]-(vz*wC+wR0*vC);
      }
      for(int u=tid+1;u<mp;u+=256){
        float vC=vcur[1+u]*scal;
        float wC=tau*pcur[1+u]-c2*vC;
        float x=pubc[u]-(vz*wC+wR0*vC);
        nxt[u]=x;
        s2+=x*x;
      }
      red[tid]=s2;
    }
    float xn2=tree256(red,&bcv,tid);
    float alpha1=nxt[0];
    float beta1,tau1,scal1;
    if(xn2==0.f){ tau1=0.f; beta1=alpha1; scal1=0.f; }
    else { beta1=-copysignf(sqrtf(alpha1*alpha1+xn2),alpha1); tau1=(beta1-alpha1)/beta1; scal1=1.f/(alpha1-beta1); }
    if(bid==0&&tid==0){ evec[i+1]=beta1; tauv[i+1]=tau1; scalv[i+1]=scal1; }
    // fused own-row pass: rank-2 update + dot with next v (+publish / +pivot overwrite)
    float* pvd=pv2+(size_t)((i+1)&1)*1280;
    float* pbd=pub4+(size_t)((i+2)&3)*1280;
    for(int rr=0;rr<2;rr++){
      int r=16*bid+wv+rr*1024;
      if(r<i+1||r>=NN) continue;
      int tr=r-(i+1);
      float vR=(tr==0)?1.f:vcur[tr]*scal;
      float wR=tau*pcur[tr]-c2*vR;
      float* arow=A+(size_t)r*LDAe;
      if(lane==0) arow[i+1]=arow[i+1]-(vR*wR0+wR*vz);
      if(tr==0){
        // row i+1: store the redundantly-computed values for bitwise consistency
        for(int c=lane;c<mp;c+=64) arow[i+2+c]=nxt[c];
      } else {
        float acc=0.f;
        int ispub=(tr==1);  // r == i+2: next iteration's pivot row
        for(int c=lane;c<mp;c+=64){
          float vC=vcur[1+c]*scal;
          float wC=tau*pcur[1+c]-c2*vC;
          float val=arow[i+2+c]-(vR*wC+wR*vC);
          arow[i+2+c]=val;
          float v1=(c==0)?1.f:nxt[c]*scal1;
          acc+=val*v1;
          if(ispub) dstore(&pbd[(i+2)+c],val);
        }
        for(int o=32;o;o>>=1) acc+=__shfl_down(acc,o,64);
        if(lane==0) dstore(&pvd[r],acc);
      }
    }
    gbar(flags,genrep,++tgt);
    cur^=1; tau=tau1; scal=scal1;
  }
}
// endgame: iterations I0E..NN-2 entirely in LDS (121x121 trailing tile)
__global__ __launch_bounds__(256) void k_tend(float* __restrict__ A, float* __restrict__ evec,
    float* __restrict__ tauv, float* __restrict__ scalv){
  __shared__ float T[121][122];
  __shared__ float red[256];
  __shared__ float bct;
  __shared__ float pl[121];
  __shared__ float el[121], tl[121], sl[121];
  __shared__ float sh3[2];
  int tid=threadIdx.x;
  for(int e=tid;e<121*121;e+=256){ int r=e/121,c=e%121; T[r][c]=A[(size_t)(I0E+r)*LDAe + I0E+c]; }
  __syncthreads();
  for(int li=0; li<120; ++li){
    int m=120-li;
    float s=0.f;
    for(int t=tid;t<m-1;t+=256){ float x=T[li][li+2+t]; s+=x*x; }
    red[tid]=s;
    float xn2t=tree256(red,&bct,tid);
    if(tid==0){
      float alpha=T[li][li+1], xn2=xn2t;
      float beta,tau,scal;
      if(xn2==0.f){ tau=0.f; beta=alpha; scal=0.f; }
      else { beta=-copysignf(sqrtf(alpha*alpha+xn2),alpha); tau=(beta-alpha)/beta; scal=1.f/(alpha-beta); }
      el[li]=beta; tl[li]=tau; sl[li]=scal;
      sh3[0]=tau; sh3[1]=scal;
    }
    __syncthreads();
    float tau=sh3[0], scal=sh3[1];
    if(tid<m){
      float acc=0.f;
      for(int c=0;c<m;c++){
        float v=(c==0)?1.f:T[li][li+1+c]*scal;
        acc+=T[li+1+tid][li+1+c]*v;
      }
      pl[tid]=acc;
    }
    __syncthreads();
    s=0.f;
    for(int t=tid;t<m;t+=256){
      float v=(t==0)?1.f:T[li][li+1+t]*scal;
      s+=pl[t]*v;
    }
    red[tid]=s;
    float sv=tree256(red,&bct,tid);
    float c2=tau*tau*sv*0.5f;
    for(int e=tid;e<m*m;e+=256){
      int r=e/m, c=e%m;
      float vR=(r==0)?1.f:T[li][li+1+r]*scal;
      float vC=(c==0)?1.f:T[li][li+1+c]*scal;
      float wR=tau*pl[r]-c2*vR;
      float wC=tau*pl[c]-c2*vC;
      T[li+1+r][li+1+c]-=vR*wC+wR*vC;
    }
    __syncthreads();
  }
  for(int e=tid;e<121*121;e+=256){ int r=e/121,c=e%121; A[(size_t)(I0E+r)*LDAe + I0E+c]=T[r][c]; }
  for(int t=tid;t<120;t+=256){ evec[I0E+t]=el[t]; tauv[I0E+t]=tl[t]; scalv[I0E+t]=sl[t]; }
}

// ---------------- fused harvest + sstedc scale + cuts (1 block) ----------------
__global__ __launch_bounds__(256) void k_prep_ed(const float* __restrict__ A, float* __restrict__ D,
                                                 float* __restrict__ E, ETree t){
  __shared__ float red[256];
  int tid=threadIdx.x;
  for(int i=tid;i<NN;i+=256) D[i]=A[(size_t)i*LDAe+i];
  __syncthreads();
  float m=0.f;
  for(int i=tid;i<NN;i+=256) m=fmaxf(m,fabsf(D[i]));
  for(int i=tid;i<NN-1;i+=256) m=fmaxf(m,fabsf(E[i]));
  red[tid]=m; __syncthreads();
  for(int s=128;s;s>>=1){ if(tid<s) red[tid]=fmaxf(red[tid],red[tid+s]); __syncthreads(); }
  float mul=1.f/red[0];
  __syncthreads();
  for(int i=tid;i<NN;i+=256) D[i]*=mul;
  for(int i=tid;i<NN-1;i+=256) E[i]*=mul;
  __syncthreads();
  if (tid>0 && tid<t.cnt){
    int cut=t.st[tid];
    float ae=fabsf(E[cut-1]);
    D[cut-1]-=ae; D[cut]-=ae;
  }
}

// ---------------- ssteqr('I'), one WAVE per leaf, d/e AND z in LDS ----------------
__device__ void steqr1w(int n, float* d, float* e, float* z, int ldz, int lane){
  if (n<=1) return;
  const float eps=EPS32, eps2=EPS32*EPS32, safmin=SAFMIN32;
  float workc[32], works[32];
  int nmaxit=n*30, jtot=0;
  int l1=0;
  for(;;){
    if (l1>n-1) break;
    if (l1>0) e[l1-1]=0.f;
    int m;
    for(m=l1;m<n-1;m++){
      float tst=fabsf(e[m]);
      if (tst==0.f) break;
      if (tst<=(sqrtf(fabsf(d[m]))*sqrtf(fabsf(d[m+1])))*eps){ e[m]=0.f; break; }
    }
    int l=l1, lend=m, lsv=l, lendsv=lend;
    l1=m+1;
    if (lend==l) continue;
    float anorm=0.f;
    for(int i=l;i<=lend;i++) anorm=fmaxf(anorm,fabsf(d[i]));
    for(int i=l;i<lend;i++) anorm=fmaxf(anorm,fabsf(e[i]));
    if (anorm==0.f) continue;
    if (fabsf(d[lend])<fabsf(d[l])){ lend=lsv; l=lendsv; }
    float c,s,g,r,p,f,b,rt1,rt2;
    if (lend>l){
      for(;;){
        int mm;
        for(mm=l;mm<lend;mm++){
          float tst=e[mm]*e[mm];
          if (tst<=(eps2*fabsf(d[mm]))*fabsf(d[mm+1])+safmin) break;
        }
        if (mm<lend) e[mm]=0.f;
        p=d[l];
        if (mm==l){ d[l]=p; l++; if (l<=lend) continue; else break; }
        if (mm==l+1){
          slaev2(d[l],e[l],d[l+1],&rt1,&rt2,&c,&s);
          for(int row=lane;row<n;row+=64){
            float t1=z[(size_t)(l+1)*ldz+row];
            z[(size_t)(l+1)*ldz+row]=c*t1 - s*z[(size_t)l*ldz+row];
            z[(size_t)l*ldz+row]=s*t1 + c*z[(size_t)l*ldz+row];
          }
          d[l]=rt1; d[l+1]=rt2; e[l]=0.f;
          l+=2;
          if (l<=lend) continue; else break;
        }
        if (jtot==nmaxit) break;
        jtot++;
        g=(d[l+1]-p)/(2.f*e[l]);
        r=lapy2f(g,1.f);
        g=d[mm]-p+(e[l]/(g+copysignf(r,g)));
        s=1.f; c=1.f; p=0.f;
        for(int i=mm-1;i>=l;i--){
          f=s*e[i]; b=c*e[i];
          slartg(g,f,&c,&s,&r);
          if (i!=mm-1) e[i+1]=r;
          g=d[i+1]-p;
          r=(d[i]-g)*s+2.f*c*b;
          p=s*r;
          d[i+1]=g+p;
          g=c*r-b;
          workc[i-l]=c; works[i-l]=-s;
        }
        for(int j2=mm-1;j2>=l;j2--){
          float cc=workc[j2-l], ss2=works[j2-l];
          if (cc!=1.f||ss2!=0.f)
            for(int row=lane;row<n;row+=64){
              float t1=z[(size_t)(j2+1)*ldz+row];
              z[(size_t)(j2+1)*ldz+row]=cc*t1 - ss2*z[(size_t)j2*ldz+row];
              z[(size_t)j2*ldz+row]=ss2*t1 + cc*z[(size_t)j2*ldz+row];
            }
        }
        d[l]=d[l]-p;
        e[l]=g;
      }
    } else {
      for(;;){
        int mm;
        for(mm=l;mm>lend;mm--){
          float tst=e[mm-1]*e[mm-1];
          if (tst<=(eps2*fabsf(d[mm]))*fabsf(d[mm-1])+safmin) break;
        }
        if (mm>lend) e[mm-1]=0.f;
        p=d[l];
        if (mm==l){ d[l]=p; l--; if (l>=lend) continue; else break; }
        if (mm==l-1){
          slaev2(d[l-1],e[l-1],d[l],&rt1,&rt2,&c,&s);
          for(int row=lane;row<n;row+=64){
            float t1=z[(size_t)l*ldz+row];
            z[(size_t)l*ldz+row]=c*t1 - s*z[(size_t)(l-1)*ldz+row];
            z[(size_t)(l-1)*ldz+row]=s*t1 + c*z[(size_t)(l-1)*ldz+row];
          }
          d[l-1]=rt1; d[l]=rt2; e[l-1]=0.f;
          l-=2;
          if (l>=lend) continue; else break;
        }
        if (jtot==nmaxit) break;
        jtot++;
        g=(d[l-1]-p)/(2.f*e[l-1]);
        r=lapy2f(g,1.f);
        g=d[mm]-p+(e[l-1]/(g+copysignf(r,g)));
        s=1.f; c=1.f; p=0.f;
        for(int i=mm;i<=l-1;i++){
          f=s*e[i]; b=c*e[i];
          slartg(g,f,&c,&s,&r);
          if (i!=mm) e[i-1]=r;
          g=d[i]-p;
          r=(d[i+1]-g)*s+2.f*c*b;
          p=s*r;
          d[i]=g+p;
          g=c*r-b;
          workc[i-mm]=c; works[i-mm]=s;
        }
        for(int j2=mm;j2<=l-1;j2++){
          float cc=workc[j2-mm], ss2=works[j2-mm];
          if (cc!=1.f||ss2!=0.f)
            for(int row=lane;row<n;row+=64){
              float t1=z[(size_t)(j2+1)*ldz+row];
              z[(size_t)(j2+1)*ldz+row]=cc*t1 - ss2*z[(size_t)j2*ldz+row];
              z[(size_t)j2*ldz+row]=ss2*t1 + cc*z[(size_t)j2*ldz+row];
            }
        }
        d[l]=d[l]-p;
        e[l-1]=g;
      }
    }
  }
  for(int ii=1;ii<n;ii++){
    int i=ii-1,k=i; float pp=d[i];
    for(int j2=ii;j2<n;j2++) if (d[j2]<pp){k=j2;pp=d[j2];}
    if (k!=i){
      d[k]=d[i]; d[i]=pp;
      for(int row=lane;row<n;row+=64){
        float t1=z[(size_t)i*ldz+row];
        z[(size_t)i*ldz+row]=z[(size_t)k*ldz+row];
        z[(size_t)k*ldz+row]=t1;
      }
    }
  }
}
__global__ __launch_bounds__(64) void k_ed_leaves(float* D, float* E, float* QM, int* indxq, ETree t){
  int lf=blockIdx.x;
  if (lf>=t.cnt) return;
  int lane=threadIdx.x;
  int st=t.st[lf], n=t.sz[lf];
  __shared__ float dl[32], el[32];
  __shared__ float zloc[32][33];
  for(int i=lane;i<n;i+=64) dl[i]=D[st+i];
  for(int i=lane;i<n-1;i+=64) el[i]=E[st+i];
  for(int e=lane;e<n*n;e+=64){ int c=e/n, r=e%n; zloc[c][r]=(c==r)?1.f:0.f; }
  __syncthreads();
  steqr1w(n, dl, el, &zloc[0][0], 33, lane);
  __syncthreads();
  for(int i=lane;i<n;i+=64){ D[st+i]=dl[i]; indxq[st+i]=i; }
  for(int i=lane;i<n-1;i+=64) E[st+i]=el[i];
  for(int e=lane;e<n*n;e+=64){ int c=e/n, r=e%n; QM[(size_t)(st+c)*LDQ + st+r]=zloc[c][r]; }
}

// ---------------- batched slaed1/slaed2: formz + deflation in LDS ----------------
__global__ __launch_bounds__(256) void k_ed_deflate2(float* __restrict__ D, int* __restrict__ indxq,
    float* __restrict__ dlamda, float* __restrict__ w, float* __restrict__ dstage,
    int* __restrict__ colmap, int* __restrict__ cmtype, int* __restrict__ indxcg,
    int* __restrict__ rotp, int* __restrict__ rotn, float* __restrict__ rotc, float* __restrict__ rots,
    EDMeta* __restrict__ meta, const float* __restrict__ QM, const float* __restrict__ E, MergeLvl lv){
  int mid=blockIdx.x; if(mid>=lv.cnt) return;
  int st=lv.st[mid], n1=lv.n1[mid], n2=lv.n2[mid], n=n1+n2;
  int tid=threadIdx.x;
  __shared__ float zl[1152], dl_[1152], dlam[1152], wl[1152], ds2[1152];
  __shared__ int iq[1152], im[1152], ix[1152], ixp[1152], ict[1152], is2[1152];
  __shared__ float rv[256]; __shared__ int ri[256];
  __shared__ float srho; __shared__ int sK, snrot, searly, simax, sjmax;
  float rr=E[st+n1-1];
  if(tid==0) srho=fabsf(2.f*rr);
  for(int i=tid;i<n;i+=256){
    float v = (i<n1)? QM[(size_t)(st+i)*LDQ + st+n1-1] : QM[(size_t)(st+i)*LDQ + st+n1];
    if(rr<0.f && i>=n1) v=-v;
    zl[i]=v*0.70710678118654752440f;
    dl_[i]=D[st+i];
    int q=indxq[st+i]; if(i>=n1) q+=n1;
    iq[i]=q;
    ict[i]=(i<n1)?1:3;
  }
  __syncthreads();
  // argmax |z| (first-max-wins == serial scan)
  {
    float bv=-1.f; int bi=0;
    for(int i2=tid;i2<n;i2+=256){ float a=fabsf(zl[i2]); if(a>bv){bv=a;bi=i2;} }
    rv[tid]=bv; ri[tid]=bi; __syncthreads();
    for(int stp=128;stp;stp>>=1){
      if(tid<stp){ if(rv[tid+stp]>rv[tid]||(rv[tid+stp]==rv[tid]&&ri[tid+stp]<ri[tid])){rv[tid]=rv[tid+stp];ri[tid]=ri[tid+stp];} }
      __syncthreads();
    }
    if(tid==0) simax=ri[0];
    __syncthreads();
  }
  {
    float bv=-1.f; int bi=0;
    for(int i2=tid;i2<n;i2+=256){ float a=fabsf(dl_[i2]); if(a>bv){bv=a;bi=i2;} }
    rv[tid]=bv; ri[tid]=bi; __syncthreads();
    for(int stp=128;stp;stp>>=1){
      if(tid<stp){ if(rv[tid+stp]>rv[tid]||(rv[tid+stp]==rv[tid]&&ri[tid+stp]<ri[tid])){rv[tid]=rv[tid+stp];ri[tid]=ri[tid+stp];} }
      __syncthreads();
    }
    if(tid==0) sjmax=ri[0];
    __syncthreads();
  }
  if(tid==0){
    for(int i=0;i<n;i++) dlam[i]=dl_[iq[i]];
    lamrg0(n1,n2,dlam,1,1,im);
    for(int i=0;i<n;i++) ix[i]=iq[im[i]];
    float tol=8.f*EPS32*fmaxf(fabsf(dl_[sjmax]),fabsf(zl[simax]));
    float rho=srho;
    int K=0,nrot=0,early=0;
    if(rho*fabsf(zl[simax])<=tol){
      early=1;
      for(int i=0;i<n;i++){ int s2=ix[i]; im[i]=s2; iq[i]=2; ds2[i]=dl_[s2]; is2[i]=i; }
    } else {
      int K2=n; int pj=0; int j=0;
      for(;j<n;j++){ int nj=ix[j]; if(rho*fabsf(zl[nj])<=tol){K2--;ict[nj]=4;ixp[K2]=nj;} else {pj=nj;break;} }
      for(j=j+1;;j++){
        if(j>=n) break;
        int nj=ix[j];
        if(rho*fabsf(zl[nj])<=tol){K2--;ict[nj]=4;ixp[K2]=nj;}
        else {
          float s=zl[pj], c=zl[nj];
          float tau2=lapy2f(c,s);
          float t=dl_[nj]-dl_[pj];
          c=c/tau2; s=-s/tau2;
          if(fabsf(t*c*s)<=tol){
            zl[nj]=tau2; zl[pj]=0.f;
            if(ict[nj]!=ict[pj]) ict[nj]=2;
            ict[pj]=4;
            rotp[st+nrot]=pj; rotn[st+nrot]=nj; rotc[st+nrot]=c; rots[st+nrot]=s; nrot++;
            float t2=dl_[pj]*c*c + dl_[nj]*s*s;
            dl_[nj]=dl_[pj]*s*s + dl_[nj]*c*c;
            dl_[pj]=t2;
            K2--;
            int i2=1;
            for(;;){
              if(K2+i2<=n-1 && dl_[pj]<dl_[ixp[K2+i2]]){ ixp[K2+i2-1]=ixp[K2+i2]; ixp[K2+i2]=pj; i2++; }
              else { ixp[K2+i2-1]=pj; break; }
            }
            pj=nj;
          } else {
            dlam[K]=dl_[pj]; wl[K]=zl[pj]; ixp[K]=pj; K++;
            pj=nj;
          }
        }
      }
      dlam[K]=dl_[pj]; wl[K]=zl[pj]; ixp[K]=pj; K++;
      int ctot[5]={0,0,0,0,0};
      for(int i=0;i<n;i++) ctot[ict[i]]++;
      int psm[5]; psm[1]=0; psm[2]=ctot[1]; psm[3]=psm[2]+ctot[2]; psm[4]=psm[3]+ctot[3];
      for(int jj=0;jj<n;jj++){
        int js=ixp[jj]; int ct=ict[js];
        int slot=psm[ct]++;
        im[slot]=js; is2[slot]=jj; ds2[slot]=dl_[js]; iq[slot]=ct;
      }
    }
    sK=K; snrot=nrot; searly=early;
  }
  __syncthreads();
  int K=sK;
  for(int i=tid;i<n;i+=256){
    colmap[st+i]=im[i];
    cmtype[st+i]=iq[i];
    indxcg[st+i]=is2[i];
    dstage[st+i]=ds2[i];
    if(i<K){ dlamda[st+i]=dlam[i]; w[st+i]=wl[i]; }
  }
  if(tid==0){ meta[mid].K=K; meta[mid].nrot=snrot; meta[mid].early=searly; meta[mid].rho=srho; }
}

// batched Givens application: row-parallel; per-thread sequential over rotations.
// Chain-cache: rotations chain (rotp[k+1]==rotn[k] for merged runs), so the value
// this thread just computed for column rotn[k] is usually the next rotation's x.
// Carrying it in a register reads the IDENTICAL value (same-thread load-after-store)
// while breaking the dependent global-latency chain.
__global__ __launch_bounds__(256) void k_ed_rot2(float* __restrict__ QM, const int* __restrict__ rotp,
    const int* __restrict__ rotn, const float* __restrict__ rotc, const float* __restrict__ rots,
    const EDMeta* __restrict__ meta, MergeLvl lv){
  int mid=blockIdx.y; if(mid>=lv.cnt) return;
  int st=lv.st[mid], n=lv.n1[mid]+lv.n2[mid];
  int row=blockIdx.x*256+threadIdx.x;
  if(row>=n) return;
  int nr=meta[mid].nrot;
  int prevn=-1; float cached=0.f;
  for(int k=0;k<nr;k++){
    int pc=rotp[st+k], nc=rotn[st+k];
    size_t ip=(size_t)(st+pc)*LDQ+st+row;
    size_t iq2=(size_t)(st+nc)*LDQ+st+row;
    float c=rotc[st+k], s=rots[st+k];
    float x=(pc==prevn)? cached : QM[ip];
    float y=(nc==prevn)? cached : QM[iq2];
    float newx=c*x+s*y;
    float newy=c*y-s*x;
    QM[ip]=newx;
    QM[iq2]=newy;
    prevn=nc; cached=newy;
  }
}
// batched gather of grouped columns into Q2 (zero-padded per column type)
__global__ __launch_bounds__(256) void k_ed_permute(const float* __restrict__ QM, float* __restrict__ Q2,
    const int* __restrict__ colmap, const int* __restrict__ cmtype, MergeLvl lv){
  int mid=blockIdx.z; if(mid>=lv.cnt) return;
  int st=lv.st[mid], n1=lv.n1[mid], n=n1+lv.n2[mid];
  int row=blockIdx.x*256+threadIdx.x;
  int slot=blockIdx.y;
  if(row>=n||slot>=n) return;
  int src=colmap[st+slot], ct=cmtype[st+slot];
  float v=QM[(size_t)(st+src)*LDQ + st+row];
  if(ct==1&&row>=n1) v=0.f;
  else if(ct==3&&row<n1) v=0.f;
  Q2[(size_t)(st+slot)*LDQ + st+row]=v;
}

// ---------------- slaed4-style secular root (f64, safeguarded) ----------------
__device__ void ed4_general(int K, int j, const float* __restrict__ dl, const float* __restrict__ wv,
                            double rho, float* __restrict__ dcol, float* __restrict__ lamout){
  bool last=(j==K-1);
  bool orgati=true; double org, lo, hi;
  int i0,i1;
  if (!last){
    i0=j; i1=j+1;
    double dj=(double)dl[j];
    double del=(double)dl[j+1]-dj, mid=0.5*del;
    double g0=1.0/rho;
    for(int i=0;i<K;i++){ double de=((double)dl[i]-dj)-mid; double zi=(double)wv[i]; g0+=zi*zi/de; }
    if (g0>0.0){ orgati=true; org=dj; lo=0.0; hi=mid; }
    else { orgati=false; org=(double)dl[j+1]; lo=-mid; hi=0.0; }
  } else {
    i0=K-2; i1=K-1;
    org=(double)dl[K-1];
    double mid=0.5*rho;
    double g0=1.0/rho;
    for(int i=0;i<K;i++){ double de=((double)dl[i]-org)-mid; double zi=(double)wv[i]; g0+=zi*zi/de; }
    if (g0<=0.0){ lo=mid; hi=rho; } else { lo=0.0; hi=mid; }
  }
  double tau=0.5*(lo+hi);
  for(int it=0; it<60; ++it){
    double g=1.0/rho, gpsi=0.0, gphi=0.0;
    for(int i=0;i<K;i++){
      double de=((double)dl[i]-org)-tau;
      double zi=(double)wv[i];
      double t=zi/de;
      g+=zi*t;
      if (i<=i0) gpsi+=t*t; else gphi+=t*t;
    }
    double gp=gpsi+gphi;
    if (g==0.0) break;
    if (g<0.0){ if (tau>lo) lo=tau; } else { if (tau<hi) hi=tau; }
    double dI=((double)dl[i0]-org)-tau, dIP=((double)dl[i1]-org)-tau;
    double c2,A,B,eta;
    if (!last){
      double zi0=(double)wv[i0], zi1=(double)wv[i1];
      if (orgati){ double t1=zi0/dI; c2=g - dIP*gp - ((double)dl[i0]-(double)dl[i1])*t1*t1; }
      else { double t1=zi1/dIP; c2=g - dI*gp - ((double)dl[i1]-(double)dl[i0])*t1*t1; }
      A=(dI+dIP)*g - dI*dIP*gp;
      B=dI*dIP*g;
      if (c2==0.0){
        if (A==0.0){
          if (orgati) A=zi0*zi0+dIP*dIP*gp;
          else A=zi1*zi1+dI*dI*gp;
        }
        eta=B/A;
      } else if (A<=0.0) eta=(A-sqrt(fabs(A*A-4.0*B*c2)))/(2.0*c2);
      else eta=2.0*B/(A+sqrt(fabs(A*A-4.0*B*c2)));
    } else {
      c2=g - dI*gpsi - dIP*gphi;
      if (c2<0.0) c2=fabs(c2);
      A=(dI+dIP)*g - dI*dIP*gp;
      B=dI*dIP*g;
      if (c2==0.0) eta=hi-tau;
      else if (A>=0.0) eta=(A+sqrt(fabs(A*A-4.0*B*c2)))/(2.0*c2);
      else eta=2.0*B/(A-sqrt(fabs(A*A-4.0*B*c2)));
    }
    if (g*eta>=0.0) eta=-g/gp;
    double tn=tau+eta;
    if (!(tn>lo && tn<hi)) tn=0.5*(lo+hi);
    double ch=fabs(tn-tau);
    tau=tn;
    if (ch<=2.220446049250313e-16*(fabs(org)+fabs(tau))) break;
  }
  for(int i=0;i<K;i++) dcol[i]=(float)(((double)dl[i]-org)-tau);
  *lamout=(float)(org+tau);
}

__global__ __launch_bounds__(64) void k_ed_secular(const float* __restrict__ dlamda, const float* __restrict__ w,
    const EDMeta* __restrict__ meta, float* __restrict__ D_, float* __restrict__ DC, MergeLvl lv){
  int mid=blockIdx.y; if(mid>=lv.cnt) return;
  int st=lv.st[mid];
  int K=meta[mid].K;
  int j=blockIdx.x*64+threadIdx.x;
  if (j>=K) return;
  const float* dl=dlamda+st;
  const float* wv=w+st;
  double rho=(double)meta[mid].rho;
  float* dcol=DC+(size_t)(st+j)*LDD;
  if (K==1){
    double lam=(double)dl[0]+rho*(double)wv[0]*(double)wv[0];
    dcol[0]=1.f; D_[st]=(float)lam;
    return;
  }
  if (K==2){
    double d1=(double)dl[0], d2=(double)dl[1], z1=(double)wv[0], z2=(double)wv[1];
    double del=d2-d1, tau, lam, v0, v1;
    if (j==0){
      double ww=1.0+2.0*rho*(z2*z2-z1*z1)/del;
      if (ww>0.0){
        double bq=del+rho*(z1*z1+z2*z2), cq=rho*z1*z1*del;
        tau=2.0*cq/(bq+sqrt(fabs(bq*bq-4.0*cq)));
        lam=d1+tau; v0=-z1/tau; v1=z2/(del-tau);
      } else {
        double bq=-del+rho*(z1*z1+z2*z2), cq=rho*z2*z2*del;
        tau=(bq>0.0)? -2.0*cq/(bq+sqrt(bq*bq+4.0*cq)) : (bq-sqrt(bq*bq+4.0*cq))*0.5;
        lam=d2+tau; v0=-z1/(del+tau); v1=-z2/tau;
      }
    } else {
      double bq=-del+rho*(z1*z1+z2*z2), cq=rho*z2*z2*del;
      tau=(bq>0.0)? (bq+sqrt(bq*bq+4.0*cq))*0.5 : 2.0*cq/(-bq+sqrt(bq*bq+4.0*cq));
      lam=d2+tau; v0=-z1/(del+tau); v1=-z2/tau;
    }
    double nr=sqrt(v0*v0+v1*v1);
    dcol[0]=(float)(v0/nr); dcol[1]=(float)(v1/nr);
    D_[st+j]=(float)lam;
    return;
  }
  float lam;
  ed4_general(K, j, dl, wv, rho, dcol, &lam);
  D_[st+j]=lam;
}

__global__ __launch_bounds__(64) void k_ed_lowner(const float* __restrict__ dlamda, float* __restrict__ w,
    const float* __restrict__ DC, const EDMeta* __restrict__ meta, MergeLvl lv){
  int mid=blockIdx.y; if(mid>=lv.cnt) return;
  int st=lv.st[mid];
  int K=meta[mid].K; if (K<=2) return;
  int i=blockIdx.x*64+threadIdx.x; if (i>=K) return;
  const float* dl=dlamda+st;
  double p=(double)DC[(size_t)(st+i)*LDD+i];
  double di=(double)dl[i];
  for(int j2=0;j2<K;j2++){
    if (j2==i) continue;
    p *= (double)DC[(size_t)(st+j2)*LDD+i]/(di-(double)dl[j2]);
  }
  float val=sqrtf(fmaxf(-(float)p,0.f));
  w[st+i]=copysignf(val,w[st+i]);
}
__global__ __launch_bounds__(256) void k_ed_vecs(const float* __restrict__ w, float* __restrict__ DC,
    const int* __restrict__ indxcg, const EDMeta* __restrict__ meta, MergeLvl lv){
  int mid=blockIdx.y; if(mid>=lv.cnt) return;
  int st=lv.st[mid];
  int K=meta[mid].K;
  int j=blockIdx.x; if (j>=K) return;
  float* dcol=DC+(size_t)(st+j)*LDD;
  const int* indxc=indxcg+st;
  int tid=threadIdx.x;
  if (K==1){ if (tid==0) dcol[0]=1.f; return; }
  if (K==2){
    if (tid==0){
      float a=dcol[0], b=dcol[1];
      float o0=(indxc[0]==0)?a:b;
      float o1=(indxc[1]==0)?a:b;
      dcol[0]=o0; dcol[1]=o1;
    }
    return;
  }
  __shared__ float sv[1152];
  __shared__ double red[256];
  double ss=0.0;
  for(int i=tid;i<K;i+=256){
    float s=w[st+i]/dcol[i];
    sv[i]=s;
    ss+=(double)s*(double)s;
  }
  red[tid]=ss; __syncthreads();
  for(int st2=128;st2;st2>>=1){ if(tid<st2) red[tid]+=red[tid+st2]; __syncthreads(); }
  float tempf=(float)sqrt(red[0]);
  __syncthreads();
  for(int i=tid;i<K;i+=256) dcol[i]=sv[indxc[i]]/tempf;
}
// Qnew(:,0..K-1) = Q2 * DC ; cols K..n-1 copied from Q2 (fused copyback)
__global__ __launch_bounds__(256) void k_gemm_cm2(const float* __restrict__ Q2, const float* __restrict__ DC,
    float* __restrict__ QM, const EDMeta* __restrict__ meta, MergeLvl lv){
  int mid=blockIdx.z; if(mid>=lv.cnt) return;
  int st=lv.st[mid], n=lv.n1[mid]+lv.n2[mid];
  int K=meta[mid].K;
  int br=blockIdx.x*64, bj=blockIdx.y*64;
  if (br>=n||bj>=n) return;
  int tid=threadIdx.x, tr=tid/16, tc=tid%16;
  if (bj>=K){
    for(int i=0;i<4;i++){ int r=br+tr*4+i; if(r>=n)continue;
      for(int j2=0;j2<4;j2++){ int cc=bj+tc*4+j2; if(cc>=n)continue;
        QM[(size_t)(st+cc)*LDQ+st+r]=Q2[(size_t)(st+cc)*LDQ+st+r]; } }
    return;
  }
  __shared__ float As[16][65], Bs[16][65];
  float acc[4][4]={};
  for(int k0=0;k0<K;k0+=16){
    for(int l=0;l<4;l++){
      int e2=tid+l*256;
      int rr=e2&63, ii=e2>>6;
      float av=0.f;
      if (br+rr<n && k0+ii<K) av=Q2[(size_t)(st+k0+ii)*LDQ + st+br+rr];
      As[ii][rr]=av;
      int bi=e2&15, bj2=e2>>4;
      float bv=0.f;
      if (k0+bi<K && bj+bj2<n) bv=DC[(size_t)(st+bj+bj2)*LDD + k0+bi];
      Bs[bi][bj2]=bv;
    }
    __syncthreads();
    #pragma unroll
    for(int kk=0;kk<16;kk++){
      float ar[4],br2[4];
      #pragma unroll
      for(int i=0;i<4;i++) ar[i]=As[kk][tr*4+i];
      #pragma unroll
      for(int j2=0;j2<4;j2++) br2[j2]=Bs[kk][tc*4+j2];
      #pragma unroll
      for(int i=0;i<4;i++)
        #pragma unroll
        for(int j2=0;j2<4;j2++) acc[i][j2]+=ar[i]*br2[j2];
    }
    __syncthreads();
  }
  for(int i=0;i<4;i++){
    int r=br+tr*4+i; if (r>=n) continue;
    for(int j2=0;j2<4;j2++){
      int cc=bj+tc*4+j2; if (cc>=n) continue;
      if (cc<K) QM[(size_t)(st+cc)*LDQ + st+r]=acc[i][j2];
      else      QM[(size_t)(st+cc)*LDQ + st+r]=Q2[(size_t)(st+cc)*LDQ + st+r];
    }
  }
}
// post: D tail restore + merge (lamrg0 on LDS)
__global__ __launch_bounds__(256) void k_ed_post(float* __restrict__ D, const float* __restrict__ dstage,
    int* __restrict__ indxq, const EDMeta* __restrict__ meta, MergeLvl lv){
  int mid=blockIdx.x; if(mid>=lv.cnt) return;
  int st=lv.st[mid], n=lv.n1[mid]+lv.n2[mid];
  int K=meta[mid].K;
  int tid=threadIdx.x;
  __shared__ float dl[1152];
  __shared__ int iq[1152];
  float* Ds=D+st;
  for(int i=tid;i<n;i+=256){
    float v = (i<K)? Ds[i] : dstage[st+i];
    dl[i]=v;
    if (i>=K) Ds[i]=v;
  }
  __syncthreads();
  if (meta[mid].early){
    for(int i=tid;i<n;i+=256) indxq[st+i]=i;
    return;
  }
  if (tid==0) lamrg0(K, n-K, dl, 1, -1, iq);
  __syncthreads();
  for(int i=tid;i<n;i+=256) indxq[st+i]=iq[i];
}

// ---------------- back-transform V = H0 H1 ... V_tri, fused with eigvec gather ----------------
// Stages column indxq[vec+1] of QM directly into LDS (identical values to the old
// k_ed_gather->Vt->stage path; pure copy elimination), then applies the Householder
// chain with unchanged arithmetic, and writes the finished column to Vt once.
__global__ __launch_bounds__(128) void k_backt(const float* __restrict__ A, const float* __restrict__ tauv,
                                               const float* __restrict__ scalv, const float* __restrict__ QM,
                                               const int* __restrict__ indxq, float* __restrict__ Vt){
  __shared__ float cols[2][1168];
  __shared__ float tl[1152], sl[1152];
  int wv=threadIdx.x>>6, lane=threadIdx.x&63;
  int vec=blockIdx.x*2+wv;
  float* cl=cols[wv];
  for(int t=threadIdx.x;t<NN;t+=128){ tl[t]=tauv[t]; sl[t]=scalv[t]; }
  {
    int src=indxq[vec+1];
    const float* qcol=QM+(size_t)src*LDQ;
    for(int t=lane;t<NN;t+=64) cl[t]=qcol[t];
  }
  __syncthreads();
  for(int i=NN-2;i>=0;i--){
    float tau=tl[i];
    if (tau==0.f) continue;
    int m=NN-1-i;
    float scal=sl[i];
    const float* rowi=A+(size_t)i*LDAe;
    float s=0.f;
    for(int t=lane;t<m;t+=64){
      float v=(t==0)?1.f:rowi[i+1+t]*scal;
      s+=v*cl[i+1+t];
    }
    for(int o=32;o;o>>=1) s+=__shfl_down(s,o,64);
    s=__shfl(s,0,64);
    s*=tau;
    for(int t=lane;t<m;t+=64){
      float v=(t==0)?1.f:rowi[i+1+t]*scal;
      cl[i+1+t]-=s*v;
    }
  }
  float* col=Vt+(size_t)vec*NN;
  for(int t=lane;t<NN;t+=64) col[t]=cl[t];
}

// ---------------- transpose Vt[512][1147] -> pe[1147][512] ----------------
__global__ __launch_bounds__(256) void k_transpose(const float* __restrict__ in, float* __restrict__ outp){
  __shared__ float tile[32][33];
  int c0=blockIdx.x*32, r0=blockIdx.y*32;
  int tx=threadIdx.x%32, ty=threadIdx.x/32;
  for(int s=0;s<32;s+=8){
    int r=r0+ty+s, c=c0+tx;
    tile[ty+s][tx]=(r<512 && c<NN)? in[(size_t)r*NN+c] : 0.f;
  }
  __syncthreads();
  for(int s=0;s<32;s+=8){
    int r=c0+ty+s, c=r0+tx;
    if (r<NN && c<512) outp[(size_t)r*512+c]=tile[tx][ty+s];
  }
}

// ---------------- generic f32 GEMM: C = A@B (+bias)(+add)(relu) ----------------
__global__ __launch_bounds__(256) void k_gemm(const float* __restrict__ A, const float* __restrict__ B,
    const float* __restrict__ bias, const float* __restrict__ add, float* __restrict__ C,
    int M, int Nc, int K, int relu){
  __shared__ float As[16][65];
  __shared__ float Bs[16][65];
  int bm=blockIdx.y*64, bn=blockIdx.x*64;
  int tid=threadIdx.x;
  int tr=tid/16, tc=tid%16;
  float acc[4][4]={};
  for(int k0=0;k0<K;k0+=16){
    for(int l=0;l<4;l++){
      int e2=tid+l*256;
      int m_=e2/16, kk=e2%16;
      float av=0.f;
      if (bm+m_<M && k0+kk<K) av=A[(size_t)(bm+m_)*K + k0+kk];
      As[kk][m_]=av;
      int k2=e2/64, n2=e2%64;
      float bv=0.f;
      if (k0+k2<K && bn+n2<Nc) bv=B[(size_t)(k0+k2)*Nc + bn+n2];
      Bs[k2][n2]=bv;
    }
    __syncthreads();
    for(int kk=0;kk<16;kk++){
      float ar[4], br[4];
      #pragma unroll
      for(int i=0;i<4;i++) ar[i]=As[kk][tr*4+i];
      #pragma unroll
      for(int j=0;j<4;j++) br[j]=Bs[kk][tc*4+j];
      #pragma unroll
      for(int i=0;i<4;i++)
        #pragma unroll
        for(int j=0;j<4;j++) acc[i][j]+=ar[i]*br[j];
    }
    __syncthreads();
  }
  for(int i=0;i<4;i++){
    int r=bm+tr*4+i;
    if (r>=M) continue;
    for(int j=0;j<4;j++){
      int c=bn+tc*4+j;
      if (c>=Nc) continue;
      float x=acc[i][j];
      if (bias) x+=bias[c];
      if (add)  x+=add[(size_t)r*Nc+c];
      if (relu) x=fmaxf(x,0.f);
      C[(size_t)r*Nc+c]=x;
    }
  }
}

// ---------------- fused 3-output GEMM (QKV): per-output arithmetic identical to k_gemm ----------------
__global__ __launch_bounds__(256) void k_gemm3(const float* __restrict__ A,
    const float* __restrict__ B0, const float* __restrict__ B1, const float* __restrict__ B2,
    float* __restrict__ C0, float* __restrict__ C1, float* __restrict__ C2,
    int M, int Nc, int K){
  __shared__ float As[16][65];
  __shared__ float Bs[3][16][65];
  int bm=blockIdx.y*64, bn=blockIdx.x*64;
  int tid=threadIdx.x;
  int tr=tid/16, tc=tid%16;
  float acc[3][4][4]={};
  const float* Bp0=B0; const float* Bp1=B1; const float* Bp2=B2;
  for(int k0=0;k0<K;k0+=16){
    for(int l=0;l<4;l++){
      int e2=tid+l*256;
      int m_=e2/16, kk=e2%16;
      float av=0.f;
      if (bm+m_<M && k0+kk<K) av=A[(size_t)(bm+m_)*K + k0+kk];
      As[kk][m_]=av;
      int k2=e2/64, n2=e2%64;
      bool ok=(k0+k2<K && bn+n2<Nc);
      size_t bidx=(size_t)(k0+k2)*Nc + bn+n2;
      Bs[0][k2][n2]= ok? Bp0[bidx]:0.f;
      Bs[1][k2][n2]= ok? Bp1[bidx]:0.f;
      Bs[2][k2][n2]= ok? Bp2[bidx]:0.f;
    }
    __syncthreads();
    for(int kk=0;kk<16;kk++){
      float ar[4];
      #pragma unroll
      for(int i=0;i<4;i++) ar[i]=As[kk][tr*4+i];
      #pragma unroll
      for(int q=0;q<3;q++){
        float br[4];
        #pragma unroll
        for(int j=0;j<4;j++) br[j]=Bs[q][kk][tc*4+j];
        #pragma unroll
        for(int i=0;i<4;i++)
          #pragma unroll
          for(int j=0;j<4;j++) acc[q][i][j]+=ar[i]*br[j];
      }
    }
    __syncthreads();
  }
  for(int i=0;i<4;i++){
    int r=bm+tr*4+i;
    if (r>=M) continue;
    for(int j=0;j<4;j++){
      int c=bn+tc*4+j;
      if (c>=Nc) continue;
      C0[(size_t)r*Nc+c]=acc[0][i][j];
      C1[(size_t)r*Nc+c]=acc[1][i][j];
      C2[(size_t)r*Nc+c]=acc[2][i][j];
    }
  }
}

// ---------------- LayerNorm(x+y) over 512 ----------------
__global__ __launch_bounds__(256) void k_lnadd(const float* __restrict__ x, const float* __restrict__ y,
                                               float* __restrict__ out){
  int row=blockIdx.x; int tid=threadIdx.x;
  __shared__ float red[256];
  size_t base=(size_t)row*HID;
  float v0=x[base+tid]+y[base+tid];
  float v1=x[base+256+tid]+y[base+256+tid];
  red[tid]=v0+v1; __syncthreads();
  for(int st=128;st;st>>=1){ if(tid<st) red[tid]+=red[tid+st]; __syncthreads(); }
  float mean=red[0]*(1.f/512.f);
  __syncthreads();
  float d0=v0-mean, d1=v1-mean;
  red[tid]=d0*d0+d1*d1; __syncthreads();
  for(int st=128;st;st>>=1){ if(tid<st) red[tid]+=red[tid+st]; __syncthreads(); }
  float r=rsqrtf(red[0]*(1.f/512.f)+1e-5f);
  out[base+tid]=d0*r;
  out[base+256+tid]=d1*r;
}

// ---------------- edge-path rank-1 collapse ----------------
__global__ __launch_bounds__(256) void k_prep_uw(const float* __restrict__ We, const float* __restrict__ be,
    const float* __restrict__ We1, float* __restrict__ u, float* __restrict__ w1){
  int c=blockIdx.x*256+threadIdx.x;
  if (c>=HID) return;
  float a=0.f,b=0.f;
  for(int f=0;f<HID;f++){ float m=We1[(size_t)f*HID+c]; a+=We[f]*m; b+=be[f]*m; }
  u[c]=a; w1[c]=b;
}

// ---------------- per-edge logits ----------------
__global__ __launch_bounds__(256) void k_elogits(const float* __restrict__ q, const float* __restrict__ kk,
    const int* __restrict__ src, const int* __restrict__ dst, const float* __restrict__ ew,
    const float* __restrict__ uu, const float* __restrict__ ww, float* __restrict__ logit, int P, int useep){
  int gw=(blockIdx.x*256+threadIdx.x)>>6;
  int lane=threadIdx.x&63;
  if (gw>=P) return;
  int s=src[gw], d=dst[gw];
  const float* kr=kk+(size_t)s*HID;
  const float* qr=q+(size_t)d*HID;
  float a1[8], a2[8];
  #pragma unroll
  for(int j=0;j<8;j++){
    int c=j*64+lane;
    float prod=kr[c]*qr[c];
    if (useep){ a1[j]=prod*uu[c]; a2[j]=prod*ww[c]; }
    else { a1[j]=prod; a2[j]=0.f; }
  }
  #pragma unroll
  for(int o=32;o;o>>=1){
    #pragma unroll
    for(int j=0;j<8;j++){ a1[j]+=__shfl_down(a1[j],o,64); a2[j]+=__shfl_down(a2[j],o,64); }
  }
  if (lane==0){
    float w0 = useep? ew[gw] : 0.f;
    #pragma unroll
    for(int j=0;j<8;j++){
      float lg = useep ? 0.125f*(w0*a1[j]+a2[j]) : 0.125f*a1[j];
      logit[(size_t)gw*8+j]=lg;
    }
  }
}

// ---------------- deterministic CSR by dst ----------------
__global__ __launch_bounds__(256) void k_count(const int* __restrict__ dst, int* __restrict__ cnt, int P){
  int p=blockIdx.x*256+threadIdx.x;
  if (p<P) atomicAdd(&cnt[dst[p]],1);
}
// scan on LDS (single-thread integer scan at LDS latency; exact)
__global__ __launch_bounds__(256) void k_scan(const int* __restrict__ cnt, int* __restrict__ iptr){
  __shared__ int c[NN+1];
  int tid=threadIdx.x;
  for(int i=tid;i<NN;i+=256) c[i]=cnt[i];
  __syncthreads();
  if (tid==0){
    int s=0;
    for(int n=0;n<NN;n++){ int t=c[n]; c[n]=s; s+=t; }
    c[NN]=s;
  }
  __syncthreads();
  for(int i=tid;i<=NN;i+=256) iptr[i]=c[i];
}
__global__ __launch_bounds__(256) void k_fill(const int* __restrict__ dst, const int* __restrict__ iptr,
                                              int* __restrict__ iidx, int P){
  int n=blockIdx.x; int tid=threadIdx.x;
  int lane=tid&63, wv=tid>>6;
  __shared__ int wb[4]; __shared__ int scnt;
  if (tid==0) scnt=iptr[n];
  __syncthreads();
  for(int base=0;base<P;base+=256){
    int p=base+tid;
    bool f=(p<P)&&(dst[p]==n);
    unsigned long long m=__ballot(f);
    if (lane==0) wb[wv]=__popcll(m);
    __syncthreads();
    int off=0;
    #pragma unroll
    for(int i=0;i<4;i++) if (i<wv) off+=wb[i];
    if (f){
      int pre=__popcll(m & ((1ull<<lane)-1ull));
      iidx[scnt+off+pre]=p;
    }
    int tot=wb[0]+wb[1]+wb[2]+wb[3];
    __syncthreads();
    if (tid==0) scnt+=tot;
    __syncthreads();
  }
}

// ---------------- per-dst segment softmax ----------------
__global__ __launch_bounds__(256) void k_softmax(const float* __restrict__ logit, const int* __restrict__ iptr,
    const int* __restrict__ iidx, float* __restrict__ wght){
  int n=blockIdx.x; int tid=threadIdx.x;
  int beg=iptr[n], end=iptr[n+1];
  if (beg==end) return;
  __shared__ float red[256];
  __shared__ float smax[8], sden[8];
  float mx[8];
  #pragma unroll
  for(int h=0;h<8;h++) mx[h]=-1e30f;
  for(int t=beg+tid;t<end;t+=256){
    int e=iidx[t];
    #pragma unroll
    for(int h=0;h<8;h++) mx[h]=fmaxf(mx[h],logit[(size_t)e*8+h]);
  }
  for(int h=0;h<8;h++){
    red[tid]=mx[h]; __syncthreads();
    for(int st=128;st;st>>=1){ if(tid<st) red[tid]=fmaxf(red[tid],red[tid+st]); __syncthreads(); }
    if (tid==0) smax[h]=red[0];
    __syncthreads();
  }
  float sm[8];
  #pragma unroll
  for(int h=0;h<8;h++) sm[h]=0.f;
  for(int t=beg+tid;t<end;t+=256){
    int e=iidx[t];
    #pragma unroll
    for(int h=0;h<8;h++) sm[h]+=expf(logit[(size_t)e*8+h]-smax[h]);
  }
  for(int h=0;h<8;h++){
    red[tid]=sm[h]; __syncthreads();
    for(int st=128;st;st>>=1){ if(tid<st) red[tid]+=red[tid+st]; __syncthreads(); }
    if (tid==0) sden[h]=red[0];
    __syncthreads();
  }
  for(int t=beg+tid;t<end;t+=256){
    int e=iidx[t];
    #pragma unroll
    for(int h=0;h<8;h++) wght[(size_t)e*8+h]=expf(logit[(size_t)e*8+h]-smax[h])/(sden[h]+1e-9f);
  }
}

// ---------------- weighted aggregation per dst node ----------------
__global__ __launch_bounds__(512) void k_agg(const float* __restrict__ wght, const float* __restrict__ vv,
    const int* __restrict__ src, const int* __restrict__ iptr, const int* __restrict__ iidx,
    float* __restrict__ agg){
  int n=blockIdx.x; int c=threadIdx.x; int h=c>>6;
  int beg=iptr[n], end=iptr[n+1];
  float acc=0.f;
  for(int t=beg;t<end;++t){
    int e=iidx[t];
    acc += wght[(size_t)e*8+h]*vv[(size_t)src[e]*HID+c];
  }
  agg[(size_t)n*HID+c]=acc;
}

// =======================================================================
extern "C" void kernel_launch(void* const* d_in, const int* in_sizes, int n_in,
                              void* d_out, int out_size, void* d_ws, size_t ws_size,
                              hipStream_t stream){
  const float* H      = (const float*)d_in[0];
  const float* edge_w = (const float*)d_in[1];
  const int*   esrc   = (const int*)d_in[2];
  const int*   edst   = (const int*)d_in[3];
  const float* W_lin  = (const float*)d_in[4];
  const float* b_lin  = (const float*)d_in[5];
  const float* W_e    = (const float*)d_in[6];
  const float* b_e    = (const float*)d_in[7];
  const float* W_h    = (const float*)d_in[8];
  const float* b_h    = (const float*)d_in[9];
  const float* W_lap  = (const float*)d_in[10];
  const float* b_lap  = (const float*)d_in[11];
  const float* Wq1    = (const float*)d_in[12];
  const float* Wk1    = (const float*)d_in[13];
  const float* Wv1    = (const float*)d_in[14];
  const float* We1    = (const float*)d_in[15];
  const float* Wo1    = (const float*)d_in[16];
  const float* Wf1a   = (const float*)d_in[18];
  const float* Wf1b   = (const float*)d_in[19];
  const float* Wq2    = (const float*)d_in[22];
  const float* Wk2    = (const float*)d_in[23];
  const float* Wv2    = (const float*)d_in[24];
  const float* Wo2    = (const float*)d_in[25];
  const float* Wf2a   = (const float*)d_in[26];
  const float* Wf2b   = (const float*)d_in[27];
  const int P = in_sizes[1];
  float* out = (float*)d_out;

  // ---- workspace: fully disjoint explicit layout (~21.6 MB) ----
  char* base=(char*)d_ws;
  size_t off=0;
  auto AF=[&](size_t n)->float*{ float* r=(float*)(base+off); off+=((n*4+255)/256)*256; return r; };
  auto AI=[&](size_t n)->int*{ int* r=(int*)(base+off); off+=((n*4+255)/256)*256; return r; };
  const size_t SLOT=(size_t)NN*HID;           // 587,264 floats
  float* A   = AF((size_t)NN*LDAe);           // 1,321,344 floats
  float* QM  = AF((size_t)LDQ*NN);            // 1,321,344
  float* Q2  = AF((size_t)LDQ*NN);            // 1,321,344
  float* DC  = AF((size_t)LDD*LDD);           // 1,315,609
  float* dvec  = AF(1280);
  float* evec  = AF(1280);
  float* tauv  = AF(1280);
  float* scalv = AF(1280);
  float* pvec  = AF(1280);
  float* eddl  = AF(1280);
  float* edw   = AF(1280);
  float* edds  = AF(1280);
  float* rotc  = AF(1280);
  float* rots  = AF(1280);
  float* ub    = AF(512);
  float* w1b   = AF(512);
  float* pv2   = AF(2*1280);                  // device-scope p double buffer
  float* pub4  = AF(4*1280);                  // device-scope pivot-row ring
  int* indxq=AI(1280); int* edcm=AI(1280); int* edcmt=AI(1280); int* edic=AI(1280);
  int* rotp=AI(1280); int* rotn=AI(1280);
  EDMeta* meta=(EDMeta*)AI(192);  // 32 structs
  int* icnt=AI(NN); int* iptr=AI(NN+1); int* iidx=AI(P);
  int* barws=AI(2048);                        // flags[64] + genrep[64*16]
  unsigned* flags=(unsigned*)barws;
  unsigned* genrep=(unsigned*)(barws+64);
  (void)ws_size; (void)n_in; (void)out_size;

  // network-phase sub-slots (each SLOT floats; A/QM/Q2 hold 2.25 slots, DC 2.24)
  float* W0=A;        float* W1=A+SLOT;    // A region  (tb layer1 uses W0..W1 contiguous)
  float* W2=QM;       float* W3=QM+SLOT;   // QM region (tb layer2 uses W2..W3 contiguous)
  float* W4=Q2;       float* W5=Q2+SLOT;   // Q2 region
  float* W6=DC;       float* W7=DC+SLOT;   // DC region
  (void)W7;
  float* Vt=W6;   // written by k_backt (DC dead after last merge)
  float* pe=W2;   // written after backt (QM dead)

  auto GEMM=[&](const float*Am,const float*Bm,const float*bias,const float*add,float*C,int M,int Nc,int K,int relu){
    dim3 g((Nc+63)/64,(M+63)/64);
    k_gemm<<<g,256,0,stream>>>(Am,Bm,bias,add,C,M,Nc,K,relu);
  };

  // ---- Laplacian (into A) ----
  {
    int ntot=NN*LDAe;
    k_zero_f<<<(ntot+255)/256,256,0,stream>>>(A,ntot);
    k_adj<<<(P+255)/256,256,0,stream>>>(esrc,edst,A,P);
    k_deg<<<NN,256,0,stream>>>(A,pvec);  // pvec reused as dinv
    dim3 g((NN+255)/256,NN);
    k_lap<<<g,256,0,stream>>>(A,pvec);
  }
  // ---- tridiagonalization: persistent ownership kernel (fence-free) + LDS endgame ----
  k_zero_i<<<8,256,0,stream>>>(barws,2048);
  {
    void* kargs[] = { (void*)&A, (void*)&evec, (void*)&tauv, (void*)&scalv,
                      (void*)&pv2, (void*)&pub4, (void*)&flags, (void*)&genrep };
    hipLaunchCooperativeKernel((const void*)k_trid, dim3(TGRID), dim3(TBLK), kargs, 0, stream);
  }
  k_tend<<<1,256,0,stream>>>(A,evec,tauv,scalv);

  // ---- sstedc: harvest+scale+cuts (fused), tree, leaves ----
  ETree tr;
  {
    int tmp[64]; tmp[0]=NN; int cnt=1;
    while (tmp[cnt-1]>25){
      for(int j2=cnt-1;j2>=0;j2--){ int p=tmp[j2]; tmp[2*j2]=p/2; tmp[2*j2+1]=p-p/2; }
      cnt*=2;
    }
    tr.cnt=cnt;
    int acc=0;
    for(int j2=0;j2<cnt;j2++){ tr.st[j2]=acc; tr.sz[j2]=tmp[j2]; acc+=tmp[j2]; }
  }
  k_prep_ed<<<1,256,0,stream>>>(A,dvec,evec,tr);
  k_zero_f<<<(LDQ*NN+255)/256,256,0,stream>>>(QM,LDQ*NN);
  k_ed_leaves<<<tr.cnt,64,0,stream>>>(dvec,evec,QM,indxq,tr);

  // ---- slaed0 merge tree, level-batched ----
  {
    int csz[64], cst[64], cn=tr.cnt;
    for(int i=0;i<cn;i++){ csz[i]=tr.sz[i]; cst[i]=tr.st[i]; }
    while (cn>1){
      MergeLvl lv; lv.cnt=cn/2;
      int maxn=0;
      for(int i=0;i<cn/2;i++){
        lv.st[i]=cst[2*i]; lv.n1[i]=csz[2*i]; lv.n2[i]=csz[2*i+1];
        int n=lv.n1[i]+lv.n2[i]; if(n>maxn) maxn=n;
      }
      k_ed_deflate2<<<lv.cnt,256,0,stream>>>(dvec,indxq,eddl,edw,edds,edcm,edcmt,edic,
                                             rotp,rotn,rotc,rots,meta,QM,evec,lv);
      { dim3 gr((maxn+255)/256,lv.cnt);
        k_ed_rot2<<<gr,256,0,stream>>>(QM,rotp,rotn,rotc,rots,meta,lv); }
      { dim3 gp((maxn+255)/256,maxn,lv.cnt);
        k_ed_permute<<<gp,256,0,stream>>>(QM,Q2,edcm,edcmt,lv); }
      { dim3 gs((maxn+63)/64,lv.cnt);
        k_ed_secular<<<gs,64,0,stream>>>(eddl,edw,meta,dvec,DC,lv);
        k_ed_lowner<<<gs,64,0,stream>>>(eddl,edw,DC,meta,lv); }
      { dim3 gv(maxn,lv.cnt);
        k_ed_vecs<<<gv,256,0,stream>>>(edw,DC,edic,meta,lv); }
      { dim3 gg((maxn+63)/64,(maxn+63)/64,lv.cnt);
        k_gemm_cm2<<<gg,256,0,stream>>>(Q2,DC,QM,meta,lv); }
      k_ed_post<<<lv.cnt,256,0,stream>>>(dvec,edds,indxq,meta,lv);
      for(int i=0;i<cn/2;i++){ cst[i]=cst[2*i]; csz[i]=csz[2*i]+csz[2*i+1]; }
      cn>>=1;
    }
  }
  // ---- back-transform (fused eigvec gather from QM via indxq; writes Vt), then transpose ----
  k_backt<<<256,128,0,stream>>>(A,tauv,scalv,QM,indxq,Vt);
  { dim3 g((NN+31)/32,(512+31)/32); k_transpose<<<g,256,0,stream>>>(Vt,pe); }

  // ---- network phase (A dead after backt; liveness-checked W-slot schedule) ----
  float* hx=W0; float* h0=W1; float* hb=W4;
  GEMM(H,W_lin,b_lin,nullptr,hx,NN,HID,NN,0);
  GEMM(hx,W_h,b_h,nullptr,h0,NN,HID,HID,0);
  GEMM(pe,W_lap,b_lap,h0,hb,NN,HID,HID,0);      // pe dead after this
  k_prep_uw<<<2,256,0,stream>>>(W_e,b_e,We1,ub,w1b);
  k_zero_i<<<(NN+255)/256,256,0,stream>>>(icnt,NN);
  k_count<<<(P+255)/256,256,0,stream>>>(edst,icnt,P);
  k_scan<<<1,256,0,stream>>>(icnt,iptr);
  k_fill<<<NN,256,0,stream>>>(edst,iptr,iidx,P);
  // ---- layer 1 (edge layer; e1 branch dead) ----
  float* qb=W0; float* kb=W1; float* vb=W3;     // hx,h0 dead
  { dim3 g((HID+63)/64,(NN+63)/64);
    k_gemm3<<<g,256,0,stream>>>(hb,Wq1,Wk1,Wv1,qb,kb,vb,NN,HID,HID); }
  float* logit=W2;                               // pe dead
  k_elogits<<<(P+3)/4,256,0,stream>>>(qb,kb,esrc,edst,edge_w,ub,w1b,logit,P,1);
  float* wght=W5;
  k_softmax<<<NN,256,0,stream>>>(logit,iptr,iidx,wght);
  float* aggb=W6;                                // Vt dead
  k_agg<<<NN,512,0,stream>>>(wght,vb,esrc,iptr,iidx,aggb);
  float* ob=W0;                                  // qb dead
  GEMM(aggb,Wo1,nullptr,nullptr,ob,NN,HID,HID,0);
  float* h1a=W3;                                 // vb dead
  k_lnadd<<<NN,256,0,stream>>>(hb,ob,h1a);
  float* tb1=W0;                                 // spans W0..W1 (ob,kb dead); NN x 1024
  GEMM(h1a,Wf1a,nullptr,nullptr,tb1,NN,1024,HID,1);
  float* fb=W2;                                  // logit dead
  GEMM(tb1,Wf1b,nullptr,nullptr,fb,NN,HID,1024,0);
  float* h1=W5;                                  // wght dead
  k_lnadd<<<NN,256,0,stream>>>(h1a,fb,h1);
  // ---- layer 2 (plain GT layer) ----
  float* q2=W0; float* k2=W1; float* v2=W2;      // tb1,fb dead
  { dim3 g((HID+63)/64,(NN+63)/64);
    k_gemm3<<<g,256,0,stream>>>(h1,Wq2,Wk2,Wv2,q2,k2,v2,NN,HID,HID); }
  float* logit2=W3;                              // h1a dead
  k_elogits<<<(P+3)/4,256,0,stream>>>(q2,k2,esrc,edst,nullptr,nullptr,nullptr,logit2,P,0);
  float* wght2=W4;                               // hb dead
  k_softmax<<<NN,256,0,stream>>>(logit2,iptr,iidx,wght2);
  float* agg2=W6;                                // aggb dead
  k_agg<<<NN,512,0,stream>>>(wght2,v2,esrc,iptr,iidx,agg2);
  float* o2=W0;                                  // q2 dead
  GEMM(agg2,Wo2,nullptr,nullptr,o2,NN,HID,HID,0);
  float* h2a=W1;                                 // k2 dead
  k_lnadd<<<NN,256,0,stream>>>(h1,o2,h2a);
  float* tb2=W2;                                 // spans W2..W3 (v2,logit2 dead); NN x 1024
  GEMM(h2a,Wf2a,nullptr,nullptr,tb2,NN,1024,HID,1);
  float* f2=W0;                                  // o2 dead
  GEMM(tb2,Wf2b,nullptr,nullptr,f2,NN,HID,1024,0);
  k_lnadd<<<NN,256,0,stream>>>(h2a,f2,out);
}